// Round 9
// baseline (1093.166 us; speedup 1.0000x reference)
//
#include <hip/hip_runtime.h>
#include <math.h>

#define T_LEN 32512
#define NTILES 508
#define NT32 1016
#define BATCH 2
#define NMEL 80
#define FRAMES 128
#define NBLK 30
#define NPAIRS 15
#define PAD 768
#define TP (T_LEN + PAD)  // 33280

typedef short bfrag __attribute__((ext_vector_type(8)));
typedef float facc __attribute__((ext_vector_type(4)));
typedef ushort us4v __attribute__((ext_vector_type(4)));
typedef ushort us8v __attribute__((ext_vector_type(8)));

#define MFMA16(a, b, c) __builtin_amdgcn_mfma_f32_16x16x32_bf16((a), (b), (c), 0, 0, 0)

// ---- workspace layout (byte offsets) ----
#define RESF_OFF   0u          // f32  [2buf][2b][TP][64] = 34,078,720
#define RESH_OFF   34078720u   // bf16 [2buf][2b][TP][64] = 17,039,360
#define CONDB_OFF  51118080u   // bf16 [2b][TP][96]       = 12,779,520
#define WA_OFF     63897600u   // bf16 30*56*512
#define WSF_OFF    65617920u   // bf16 30*16*512
#define WRF_OFF    66109440u   // bf16 30*8*512
#define WP1_OFF    66355200u   // bf16 64*512
#define WP2_OFF    66420736u   // bf16 128*512
#define ZB_OFF     66551808u   // f32 30*128
#define SBS_OFF    66567168u   // f32 128
#define SKIPG_OFF  66567680u   // f32 [2b][T][128] = 33,292,288
#define CONDA_OFF  SKIPG_OFF   // condA aliased (dead before first skip_accum)
#define HB_OFF     99859968u   // bf16 h slots: [slot][2b][T][64]
#define SLOT_BYTES 8323072ull
#define SLOT_ELEMS 4161536ull
#define Y1R_OFF    0u          // bf16 [2b][256][T] aliases resf (dead after pairs)

static __device__ __forceinline__ ushort f2bf(float f) {
  union { float f; unsigned int u; } v;
  v.f = f;
  unsigned int r = (v.u + 0x7FFFu + ((v.u >> 16) & 1u)) >> 16;
  return (ushort)r;
}
static __device__ __forceinline__ float bf2f(ushort h) {
  union { unsigned int u; float f; } v;
  v.u = ((unsigned int)h) << 16;
  return v.f;
}
static __device__ __forceinline__ float sigmoidf_(float x) {
  return 1.f / (1.f + __expf(-x));
}
static __device__ __forceinline__ float tanhf_(float x) {
  return 2.f / (1.f + __expf(-2.f * x)) - 1.f;
}
static __device__ __forceinline__ bfrag ldfrag(const ushort* p) {
  return *reinterpret_cast<const bfrag*>(p);
}
static __device__ __forceinline__ void gload_lds16(const void* g, void* l) {
  __builtin_amdgcn_global_load_lds(
      (const __attribute__((address_space(1))) unsigned int*)g,
      (__attribute__((address_space(3))) unsigned int*)l, 16, 0, 0);
}

// ---- prep: weights -> MFMA A-fragments; condA; zb; sbs ----
__global__ __launch_bounds__(256) void prep_kernel(
    const float* __restrict__ dil_w, const float* __restrict__ cond_w,
    const float* __restrict__ skip_w, const float* __restrict__ res_w,
    const float* __restrict__ p1_w, const float* __restrict__ p2_w,
    const float* __restrict__ mel_w, const float* __restrict__ dil_b,
    const float* __restrict__ cond_b, const float* __restrict__ skip_b,
    ushort* __restrict__ wa, ushort* __restrict__ wsf, ushort* __restrict__ wrf,
    ushort* __restrict__ wp1, ushort* __restrict__ wp2,
    ushort* __restrict__ condA, float* __restrict__ zb,
    float* __restrict__ sbs) {
  int tid = blockIdx.x * blockDim.x + threadIdx.x;
  int stride = gridDim.x * blockDim.x;
  // W_all[layer][128 m][224 k]: k<64 tap0; k<128 tap1; k<208 cond(96-pad); else 0
  for (int idx = tid; idx < NBLK * 56 * 512; idx += stride) {
    int j = idx & 7, lane = (idx >> 3) & 63;
    int f = (idx >> 9) % 56, layer = idx / (56 * 512);
    int mt = f / 7, kt = f % 7;
    int m = 16 * mt + (lane & 15);
    int k = 32 * kt + 8 * (lane >> 4) + j;
    float v;
    if (k < 64)       v = dil_w[(((size_t)layer * 128 + m) * 64 + k) * 2 + 0];
    else if (k < 128) v = dil_w[(((size_t)layer * 128 + m) * 64 + (k - 64)) * 2 + 1];
    else if (k < 208) v = cond_w[((size_t)layer * 128 + m) * 80 + (k - 128)];
    else              v = 0.f;
    wa[idx] = f2bf(v);
  }
  for (int idx = tid; idx < NBLK * 16 * 512; idx += stride) {
    int j = idx & 7, lane = (idx >> 3) & 63;
    int f = (idx >> 9) & 15, layer = idx / (16 * 512);
    int mt = f >> 1, kt = f & 1;
    int m = 16 * mt + (lane & 15);
    int k = 32 * kt + 8 * (lane >> 4) + j;
    wsf[idx] = f2bf(skip_w[((size_t)layer * 128 + m) * 64 + k]);
  }
  for (int idx = tid; idx < NBLK * 8 * 512; idx += stride) {
    int j = idx & 7, lane = (idx >> 3) & 63;
    int f = (idx >> 9) & 7, layer = idx / (8 * 512);
    int mt = f >> 1, kt = f & 1;
    int m = 16 * mt + (lane & 15);
    int k = 32 * kt + 8 * (lane >> 4) + j;
    wrf[idx] = f2bf(res_w[((size_t)layer * 64 + m) * 64 + k]);
  }
  for (int idx = tid; idx < 64 * 512; idx += stride) {
    int j = idx & 7, lane = (idx >> 3) & 63;
    int f = idx >> 9;
    int mt = f >> 2, kt = f & 3;
    int m = 16 * mt + (lane & 15);
    int k = 32 * kt + 8 * (lane >> 4) + j;
    wp1[idx] = f2bf(p1_w[(size_t)m * 128 + k]);
  }
  for (int idx = tid; idx < 128 * 512; idx += stride) {
    int j = idx & 7, lane = (idx >> 3) & 63;
    int f = idx >> 9;
    int mt = f >> 3, kt = f & 7;
    int m = 16 * mt + (lane & 15);
    int k = 32 * kt + 8 * (lane >> 4) + j;
    wp2[idx] = f2bf(p2_w[(size_t)m * 256 + k]);
  }
  // condA[u][f=mt*5+kt][512] -- linear index = write-contiguous
  for (int idx = tid; idx < 25 * 512 * 256; idx += stride) {
    int q = idx & 511;
    int f = (idx >> 9) % 25;
    int u = idx / (25 * 512);
    int j = q & 7, lane = q >> 3;
    int mt = f / 5, kt = f % 5;
    int m = 16 * mt + (lane & 15);
    int k = 32 * kt + 8 * (lane >> 4) + j;
    int ci = (k < 80) ? k : k - 80;
    int kk = (k < 80) ? (255 - u) : (511 - u);
    condA[idx] = f2bf(mel_w[((size_t)m * 80 + ci) * 512 + kk]);
  }
  for (int idx = tid; idx < NBLK * 128; idx += stride)
    zb[idx] = dil_b[idx] + cond_b[idx];
  for (int idx = tid; idx < 128; idx += stride) {
    float s = 0.f;
    for (int i2 = 0; i2 < NBLK; ++i2) s += skip_b[i2 * 128 + idx];
    sbs[idx] = s;
  }
}

// ---- mel upsample MFMA; writes cond t-major [b][TP][96] bf16 ----
#define BSTR 168
__global__ __launch_bounds__(256) void cond_mfma(
    const float* __restrict__ mels, const ushort* __restrict__ condA,
    const float* __restrict__ mel_b, ushort* __restrict__ condb) {
  __shared__ ushort BT[128 * BSTR];
  const int tid = threadIdx.x;
  const int lane = tid & 63;
  const int w = tid >> 6;
  const int b = blockIdx.y;
  const int half = blockIdx.z;
  const int u = blockIdx.x * 4 + w;
  const int q4 = 4 * (lane >> 4);
  const int l15 = lane & 15;
  const float* melb = mels + (size_t)b * NMEL * FRAMES;
  for (int idx = tid; idx < 160 * 128; idx += 256) {
    int M = idx & 127;
    int k = idx >> 7;
    int ci = (k < 80) ? k : k - 80;
    int Mp = M + ((k < 80) ? 0 : 1);
    float v = (Mp < 128) ? melb[(size_t)ci * FRAMES + Mp] : 0.f;
    BT[M * BSTR + k] = f2bf(v);
  }
  __syncthreads();
  facc acc[5][4];
  #pragma unroll
  for (int mt = 0; mt < 5; ++mt) {
    #pragma unroll
    for (int nt = 0; nt < 4; ++nt) {
      #pragma unroll
      for (int r = 0; r < 4; ++r) acc[mt][nt][r] = mel_b[16 * mt + q4 + r];
    }
  }
  const ushort* cA = condA + (size_t)u * 25 * 512 + lane * 8;
  const int bofs = l15 * BSTR + 8 * (lane >> 4);
  #pragma unroll
  for (int kt = 0; kt < 5; ++kt) {
    bfrag a[5];
    #pragma unroll
    for (int mt = 0; mt < 5; ++mt) a[mt] = ldfrag(cA + (mt * 5 + kt) * 512);
    #pragma unroll
    for (int nt = 0; nt < 4; ++nt) {
      bfrag bb = ldfrag(&BT[(half * 64 + nt * 16) * BSTR + bofs + kt * 32]);
      #pragma unroll
      for (int mt = 0; mt < 5; ++mt) acc[mt][nt] = MFMA16(a[mt], bb, acc[mt][nt]);
    }
  }
  ushort* cbp = condb + (size_t)b * TP * 96;
  #pragma unroll
  for (int mt = 0; mt < 5; ++mt) {
    #pragma unroll
    for (int nt = 0; nt < 4; ++nt) {
      const int M = half * 64 + nt * 16 + l15;
      if (M < 127) {
        us4v p;
        #pragma unroll
        for (int r = 0; r < 4; ++r) p[r] = f2bf(acc[mt][nt][r]);
        const int t = M * 256 + u;
        *reinterpret_cast<us4v*>(&cbp[(size_t)(t + PAD) * 96 + 16 * mt + q4]) = p;
      }
    }
  }
}

// ---- init: res_0 fp32 + bf16, t-major rows [PAD, PAD+T) ----
__global__ __launch_bounds__(256) void init_res_kernel(
    const float* __restrict__ x, const float* __restrict__ iw,
    const float* __restrict__ ib, float* __restrict__ resf0,
    ushort* __restrict__ resh0) {
  int idx = blockIdx.x * blockDim.x + threadIdx.x;
  if (idx >= BATCH * T_LEN * 64) return;
  int c = idx & 63;
  int t = (idx >> 6) % T_LEN;
  int b = idx / (64 * T_LEN);
  float v = x[(size_t)b * T_LEN + t] * iw[c] + ib[c];
  size_t o = (size_t)b * TP * 64 + (size_t)(t + PAD) * 64 + c;
  resf0[o] = v;
  resh0[o] = f2bf(v);
}

// ============ pair kernel: layers (i0,i0+1); 32-t tiles, 8 blocks/CU ============
// Round-7 verified phase structure (sequential contexts); tile halved for
// occupancy: grid 1016x2, LDS 13.8KB, nt=2 -> 32 waves/CU.
template <int DEFER>
__global__ __launch_bounds__(256, 8) void wn_pair_kernel(
    const float* __restrict__ resf_in, float* __restrict__ resf_out,
    const ushort* __restrict__ resh_in, ushort* __restrict__ resh_out,
    const ushort* __restrict__ condb, const ushort* __restrict__ wa,
    const ushort* __restrict__ wsf, const ushort* __restrict__ wrf,
    const float* __restrict__ zb, const float* __restrict__ res_b,
    const float* __restrict__ skip_b, float* __restrict__ skipg,
    ushort* __restrict__ hb0, ushort* __restrict__ hb1, int i0, int d0,
    int writeRes) {
  __shared__ ushort HT[32 * 72];
  __shared__ ushort RTs[32 * 72];
  __shared__ ushort RTh[32 * 72];
  const int i1 = i0 + 1;
  const int d1 = 2 * d0;
  const int tid = threadIdx.x;
  const int lane = tid & 63;
  const int w = tid >> 6;
  const int l15 = lane & 15;
  const int q4 = 4 * (lane >> 4);
  const int colq = 8 * (lane >> 4);
  // bijective XCD swizzle (1016 = 8*127)
  const int orig = blockIdx.x;
  const int tile = (orig & 7) * 127 + (orig >> 3);
  const int t0 = tile * 32;
  const int t0s = t0 - d1;
  const int b = blockIdx.y;

  const float* rfi = resf_in + (size_t)b * TP * 64;
  float* rfo = resf_out + (size_t)b * TP * 64;
  const ushort* rhi = resh_in + (size_t)b * TP * 64;
  ushort* rho = resh_out + (size_t)b * TP * 64;
  const ushort* cbp = condb + (size_t)b * TP * 96;
  const int bofs_h = l15 * 72 + colq;

  facc rs_s[2], rs_h[2], sk[4];
  facc accF[2], accG[2];
  if constexpr (!DEFER) {
    #pragma unroll
    for (int j = 0; j < 4; ++j) {
      const int ch = 32 * w + 16 * (j >> 1) + q4;
      facc s0 = *(const facc*)(skip_b + i0 * 128 + ch);
      facc s1 = *(const facc*)(skip_b + i1 * 128 + ch);
      sk[j] = s0 + s1;
    }
  }

#define ZG_INITB(LAYER)                                                       \
  _Pragma("unroll")                                                           \
  for (int nt = 0; nt < 2; ++nt) {                                            \
    accF[nt] = *(const facc*)(zb + (LAYER) * 128 + 16 * w + q4);              \
    accG[nt] = *(const facc*)(zb + (LAYER) * 128 + 64 + 16 * w + q4);         \
  }

#define ZG_GLOBAL(LAYER, TB)                                                  \
  {                                                                           \
    ZG_INITB(LAYER)                                                           \
    const ushort* wal = wa + (size_t)(LAYER) * 56 * 512 + lane * 8;           \
    const ushort* bp0[2];                                                     \
    const ushort* bp1[2];                                                     \
    const ushort* bpc[2];                                                     \
    _Pragma("unroll")                                                         \
    for (int nt = 0; nt < 2; ++nt) {                                          \
      const int tg = (TB) + nt * 16 + l15;                                    \
      bp0[nt] = rhi + (size_t)(tg - d0 + PAD) * 64 + colq;                    \
      bp1[nt] = rhi + (size_t)(tg + PAD) * 64 + colq;                         \
      bpc[nt] = cbp + (size_t)(tg + PAD) * 96 + colq;                         \
    }                                                                         \
    _Pragma("unroll")                                                         \
    for (int kt = 0; kt < 7; ++kt) {                                          \
      bfrag aF = ldfrag(wal + (w * 7 + kt) * 512);                            \
      bfrag aG = ldfrag(wal + ((w + 4) * 7 + kt) * 512);                      \
      _Pragma("unroll")                                                       \
      for (int nt = 0; nt < 2; ++nt) {                                        \
        bfrag bb = (kt < 2)   ? ldfrag(bp0[nt] + kt * 32)                     \
                   : (kt < 4) ? ldfrag(bp1[nt] + (kt - 2) * 32)               \
                              : ldfrag(bpc[nt] + (kt - 4) * 32);              \
        accF[nt] = MFMA16(aF, bb, accF[nt]);                                  \
        accG[nt] = MFMA16(aG, bb, accG[nt]);                                  \
      }                                                                       \
    }                                                                         \
  }

#define ZG_LDS(LAYER)                                                        \
  {                                                                           \
    ZG_INITB(LAYER)                                                           \
    const ushort* wal = wa + (size_t)(LAYER) * 56 * 512 + lane * 8;           \
    const ushort* bpc[2];                                                     \
    _Pragma("unroll")                                                         \
    for (int nt = 0; nt < 2; ++nt)                                            \
      bpc[nt] = cbp + (size_t)(t0 + nt * 16 + l15 + PAD) * 96 + colq;         \
    _Pragma("unroll")                                                         \
    for (int kt = 0; kt < 7; ++kt) {                                          \
      bfrag aF = ldfrag(wal + (w * 7 + kt) * 512);                            \
      bfrag aG = ldfrag(wal + ((w + 4) * 7 + kt) * 512);                      \
      _Pragma("unroll")                                                       \
      for (int nt = 0; nt < 2; ++nt) {                                        \
        bfrag bb = (kt < 2)                                                   \
            ? ldfrag(&RTs[(nt * 16 + l15) * 72 + kt * 32 + colq])             \
            : (kt < 4)                                                        \
                ? ldfrag(&RTh[(nt * 16 + l15) * 72 + (kt - 2) * 32 + colq])   \
                : ldfrag(bpc[nt] + (kt - 4) * 32);                            \
        accF[nt] = MFMA16(aF, bb, accF[nt]);                                  \
        accG[nt] = MFMA16(aG, bb, accG[nt]);                                  \
      }                                                                       \
    }                                                                         \
  }

#define GATE(HBPTR, DOHB)                                                     \
  {                                                                           \
    _Pragma("unroll")                                                         \
    for (int nt = 0; nt < 2; ++nt) {                                          \
      us4v p;                                                                 \
      _Pragma("unroll")                                                       \
      for (int r = 0; r < 4; ++r)                                             \
        p[r] = f2bf(tanhf_(accF[nt][r]) * sigmoidf_(accG[nt][r]));            \
      *reinterpret_cast<us4v*>(&HT[(nt * 16 + l15) * 72 + 16 * w + q4]) = p;  \
      if (DOHB)                                                               \
        *reinterpret_cast<us4v*>((HBPTR) + (size_t)b * T_LEN * 64 +           \
                                 (size_t)(t0 + nt * 16 + l15) * 64 +          \
                                 16 * w + q4) = p;                            \
    }                                                                         \
  }

#define RES_GEMM(LAYER, RS)                                                   \
  {                                                                           \
    const ushort* wrl = wrf + (size_t)(LAYER) * 8 * 512 + lane * 8;           \
    _Pragma("unroll")                                                         \
    for (int kt = 0; kt < 2; ++kt) {                                          \
      bfrag ar = ldfrag(wrl + (w * 2 + kt) * 512);                            \
      _Pragma("unroll")                                                       \
      for (int nt = 0; nt < 2; ++nt) {                                        \
        bfrag bb = ldfrag(&HT[nt * 16 * 72 + bofs_h + kt * 32]);              \
        RS[nt] = MFMA16(ar, bb, RS[nt]);                                      \
      }                                                                       \
    }                                                                         \
  }

#define SKIP_GEMM(LAYER)                                                      \
  {                                                                           \
    const ushort* wsl = wsf + (size_t)(LAYER) * 16 * 512 + lane * 8;          \
    _Pragma("unroll")                                                         \
    for (int kt = 0; kt < 2; ++kt) {                                          \
      bfrag a0 = ldfrag(wsl + ((2 * w) * 2 + kt) * 512);                      \
      bfrag a1 = ldfrag(wsl + ((2 * w + 1) * 2 + kt) * 512);                  \
      _Pragma("unroll")                                                       \
      for (int nt = 0; nt < 2; ++nt) {                                        \
        bfrag bb = ldfrag(&HT[nt * 16 * 72 + bofs_h + kt * 32]);              \
        sk[nt] = MFMA16(a0, bb, sk[nt]);                                      \
        sk[2 + nt] = MFMA16(a1, bb, sk[2 + nt]);                              \
      }                                                                       \
    }                                                                         \
  }

  // ===== ctx S: layer i0 @ shifted tile =====
  ZG_GLOBAL(i0, t0s);
  GATE(hb0, 0);
  __syncthreads();
  #pragma unroll
  for (int nt = 0; nt < 2; ++nt) {
    const int tg = t0s + nt * 16 + l15;
    us4v hv = *(const us4v*)(rhi + (size_t)(tg + PAD) * 64 + 16 * w + q4);
    facc rbv = *(const facc*)(res_b + i0 * 64 + 16 * w + q4);
    #pragma unroll
    for (int r = 0; r < 4; ++r) rs_s[nt][r] = bf2f(hv[r]) + rbv[r];
  }
  RES_GEMM(i0, rs_s);
  #pragma unroll
  for (int nt = 0; nt < 2; ++nt) {
    const bool ok = (t0s + nt * 16 + l15) >= 0;
    us4v p;
    #pragma unroll
    for (int r = 0; r < 4; ++r) p[r] = ok ? f2bf(rs_s[nt][r]) : (ushort)0;
    *reinterpret_cast<us4v*>(&RTs[(nt * 16 + l15) * 72 + 16 * w + q4]) = p;
  }
  __syncthreads();
  // ===== ctx H: layer i0 @ home =====
  ZG_GLOBAL(i0, t0);
  GATE(hb0, DEFER);
  __syncthreads();
  #pragma unroll
  for (int nt = 0; nt < 2; ++nt) {
    const int tg = t0 + nt * 16 + l15;
    facc v = *(const facc*)(rfi + (size_t)(tg + PAD) * 64 + 16 * w + q4);
    facc rbv = *(const facc*)(res_b + i0 * 64 + 16 * w + q4);
    rs_h[nt] = v + rbv;
  }
  if constexpr (!DEFER) { SKIP_GEMM(i0); }
  RES_GEMM(i0, rs_h);
  #pragma unroll
  for (int nt = 0; nt < 2; ++nt) {
    us4v p;
    #pragma unroll
    for (int r = 0; r < 4; ++r) p[r] = f2bf(rs_h[nt][r]);
    *reinterpret_cast<us4v*>(&RTh[(nt * 16 + l15) * 72 + 16 * w + q4]) = p;
  }
  __syncthreads();
  // ===== layer i1 @ home (taps from RTs/RTh) =====
  ZG_LDS(i1);
  GATE(hb1, DEFER);
  __syncthreads();
  #pragma unroll
  for (int nt = 0; nt < 2; ++nt) {
    facc rbv = *(const facc*)(res_b + i1 * 64 + 16 * w + q4);
    rs_s[nt] = rs_h[nt] + rbv;
  }
  if constexpr (!DEFER) { SKIP_GEMM(i1); }
  RES_GEMM(i1, rs_s);
  // ===== epilogue =====
  if (writeRes) {
    #pragma unroll
    for (int nt = 0; nt < 2; ++nt) {
      const int tg = t0 + nt * 16 + l15;
      *(facc*)(rfo + (size_t)(tg + PAD) * 64 + 16 * w + q4) = rs_s[nt];
      us4v p;
      #pragma unroll
      for (int r = 0; r < 4; ++r) p[r] = f2bf(rs_s[nt][r]);
      *reinterpret_cast<us4v*>(rho + (size_t)(tg + PAD) * 64 + 16 * w + q4) = p;
    }
  }
  if constexpr (!DEFER) {
    float* sg = skipg + (size_t)b * T_LEN * 128;
    #pragma unroll
    for (int nt = 0; nt < 2; ++nt) {
      const int tg = t0 + nt * 16 + l15;
      facc* p0 = (facc*)(sg + (size_t)tg * 128 + 32 * w + q4);
      facc* p1 = (facc*)(sg + (size_t)tg * 128 + 32 * w + 16 + q4);
      *p0 = *p0 + sk[nt];
      *p1 = *p1 + sk[2 + nt];
    }
  }
#undef ZG_INITB
#undef ZG_GLOBAL
#undef ZG_LDS
#undef GATE
#undef RES_GEMM
#undef SKIP_GEMM
}

// ---- skip_accum v3: LDS-staged h, 32-t blocks; optional fused post1 ----
template <int FIRST, int FUSE>
__global__ __launch_bounds__(256) void skip_accum(
    const ushort* __restrict__ hb, const ushort* __restrict__ wsf,
    float* __restrict__ skipg, const float* __restrict__ sbs,
    const ushort* __restrict__ wp1, const float* __restrict__ p1b,
    ushort* __restrict__ y1r, int base, int nl) {
  __shared__ ushort HL[12 * 2048];
  const int tid = threadIdx.x;
  const int lane = tid & 63;
  const int w = tid >> 6;
  const int l15 = lane & 15;
  const int q4 = 4 * (lane >> 4);
  const int colq = 8 * (lane >> 4);
  const int t0 = blockIdx.x * 32;
  const int b = blockIdx.y;

  {
    const int D = tid * 16;
    const int Dsw = D ^ (((D >> 7) & 7) << 4);
    const char* srcb =
        (const char*)(hb + (size_t)b * T_LEN * 64 + (size_t)t0 * 64);
    char* ldsb = (char*)HL + (tid >> 6) * 1024;
    for (int l = 0; l < nl; ++l)
      gload_lds16(srcb + (size_t)l * SLOT_BYTES + Dsw, ldsb + l * 4096);
  }

  float* sg = skipg + (size_t)b * T_LEN * 128;
  facc a0[2], a1[2];
  if constexpr (FIRST) {
    #pragma unroll
    for (int nt = 0; nt < 2; ++nt) {
      #pragma unroll
      for (int r = 0; r < 4; ++r) { a0[nt][r] = 0.f; a1[nt][r] = 0.f; }
    }
  } else {
    #pragma unroll
    for (int nt = 0; nt < 2; ++nt) {
      const int tg = t0 + nt * 16 + l15;
      a0[nt] = *(const facc*)(sg + (size_t)tg * 128 + 32 * w + q4);
      a1[nt] = *(const facc*)(sg + (size_t)tg * 128 + 32 * w + 16 + q4);
    }
  }
  __syncthreads();

  for (int l = 0; l < nl; ++l) {
    const ushort* wsl = wsf + (size_t)(base + l) * 16 * 512 + lane * 8;
    #pragma unroll
    for (int kt = 0; kt < 2; ++kt) {
      bfrag f0 = ldfrag(wsl + ((2 * w) * 2 + kt) * 512);
      bfrag f1 = ldfrag(wsl + ((2 * w + 1) * 2 + kt) * 512);
      #pragma unroll
      for (int nt = 0; nt < 2; ++nt) {
        const int t = nt * 16 + l15;
        int byteoff = t * 128 + kt * 64 + colq * 2;
        byteoff ^= ((t & 7) << 4);
        bfrag bb = ldfrag((const ushort*)((const char*)HL + l * 4096 + byteoff));
        a0[nt] = MFMA16(f0, bb, a0[nt]);
        a1[nt] = MFMA16(f1, bb, a1[nt]);
      }
    }
  }

  if constexpr (!FUSE) {
    #pragma unroll
    for (int nt = 0; nt < 2; ++nt) {
      const int tg = t0 + nt * 16 + l15;
      *(facc*)(sg + (size_t)tg * 128 + 32 * w + q4) = a0[nt];
      *(facc*)(sg + (size_t)tg * 128 + 32 * w + 16 + q4) = a1[nt];
    }
  } else {
    __syncthreads();
    ushort* ST = HL;
    #pragma unroll
    for (int nt = 0; nt < 2; ++nt) {
      us4v p0, p1;
      #pragma unroll
      for (int r = 0; r < 4; ++r) {
        p0[r] = f2bf(fmaxf(a0[nt][r] + sbs[32 * w + q4 + r], 0.f));
        p1[r] = f2bf(fmaxf(a1[nt][r] + sbs[32 * w + 16 + q4 + r], 0.f));
      }
      const int row = nt * 16 + l15;
      *reinterpret_cast<us4v*>(&ST[row * 136 + 32 * w + q4]) = p0;
      *reinterpret_cast<us4v*>(&ST[row * 136 + 32 * w + 16 + q4]) = p1;
    }
    __syncthreads();
    facc acc2[4][2];
    #pragma unroll
    for (int mi = 0; mi < 4; ++mi) {
      #pragma unroll
      for (int nt = 0; nt < 2; ++nt) {
        #pragma unroll
        for (int r = 0; r < 4; ++r)
          acc2[mi][nt][r] = p1b[16 * (4 * w + mi) + q4 + r];
      }
    }
    const int lo = lane * 8;
    #pragma unroll
    for (int kt = 0; kt < 4; ++kt) {
      bfrag am[4];
      #pragma unroll
      for (int mi = 0; mi < 4; ++mi)
        am[mi] = ldfrag(wp1 + ((4 * w + mi) * 4 + kt) * 512 + lo);
      #pragma unroll
      for (int nt = 0; nt < 2; ++nt) {
        bfrag bb = ldfrag(&ST[(nt * 16 + l15) * 136 + kt * 32 + colq]);
        #pragma unroll
        for (int mi = 0; mi < 4; ++mi)
          acc2[mi][nt] = MFMA16(am[mi], bb, acc2[mi][nt]);
      }
    }
    ushort* yb = y1r + (size_t)b * 256 * T_LEN;
    #pragma unroll
    for (int mi = 0; mi < 4; ++mi) {
      #pragma unroll
      for (int nt = 0; nt < 2; ++nt) {
        const int tt = t0 + nt * 16 + l15;
        #pragma unroll
        for (int r = 0; r < 4; ++r)
          yb[(size_t)(16 * (4 * w + mi) + q4 + r) * T_LEN + tt] =
              f2bf(fmaxf(acc2[mi][nt][r], 0.f));
      }
    }
  }
}

// ---- standalone post1 (non-defer fallback only; sbs may be null) ----
#define FSSTR 136
__global__ __launch_bounds__(256) void post1_mfma(
    const float* __restrict__ skipg, const float* __restrict__ sbs,
    const ushort* __restrict__ wp1, const float* __restrict__ p1b,
    ushort* __restrict__ y1r) {
  __shared__ ushort ST[64 * FSSTR];
  const int tid = threadIdx.x;
  const int lane = tid & 63;
  const int w = tid >> 6;
  const int t0 = blockIdx.x * 64;
  const int b = blockIdx.y;
  {
    const int t = tid & 63;
    const int kc = tid >> 6;
    const float* sp =
        skipg + (size_t)b * T_LEN * 128 + (size_t)(t0 + t) * 128 + kc * 32;
    #pragma unroll
    for (int j = 0; j < 8; ++j) {
      facc v = *(const facc*)(sp + j * 4);
      us4v o;
      #pragma unroll
      for (int r = 0; r < 4; ++r) {
        float s = sbs ? sbs[kc * 32 + j * 4 + r] : 0.f;
        o[r] = f2bf(fmaxf(v[r] + s, 0.f));
      }
      *reinterpret_cast<us4v*>(&ST[t * FSSTR + kc * 32 + j * 4]) = o;
    }
  }
  __syncthreads();
  const int q4 = 4 * (lane >> 4);
  facc acc[4][4];
  #pragma unroll
  for (int mi = 0; mi < 4; ++mi) {
    #pragma unroll
    for (int nt = 0; nt < 4; ++nt) {
      #pragma unroll
      for (int r = 0; r < 4; ++r)
        acc[mi][nt][r] = p1b[16 * (4 * w + mi) + q4 + r];
    }
  }
  const int lo = lane * 8;
  const int bofs = (lane & 15) * FSSTR + 8 * (lane >> 4);
  #pragma unroll
  for (int kt = 0; kt < 4; ++kt) {
    bfrag a[4];
    #pragma unroll
    for (int mi = 0; mi < 4; ++mi)
      a[mi] = ldfrag(wp1 + ((4 * w + mi) * 4 + kt) * 512 + lo);
    #pragma unroll
    for (int nt = 0; nt < 4; ++nt) {
      bfrag bb = ldfrag(&ST[nt * 16 * FSSTR + bofs + kt * 32]);
      #pragma unroll
      for (int mi = 0; mi < 4; ++mi) acc[mi][nt] = MFMA16(a[mi], bb, acc[mi][nt]);
    }
  }
  ushort* yb = y1r + (size_t)b * 256 * T_LEN;
  #pragma unroll
  for (int mi = 0; mi < 4; ++mi) {
    #pragma unroll
    for (int nt = 0; nt < 4; ++nt) {
      const int tt = t0 + nt * 16 + (lane & 15);
      #pragma unroll
      for (int r = 0; r < 4; ++r)
        yb[(size_t)(16 * (4 * w + mi) + q4 + r) * T_LEN + tt] =
            f2bf(fmaxf(acc[mi][nt][r], 0.f));
    }
  }
}

// ---- post2: out = p2_w @ y1r + b (fp32) ----
#define YSTR 264
__global__ __launch_bounds__(256) void post2_mfma(
    const ushort* __restrict__ y1r, const ushort* __restrict__ wp2,
    const float* __restrict__ p2b, float* __restrict__ out) {
  __shared__ ushort YT[64 * YSTR];
  const int tid = threadIdx.x;
  const int lane = tid & 63;
  const int w = tid >> 6;
  const int t0 = blockIdx.x * 64;
  const int b = blockIdx.y;
  const ushort* yb = y1r + (size_t)b * 256 * T_LEN;
  const int t = t0 + lane;
  for (int kc = 0; kc < 8; ++kc) {
    int k0 = w * 64 + kc * 8;
    us8v v;
    #pragma unroll
    for (int j = 0; j < 8; ++j) v[j] = yb[(size_t)(k0 + j) * T_LEN + t];
    *reinterpret_cast<us8v*>(&YT[lane * YSTR + k0]) = v;
  }
  __syncthreads();
  const int q4 = 4 * (lane >> 4);
  facc acc[4][4];
  #pragma unroll
  for (int mi = 0; mi < 4; ++mi) {
    #pragma unroll
    for (int nt = 0; nt < 4; ++nt) {
      #pragma unroll
      for (int r = 0; r < 4; ++r)
        acc[mi][nt][r] = p2b[16 * (4 * w + mi) + q4 + r];
    }
  }
  const int lo = lane * 8;
  const int bofs = (lane & 15) * YSTR + 8 * (lane >> 4);
  #pragma unroll
  for (int kt = 0; kt < 8; ++kt) {
    bfrag a[4];
    #pragma unroll
    for (int mi = 0; mi < 4; ++mi)
      a[mi] = ldfrag(wp2 + ((4 * w + mi) * 8 + kt) * 512 + lo);
    #pragma unroll
    for (int nt = 0; nt < 4; ++nt) {
      bfrag bb = ldfrag(&YT[nt * 16 * YSTR + bofs + kt * 32]);
      #pragma unroll
      for (int mi = 0; mi < 4; ++mi) acc[mi][nt] = MFMA16(a[mi], bb, acc[mi][nt]);
    }
  }
  float* ob = out + (size_t)b * 256 * T_LEN;
  #pragma unroll
  for (int mi = 0; mi < 4; ++mi) {
    #pragma unroll
    for (int nt = 0; nt < 4; ++nt) {
      const int tt = t0 + nt * 16 + (lane & 15);
      #pragma unroll
      for (int r = 0; r < 4; ++r)
        ob[(size_t)(16 * (4 * w + mi) + q4 + r) * T_LEN + tt] = acc[mi][nt][r];
    }
  }
}

extern "C" void kernel_launch(void* const* d_in, const int* in_sizes, int n_in,
                              void* d_out, int out_size, void* d_ws,
                              size_t ws_size, hipStream_t stream) {
  const float* x       = (const float*)d_in[0];
  const float* mels    = (const float*)d_in[1];
  const float* input_w = (const float*)d_in[2];
  const float* input_b = (const float*)d_in[3];
  const float* mel_w   = (const float*)d_in[4];
  const float* mel_b   = (const float*)d_in[5];
  const float* dil_w   = (const float*)d_in[6];
  const float* dil_b   = (const float*)d_in[7];
  const float* cond_w  = (const float*)d_in[8];
  const float* cond_b  = (const float*)d_in[9];
  const float* skip_w  = (const float*)d_in[10];
  const float* skip_b  = (const float*)d_in[11];
  const float* res_w   = (const float*)d_in[12];
  const float* res_b   = (const float*)d_in[13];
  const float* p1_w    = (const float*)d_in[14];
  const float* p1_b    = (const float*)d_in[15];
  const float* p2_w    = (const float*)d_in[16];
  const float* p2_b    = (const float*)d_in[17];

  char* ws = (char*)d_ws;
  float* rfA    = (float*)(ws + RESF_OFF);
  float* rfB    = rfA + (size_t)2 * TP * 64;
  ushort* rhA   = (ushort*)(ws + RESH_OFF);
  ushort* rhB   = rhA + (size_t)2 * TP * 64;
  ushort* condb = (ushort*)(ws + CONDB_OFF);
  ushort* wa    = (ushort*)(ws + WA_OFF);
  ushort* wsf   = (ushort*)(ws + WSF_OFF);
  ushort* wrf   = (ushort*)(ws + WRF_OFF);
  ushort* wp1   = (ushort*)(ws + WP1_OFF);
  ushort* wp2   = (ushort*)(ws + WP2_OFF);
  float* zbp    = (float*)(ws + ZB_OFF);
  float* sbsp   = (float*)(ws + SBS_OFF);
  float* skipg  = (float*)(ws + SKIPG_OFF);
  ushort* condA = (ushort*)(ws + CONDA_OFF);
  ushort* hbuf  = (ushort*)(ws + HB_OFF);
  ushort* y1rp  = (ushort*)(ws + Y1R_OFF);
  float* out    = (float*)d_out;

  int G = 0;
  if (ws_size >= (size_t)HB_OFF + 12ull * SLOT_BYTES) {
    G = 6;
  } else if (ws_size >= (size_t)HB_OFF + 2ull * SLOT_BYTES) {
    G = (int)((ws_size - HB_OFF) / (2ull * SLOT_BYTES));
    if (G > 6) G = 6;
  }
  const bool defer = (G >= 1);

  for (int k = 0; k < 2; ++k)
    for (int b = 0; b < 2; ++b) {
      hipMemsetAsync((char*)(k == 0 ? rfA : rfB) + (size_t)b * TP * 64 * 4, 0,
                     (size_t)PAD * 64 * 4, stream);
      hipMemsetAsync((char*)(k == 0 ? rhA : rhB) + (size_t)b * TP * 64 * 2, 0,
                     (size_t)PAD * 64 * 2, stream);
    }
  hipMemsetAsync(condb, 0, (size_t)2 * TP * 96 * 2, stream);

  prep_kernel<<<2048, 256, 0, stream>>>(dil_w, cond_w, skip_w, res_w, p1_w,
                                        p2_w, mel_w, dil_b, cond_b, skip_b, wa,
                                        wsf, wrf, wp1, wp2, condA, zbp, sbsp);
  cond_mfma<<<dim3(64, BATCH, 2), 256, 0, stream>>>(mels, condA, mel_b, condb);
  if (!defer) {
    hipMemsetAsync(skipg, 0, (size_t)2 * T_LEN * 128 * 4, stream);
  }
  init_res_kernel<<<(BATCH * T_LEN * 64 + 255) / 256, 256, 0, stream>>>(
      x, input_w, input_b, rfA, rhA);

  float* rfi = rfA;
  float* rfo = rfB;
  ushort* rhi = rhA;
  ushort* rho = rhB;
  int groupStart = 0;
  const dim3 ag(T_LEN / 32, BATCH);
  for (int p = 0; p < NPAIRS; ++p) {
    int i0 = 2 * p;
    int d0 = 1 << (i0 % 10);
    int wr = (p < NPAIRS - 1) ? 1 : 0;
    if (defer) {
      ushort* h0 = hbuf + (size_t)(2 * (p - groupStart)) * SLOT_ELEMS;
      wn_pair_kernel<1><<<dim3(NT32, BATCH), 256, 0, stream>>>(
          rfi, rfo, rhi, rho, condb, wa, wsf, wrf, zbp, res_b, skip_b, skipg,
          h0, h0 + SLOT_ELEMS, i0, d0, wr);
      if (p - groupStart + 1 == G || p == NPAIRS - 1) {
        int nl = 2 * (p - groupStart + 1);
        int base = 2 * groupStart;
        bool isF = (groupStart == 0);
        bool isL = (p == NPAIRS - 1);
        if (isF && isL)
          skip_accum<1, 1><<<ag, 256, 0, stream>>>(hbuf, wsf, skipg, sbsp, wp1,
                                                   p1_b, y1rp, base, nl);
        else if (isF)
          skip_accum<1, 0><<<ag, 256, 0, stream>>>(hbuf, wsf, skipg, sbsp, wp1,
                                                   p1_b, y1rp, base, nl);
        else if (isL)
          skip_accum<0, 1><<<ag, 256, 0, stream>>>(hbuf, wsf, skipg, sbsp, wp1,
                                                   p1_b, y1rp, base, nl);
        else
          skip_accum<0, 0><<<ag, 256, 0, stream>>>(hbuf, wsf, skipg, sbsp, wp1,
                                                   p1_b, y1rp, base, nl);
        groupStart = p + 1;
      }
    } else {
      wn_pair_kernel<0><<<dim3(NT32, BATCH), 256, 0, stream>>>(
          rfi, rfo, rhi, rho, condb, wa, wsf, wrf, zbp, res_b, skip_b, skipg,
          nullptr, nullptr, i0, d0, wr);
    }
    float* tf = rfi; rfi = rfo; rfo = tf;
    ushort* th = rhi; rhi = rho; rho = th;
  }

  if (!defer) {
    post1_mfma<<<dim3(NTILES, BATCH), 256, 0, stream>>>(skipg, nullptr, wp1,
                                                        p1_b, y1rp);
  }
  post2_mfma<<<dim3(NTILES, BATCH), 256, 0, stream>>>(y1rp, wp2, p2_b, out);
}

// Round 10
// 1084.476 us; speedup vs baseline: 1.0080x; 1.0080x over previous
//
#include <hip/hip_runtime.h>
#include <math.h>

#define T_LEN 32512
#define NTILES 508
#define BATCH 2
#define NMEL 80
#define FRAMES 128
#define NBLK 30
#define NPAIRS 15
#define PAD 768
#define TP (T_LEN + PAD)  // 33280

typedef short bfrag __attribute__((ext_vector_type(8)));
typedef float facc __attribute__((ext_vector_type(4)));
typedef ushort us4v __attribute__((ext_vector_type(4)));
typedef ushort us8v __attribute__((ext_vector_type(8)));

#define MFMA16(a, b, c) __builtin_amdgcn_mfma_f32_16x16x32_bf16((a), (b), (c), 0, 0, 0)

// ---- workspace layout (byte offsets) ----
#define RESF_OFF   0u          // f32  [2buf][2b][TP][64] = 34,078,720
#define RESH_OFF   34078720u   // bf16 [2buf][2b][TP][64] = 17,039,360
#define CONDB_OFF  51118080u   // bf16 [2b][TP][96]       = 12,779,520
#define WA_OFF     63897600u   // bf16 30*56*512
#define WSF_OFF    65617920u   // bf16 30*16*512
#define WRF_OFF    66109440u   // bf16 30*8*512
#define WP1_OFF    66355200u   // bf16 64*512
#define WP2_OFF    66420736u   // bf16 128*512
#define ZB_OFF     66551808u   // f32 30*128
#define SBS_OFF    66567168u   // f32 128
#define SKIPG_OFF  66567680u   // f32 [2b][T][128] = 33,292,288
#define CONDA_OFF  SKIPG_OFF   // condA aliased (dead before first skip_accum)
#define HB_OFF     99859968u   // bf16 h slots: [slot][2b][T][64]
#define SLOT_BYTES 8323072ull
#define SLOT_ELEMS 4161536ull
#define Y1R_OFF    0u          // bf16 [2b][256][T] aliases resf (dead after pairs)

static __device__ __forceinline__ ushort f2bf(float f) {
  union { float f; unsigned int u; } v;
  v.f = f;
  unsigned int r = (v.u + 0x7FFFu + ((v.u >> 16) & 1u)) >> 16;
  return (ushort)r;
}
static __device__ __forceinline__ float bf2f(ushort h) {
  union { unsigned int u; float f; } v;
  v.u = ((unsigned int)h) << 16;
  return v.f;
}
static __device__ __forceinline__ float sigmoidf_(float x) {
  return 1.f / (1.f + __expf(-x));
}
static __device__ __forceinline__ float tanhf_(float x) {
  return 2.f / (1.f + __expf(-2.f * x)) - 1.f;
}
static __device__ __forceinline__ bfrag ldfrag(const ushort* p) {
  return *reinterpret_cast<const bfrag*>(p);
}
static __device__ __forceinline__ void gload_lds16(const void* g, void* l) {
  __builtin_amdgcn_global_load_lds(
      (const __attribute__((address_space(1))) unsigned int*)g,
      (__attribute__((address_space(3))) unsigned int*)l, 16, 0, 0);
}

// ---- prep: weights -> MFMA A-fragments; condA; zb; sbs ----
__global__ __launch_bounds__(256) void prep_kernel(
    const float* __restrict__ dil_w, const float* __restrict__ cond_w,
    const float* __restrict__ skip_w, const float* __restrict__ res_w,
    const float* __restrict__ p1_w, const float* __restrict__ p2_w,
    const float* __restrict__ mel_w, const float* __restrict__ dil_b,
    const float* __restrict__ cond_b, const float* __restrict__ skip_b,
    ushort* __restrict__ wa, ushort* __restrict__ wsf, ushort* __restrict__ wrf,
    ushort* __restrict__ wp1, ushort* __restrict__ wp2,
    ushort* __restrict__ condA, float* __restrict__ zb,
    float* __restrict__ sbs) {
  int tid = blockIdx.x * blockDim.x + threadIdx.x;
  int stride = gridDim.x * blockDim.x;
  // W_all[layer][128 m][224 k]: k<64 tap0; k<128 tap1; k<208 cond(96-pad); else 0
  for (int idx = tid; idx < NBLK * 56 * 512; idx += stride) {
    int j = idx & 7, lane = (idx >> 3) & 63;
    int f = (idx >> 9) % 56, layer = idx / (56 * 512);
    int mt = f / 7, kt = f % 7;
    int m = 16 * mt + (lane & 15);
    int k = 32 * kt + 8 * (lane >> 4) + j;
    float v;
    if (k < 64)       v = dil_w[(((size_t)layer * 128 + m) * 64 + k) * 2 + 0];
    else if (k < 128) v = dil_w[(((size_t)layer * 128 + m) * 64 + (k - 64)) * 2 + 1];
    else if (k < 208) v = cond_w[((size_t)layer * 128 + m) * 80 + (k - 128)];
    else              v = 0.f;
    wa[idx] = f2bf(v);
  }
  for (int idx = tid; idx < NBLK * 16 * 512; idx += stride) {
    int j = idx & 7, lane = (idx >> 3) & 63;
    int f = (idx >> 9) & 15, layer = idx / (16 * 512);
    int mt = f >> 1, kt = f & 1;
    int m = 16 * mt + (lane & 15);
    int k = 32 * kt + 8 * (lane >> 4) + j;
    wsf[idx] = f2bf(skip_w[((size_t)layer * 128 + m) * 64 + k]);
  }
  for (int idx = tid; idx < NBLK * 8 * 512; idx += stride) {
    int j = idx & 7, lane = (idx >> 3) & 63;
    int f = (idx >> 9) & 7, layer = idx / (8 * 512);
    int mt = f >> 1, kt = f & 1;
    int m = 16 * mt + (lane & 15);
    int k = 32 * kt + 8 * (lane >> 4) + j;
    wrf[idx] = f2bf(res_w[((size_t)layer * 64 + m) * 64 + k]);
  }
  for (int idx = tid; idx < 64 * 512; idx += stride) {
    int j = idx & 7, lane = (idx >> 3) & 63;
    int f = idx >> 9;
    int mt = f >> 2, kt = f & 3;
    int m = 16 * mt + (lane & 15);
    int k = 32 * kt + 8 * (lane >> 4) + j;
    wp1[idx] = f2bf(p1_w[(size_t)m * 128 + k]);
  }
  for (int idx = tid; idx < 128 * 512; idx += stride) {
    int j = idx & 7, lane = (idx >> 3) & 63;
    int f = idx >> 9;
    int mt = f >> 3, kt = f & 7;
    int m = 16 * mt + (lane & 15);
    int k = 32 * kt + 8 * (lane >> 4) + j;
    wp2[idx] = f2bf(p2_w[(size_t)m * 256 + k]);
  }
  // condA[u][f=mt*5+kt][512] -- linear index = write-contiguous
  for (int idx = tid; idx < 25 * 512 * 256; idx += stride) {
    int q = idx & 511;
    int f = (idx >> 9) % 25;
    int u = idx / (25 * 512);
    int j = q & 7, lane = q >> 3;
    int mt = f / 5, kt = f % 5;
    int m = 16 * mt + (lane & 15);
    int k = 32 * kt + 8 * (lane >> 4) + j;
    int ci = (k < 80) ? k : k - 80;
    int kk = (k < 80) ? (255 - u) : (511 - u);
    condA[idx] = f2bf(mel_w[((size_t)m * 80 + ci) * 512 + kk]);
  }
  for (int idx = tid; idx < NBLK * 128; idx += stride)
    zb[idx] = dil_b[idx] + cond_b[idx];
  for (int idx = tid; idx < 128; idx += stride) {
    float s = 0.f;
    for (int i2 = 0; i2 < NBLK; ++i2) s += skip_b[i2 * 128 + idx];
    sbs[idx] = s;
  }
}

// ---- mel upsample MFMA; writes cond t-major [b][TP][96] bf16 ----
#define BSTR 168
__global__ __launch_bounds__(256) void cond_mfma(
    const float* __restrict__ mels, const ushort* __restrict__ condA,
    const float* __restrict__ mel_b, ushort* __restrict__ condb) {
  __shared__ ushort BT[128 * BSTR];
  const int tid = threadIdx.x;
  const int lane = tid & 63;
  const int w = tid >> 6;
  const int b = blockIdx.y;
  const int half = blockIdx.z;
  const int u = blockIdx.x * 4 + w;
  const int q4 = 4 * (lane >> 4);
  const int l15 = lane & 15;
  const float* melb = mels + (size_t)b * NMEL * FRAMES;
  for (int idx = tid; idx < 160 * 128; idx += 256) {
    int M = idx & 127;
    int k = idx >> 7;
    int ci = (k < 80) ? k : k - 80;
    int Mp = M + ((k < 80) ? 0 : 1);
    float v = (Mp < 128) ? melb[(size_t)ci * FRAMES + Mp] : 0.f;
    BT[M * BSTR + k] = f2bf(v);
  }
  __syncthreads();
  facc acc[5][4];
  #pragma unroll
  for (int mt = 0; mt < 5; ++mt) {
    #pragma unroll
    for (int nt = 0; nt < 4; ++nt) {
      #pragma unroll
      for (int r = 0; r < 4; ++r) acc[mt][nt][r] = mel_b[16 * mt + q4 + r];
    }
  }
  const ushort* cA = condA + (size_t)u * 25 * 512 + lane * 8;
  const int bofs = l15 * BSTR + 8 * (lane >> 4);
  #pragma unroll
  for (int kt = 0; kt < 5; ++kt) {
    bfrag a[5];
    #pragma unroll
    for (int mt = 0; mt < 5; ++mt) a[mt] = ldfrag(cA + (mt * 5 + kt) * 512);
    #pragma unroll
    for (int nt = 0; nt < 4; ++nt) {
      bfrag bb = ldfrag(&BT[(half * 64 + nt * 16) * BSTR + bofs + kt * 32]);
      #pragma unroll
      for (int mt = 0; mt < 5; ++mt) acc[mt][nt] = MFMA16(a[mt], bb, acc[mt][nt]);
    }
  }
  ushort* cbp = condb + (size_t)b * TP * 96;
  #pragma unroll
  for (int mt = 0; mt < 5; ++mt) {
    #pragma unroll
    for (int nt = 0; nt < 4; ++nt) {
      const int M = half * 64 + nt * 16 + l15;
      if (M < 127) {
        us4v p;
        #pragma unroll
        for (int r = 0; r < 4; ++r) p[r] = f2bf(acc[mt][nt][r]);
        const int t = M * 256 + u;
        *reinterpret_cast<us4v*>(&cbp[(size_t)(t + PAD) * 96 + 16 * mt + q4]) = p;
      }
    }
  }
}

// ---- init: res_0 fp32 + bf16, t-major rows [PAD, PAD+T) ----
__global__ __launch_bounds__(256) void init_res_kernel(
    const float* __restrict__ x, const float* __restrict__ iw,
    const float* __restrict__ ib, float* __restrict__ resf0,
    ushort* __restrict__ resh0) {
  int idx = blockIdx.x * blockDim.x + threadIdx.x;
  if (idx >= BATCH * T_LEN * 64) return;
  int c = idx & 63;
  int t = (idx >> 6) % T_LEN;
  int b = idx / (64 * T_LEN);
  float v = x[(size_t)b * T_LEN + t] * iw[c] + ib[c];
  size_t o = (size_t)b * TP * 64 + (size_t)(t + PAD) * 64 + c;
  resf0[o] = v;
  resh0[o] = f2bf(v);
}

// ============ pair kernel v5: wave-independent (ZERO barriers) ============
// Each wave owns 16 t positions x ALL 128 m. h / res redistribution via
// wave-PRIVATE XOR-swizzled LDS tiles; in-wave lgkmcnt ordering only.
template <int DEFER>
__global__ __launch_bounds__(256, 4) void wn_pair_kernel(
    const float* __restrict__ resf_in, float* __restrict__ resf_out,
    const ushort* __restrict__ resh_in, ushort* __restrict__ resh_out,
    const ushort* __restrict__ condb, const ushort* __restrict__ wa,
    const ushort* __restrict__ wsf, const ushort* __restrict__ wrf,
    const float* __restrict__ zb, const float* __restrict__ res_b,
    const float* __restrict__ skip_b, float* __restrict__ skipg,
    ushort* __restrict__ hb0, ushort* __restrict__ hb1, int i0, int d0,
    int writeRes) {
  // per-wave private: HT (16x64 h), RTs, RTh (16x64 res bf16) -- 2KB each
  __shared__ ushort SW[4 * 3 * 1024];
  const int i1 = i0 + 1;
  const int d1 = 2 * d0;
  const int tid = threadIdx.x;
  const int lane = tid & 63;
  const int w = tid >> 6;
  const int l15 = lane & 15;
  const int g = lane >> 4;
  const int q4 = 4 * g;
  const int colq = 8 * g;
  // bijective XCD swizzle (508 = 8*63+4)
  const int orig = blockIdx.x;
  const int xcd = orig & 7;
  const int loc = orig >> 3;
  const int tile = (xcd < 4 ? xcd * 64 : 256 + (xcd - 4) * 63) + loc;
  const int b = blockIdx.y;
  const int tg = tile * 64 + w * 16 + l15;  // this lane's home t
  const int tgs = tg - d1;                  // shifted t

  const float* rfi = resf_in + (size_t)b * TP * 64;
  float* rfo = resf_out + (size_t)b * TP * 64;
  const ushort* rhi = resh_in + (size_t)b * TP * 64;
  ushort* rho = resh_out + (size_t)b * TP * 64;
  const ushort* cbp = condb + (size_t)b * TP * 96;

  char* HTw  = (char*)(SW + w * 3072);
  char* RTsw = (char*)(SW + w * 3072 + 1024);
  char* RThw = (char*)(SW + w * 3072 + 2048);
  const int sw = (l15 & 7) << 4;                 // XOR swizzle (16B units)
  const int rowb = l15 * 128;                    // row byte base
  // B-frag read offsets (16B) and gate-write offsets (8B), swizzled:
  // read  kt: (rowb + kt*64 + g*16) ^ sw
  // write mt: (rowb + mt*32 + g*8) ^ sw

  facc za[8], rsh[4], rs[4], sk[8];
  if constexpr (!DEFER) {
    #pragma unroll
    for (int mt = 0; mt < 8; ++mt) {
      #pragma unroll
      for (int r = 0; r < 4; ++r)
        sk[mt][r] = skip_b[i0 * 128 + 16 * mt + q4 + r] +
                    skip_b[i1 * 128 + 16 * mt + q4 + r];
    }
  }

#define ZG_GLOBAL(LAYER, TGL)                                                 \
  {                                                                           \
    _Pragma("unroll")                                                         \
    for (int mt = 0; mt < 8; ++mt)                                            \
      za[mt] = *(const facc*)(zb + (LAYER) * 128 + 16 * mt + q4);             \
    const ushort* wal = wa + (size_t)(LAYER) * 56 * 512 + lane * 8;           \
    const ushort* b0 = rhi + (size_t)((TGL) - d0 + PAD) * 64 + colq;          \
    const ushort* b1 = rhi + (size_t)((TGL) + PAD) * 64 + colq;               \
    const ushort* bc = cbp + (size_t)((TGL) + PAD) * 96 + colq;               \
    _Pragma("unroll")                                                         \
    for (int kt = 0; kt < 7; ++kt) {                                          \
      bfrag bb = (kt < 2)   ? ldfrag(b0 + kt * 32)                            \
                 : (kt < 4) ? ldfrag(b1 + (kt - 2) * 32)                      \
                            : ldfrag(bc + (kt - 4) * 32);                     \
      _Pragma("unroll")                                                       \
      for (int mt = 0; mt < 8; ++mt)                                          \
        za[mt] = MFMA16(ldfrag(wal + (mt * 7 + kt) * 512), bb, za[mt]);       \
    }                                                                         \
  }

#define ZG_LDS(LAYER)                                                         \
  {                                                                           \
    _Pragma("unroll")                                                         \
    for (int mt = 0; mt < 8; ++mt)                                            \
      za[mt] = *(const facc*)(zb + (LAYER) * 128 + 16 * mt + q4);             \
    const ushort* wal = wa + (size_t)(LAYER) * 56 * 512 + lane * 8;           \
    const ushort* bc = cbp + (size_t)(tg + PAD) * 96 + colq;                  \
    _Pragma("unroll")                                                         \
    for (int kt = 0; kt < 7; ++kt) {                                          \
      bfrag bb =                                                              \
          (kt < 2)                                                            \
              ? ldfrag((const ushort*)(RTsw + ((rowb + kt * 64 + g * 16) ^ sw))) \
              : (kt < 4) ? ldfrag((const ushort*)(                            \
                               RThw + ((rowb + (kt - 2) * 64 + g * 16) ^ sw))) \
                         : ldfrag(bc + (kt - 4) * 32);                        \
      _Pragma("unroll")                                                       \
      for (int mt = 0; mt < 8; ++mt)                                          \
        za[mt] = MFMA16(ldfrag(wal + (mt * 7 + kt) * 512), bb, za[mt]);       \
    }                                                                         \
  }

#define GATE(HBPTR, DOHB)                                                     \
  {                                                                           \
    _Pragma("unroll")                                                         \
    for (int mt = 0; mt < 4; ++mt) {                                          \
      us4v p;                                                                 \
      _Pragma("unroll")                                                       \
      for (int r = 0; r < 4; ++r)                                             \
        p[r] = f2bf(tanhf_(za[mt][r]) * sigmoidf_(za[mt + 4][r]));            \
      *reinterpret_cast<us4v*>(HTw + ((rowb + mt * 32 + g * 8) ^ sw)) = p;    \
      if (DOHB)                                                               \
        *reinterpret_cast<us4v*>((HBPTR) + (size_t)b * T_LEN * 64 +           \
                                 (size_t)tg * 64 + 16 * mt + q4) = p;         \
    }                                                                         \
  }

#define RES_GEMM(LAYER, RS)                                                   \
  {                                                                           \
    const ushort* wrl = wrf + (size_t)(LAYER) * 8 * 512 + lane * 8;           \
    _Pragma("unroll")                                                         \
    for (int kt = 0; kt < 2; ++kt) {                                          \
      bfrag bb =                                                              \
          ldfrag((const ushort*)(HTw + ((rowb + kt * 64 + g * 16) ^ sw)));    \
      _Pragma("unroll")                                                       \
      for (int mt = 0; mt < 4; ++mt)                                          \
        RS[mt] = MFMA16(ldfrag(wrl + (mt * 2 + kt) * 512), bb, RS[mt]);       \
    }                                                                         \
  }

#define SKIP_GEMM(LAYER)                                                      \
  {                                                                           \
    const ushort* wsl = wsf + (size_t)(LAYER) * 16 * 512 + lane * 8;          \
    _Pragma("unroll")                                                         \
    for (int kt = 0; kt < 2; ++kt) {                                          \
      bfrag bb =                                                              \
          ldfrag((const ushort*)(HTw + ((rowb + kt * 64 + g * 16) ^ sw)));    \
      _Pragma("unroll")                                                       \
      for (int mt = 0; mt < 8; ++mt)                                          \
        sk[mt] = MFMA16(ldfrag(wsl + (mt * 2 + kt) * 512), bb, sk[mt]);       \
    }                                                                         \
  }

  // ===== phase 1: layer i0 @ shifted (t = tg - d1) =====
  ZG_GLOBAL(i0, tgs);
  GATE(hb0, 0);
  #pragma unroll
  for (int mt = 0; mt < 4; ++mt) {
    us4v hv = *(const us4v*)(rhi + (size_t)(tgs + PAD) * 64 + 16 * mt + q4);
    #pragma unroll
    for (int r = 0; r < 4; ++r)
      rs[mt][r] = bf2f(hv[r]) + res_b[i0 * 64 + 16 * mt + q4 + r];
  }
  RES_GEMM(i0, rs);
  {
    const bool ok = tgs >= 0;
    #pragma unroll
    for (int mt = 0; mt < 4; ++mt) {
      us4v p;
      #pragma unroll
      for (int r = 0; r < 4; ++r) p[r] = ok ? f2bf(rs[mt][r]) : (ushort)0;
      *reinterpret_cast<us4v*>(RTsw + ((rowb + mt * 32 + g * 8) ^ sw)) = p;
    }
  }
  // ===== phase 2: layer i0 @ home =====
  ZG_GLOBAL(i0, tg);
  GATE(hb0, DEFER);
  #pragma unroll
  for (int mt = 0; mt < 4; ++mt) {
    facc v = *(const facc*)(rfi + (size_t)(tg + PAD) * 64 + 16 * mt + q4);
    #pragma unroll
    for (int r = 0; r < 4; ++r)
      rsh[mt][r] = v[r] + res_b[i0 * 64 + 16 * mt + q4 + r];
  }
  if constexpr (!DEFER) { SKIP_GEMM(i0); }
  RES_GEMM(i0, rsh);
  #pragma unroll
  for (int mt = 0; mt < 4; ++mt) {
    us4v p;
    #pragma unroll
    for (int r = 0; r < 4; ++r) p[r] = f2bf(rsh[mt][r]);
    *reinterpret_cast<us4v*>(RThw + ((rowb + mt * 32 + g * 8) ^ sw)) = p;
  }
  // ===== phase 3: layer i1 @ home (taps from RTs/RTh) =====
  ZG_LDS(i1);
  GATE(hb1, DEFER);
  #pragma unroll
  for (int mt = 0; mt < 4; ++mt) {
    #pragma unroll
    for (int r = 0; r < 4; ++r)
      rs[mt][r] = rsh[mt][r] + res_b[i1 * 64 + 16 * mt + q4 + r];
  }
  if constexpr (!DEFER) { SKIP_GEMM(i1); }
  RES_GEMM(i1, rs);
  // ===== epilogue =====
  if (writeRes) {
    #pragma unroll
    for (int mt = 0; mt < 4; ++mt) {
      *(facc*)(rfo + (size_t)(tg + PAD) * 64 + 16 * mt + q4) = rs[mt];
      us4v p;
      #pragma unroll
      for (int r = 0; r < 4; ++r) p[r] = f2bf(rs[mt][r]);
      *reinterpret_cast<us4v*>(rho + (size_t)(tg + PAD) * 64 + 16 * mt + q4) = p;
    }
  }
  if constexpr (!DEFER) {
    float* sg = skipg + (size_t)b * T_LEN * 128 + (size_t)tg * 128;
    #pragma unroll
    for (int mt = 0; mt < 8; ++mt) {
      facc* p0 = (facc*)(sg + 16 * mt + q4);
      *p0 = *p0 + sk[mt];
    }
  }
#undef ZG_GLOBAL
#undef ZG_LDS
#undef GATE
#undef RES_GEMM
#undef SKIP_GEMM
}

// ---- skip_accum v3: LDS-staged h, 32-t blocks; optional fused post1 ----
template <int FIRST, int FUSE>
__global__ __launch_bounds__(256) void skip_accum(
    const ushort* __restrict__ hb, const ushort* __restrict__ wsf,
    float* __restrict__ skipg, const float* __restrict__ sbs,
    const ushort* __restrict__ wp1, const float* __restrict__ p1b,
    ushort* __restrict__ y1r, int base, int nl) {
  __shared__ ushort HL[12 * 2048];
  const int tid = threadIdx.x;
  const int lane = tid & 63;
  const int w = tid >> 6;
  const int l15 = lane & 15;
  const int q4 = 4 * (lane >> 4);
  const int colq = 8 * (lane >> 4);
  const int t0 = blockIdx.x * 32;
  const int b = blockIdx.y;

  {
    const int D = tid * 16;
    const int Dsw = D ^ (((D >> 7) & 7) << 4);
    const char* srcb =
        (const char*)(hb + (size_t)b * T_LEN * 64 + (size_t)t0 * 64);
    char* ldsb = (char*)HL + (tid >> 6) * 1024;
    for (int l = 0; l < nl; ++l)
      gload_lds16(srcb + (size_t)l * SLOT_BYTES + Dsw, ldsb + l * 4096);
  }

  float* sg = skipg + (size_t)b * T_LEN * 128;
  facc a0[2], a1[2];
  if constexpr (FIRST) {
    #pragma unroll
    for (int nt = 0; nt < 2; ++nt) {
      #pragma unroll
      for (int r = 0; r < 4; ++r) { a0[nt][r] = 0.f; a1[nt][r] = 0.f; }
    }
  } else {
    #pragma unroll
    for (int nt = 0; nt < 2; ++nt) {
      const int tg = t0 + nt * 16 + l15;
      a0[nt] = *(const facc*)(sg + (size_t)tg * 128 + 32 * w + q4);
      a1[nt] = *(const facc*)(sg + (size_t)tg * 128 + 32 * w + 16 + q4);
    }
  }
  __syncthreads();

  for (int l = 0; l < nl; ++l) {
    const ushort* wsl = wsf + (size_t)(base + l) * 16 * 512 + lane * 8;
    #pragma unroll
    for (int kt = 0; kt < 2; ++kt) {
      bfrag f0 = ldfrag(wsl + ((2 * w) * 2 + kt) * 512);
      bfrag f1 = ldfrag(wsl + ((2 * w + 1) * 2 + kt) * 512);
      #pragma unroll
      for (int nt = 0; nt < 2; ++nt) {
        const int t = nt * 16 + l15;
        int byteoff = t * 128 + kt * 64 + colq * 2;
        byteoff ^= ((t & 7) << 4);
        bfrag bb = ldfrag((const ushort*)((const char*)HL + l * 4096 + byteoff));
        a0[nt] = MFMA16(f0, bb, a0[nt]);
        a1[nt] = MFMA16(f1, bb, a1[nt]);
      }
    }
  }

  if constexpr (!FUSE) {
    #pragma unroll
    for (int nt = 0; nt < 2; ++nt) {
      const int tg = t0 + nt * 16 + l15;
      *(facc*)(sg + (size_t)tg * 128 + 32 * w + q4) = a0[nt];
      *(facc*)(sg + (size_t)tg * 128 + 32 * w + 16 + q4) = a1[nt];
    }
  } else {
    __syncthreads();
    ushort* ST = HL;
    #pragma unroll
    for (int nt = 0; nt < 2; ++nt) {
      us4v p0, p1;
      #pragma unroll
      for (int r = 0; r < 4; ++r) {
        p0[r] = f2bf(fmaxf(a0[nt][r] + sbs[32 * w + q4 + r], 0.f));
        p1[r] = f2bf(fmaxf(a1[nt][r] + sbs[32 * w + 16 + q4 + r], 0.f));
      }
      const int row = nt * 16 + l15;
      *reinterpret_cast<us4v*>(&ST[row * 136 + 32 * w + q4]) = p0;
      *reinterpret_cast<us4v*>(&ST[row * 136 + 32 * w + 16 + q4]) = p1;
    }
    __syncthreads();
    facc acc2[4][2];
    #pragma unroll
    for (int mi = 0; mi < 4; ++mi) {
      #pragma unroll
      for (int nt = 0; nt < 2; ++nt) {
        #pragma unroll
        for (int r = 0; r < 4; ++r)
          acc2[mi][nt][r] = p1b[16 * (4 * w + mi) + q4 + r];
      }
    }
    const int lo = lane * 8;
    #pragma unroll
    for (int kt = 0; kt < 4; ++kt) {
      bfrag am[4];
      #pragma unroll
      for (int mi = 0; mi < 4; ++mi)
        am[mi] = ldfrag(wp1 + ((4 * w + mi) * 4 + kt) * 512 + lo);
      #pragma unroll
      for (int nt = 0; nt < 2; ++nt) {
        bfrag bb = ldfrag(&ST[(nt * 16 + l15) * 136 + kt * 32 + colq]);
        #pragma unroll
        for (int mi = 0; mi < 4; ++mi)
          acc2[mi][nt] = MFMA16(am[mi], bb, acc2[mi][nt]);
      }
    }
    ushort* yb = y1r + (size_t)b * 256 * T_LEN;
    #pragma unroll
    for (int mi = 0; mi < 4; ++mi) {
      #pragma unroll
      for (int nt = 0; nt < 2; ++nt) {
        const int tt = t0 + nt * 16 + l15;
        #pragma unroll
        for (int r = 0; r < 4; ++r)
          yb[(size_t)(16 * (4 * w + mi) + q4 + r) * T_LEN + tt] =
              f2bf(fmaxf(acc2[mi][nt][r], 0.f));
      }
    }
  }
}

// ---- standalone post1 (non-defer fallback only; sbs may be null) ----
#define FSSTR 136
__global__ __launch_bounds__(256) void post1_mfma(
    const float* __restrict__ skipg, const float* __restrict__ sbs,
    const ushort* __restrict__ wp1, const float* __restrict__ p1b,
    ushort* __restrict__ y1r) {
  __shared__ ushort ST[64 * FSSTR];
  const int tid = threadIdx.x;
  const int lane = tid & 63;
  const int w = tid >> 6;
  const int t0 = blockIdx.x * 64;
  const int b = blockIdx.y;
  {
    const int t = tid & 63;
    const int kc = tid >> 6;
    const float* sp =
        skipg + (size_t)b * T_LEN * 128 + (size_t)(t0 + t) * 128 + kc * 32;
    #pragma unroll
    for (int j = 0; j < 8; ++j) {
      facc v = *(const facc*)(sp + j * 4);
      us4v o;
      #pragma unroll
      for (int r = 0; r < 4; ++r) {
        float s = sbs ? sbs[kc * 32 + j * 4 + r] : 0.f;
        o[r] = f2bf(fmaxf(v[r] + s, 0.f));
      }
      *reinterpret_cast<us4v*>(&ST[t * FSSTR + kc * 32 + j * 4]) = o;
    }
  }
  __syncthreads();
  const int q4 = 4 * (lane >> 4);
  facc acc[4][4];
  #pragma unroll
  for (int mi = 0; mi < 4; ++mi) {
    #pragma unroll
    for (int nt = 0; nt < 4; ++nt) {
      #pragma unroll
      for (int r = 0; r < 4; ++r)
        acc[mi][nt][r] = p1b[16 * (4 * w + mi) + q4 + r];
    }
  }
  const int lo = lane * 8;
  const int bofs = (lane & 15) * FSSTR + 8 * (lane >> 4);
  #pragma unroll
  for (int kt = 0; kt < 4; ++kt) {
    bfrag a[4];
    #pragma unroll
    for (int mi = 0; mi < 4; ++mi)
      a[mi] = ldfrag(wp1 + ((4 * w + mi) * 4 + kt) * 512 + lo);
    #pragma unroll
    for (int nt = 0; nt < 4; ++nt) {
      bfrag bb = ldfrag(&ST[nt * 16 * FSSTR + bofs + kt * 32]);
      #pragma unroll
      for (int mi = 0; mi < 4; ++mi) acc[mi][nt] = MFMA16(a[mi], bb, acc[mi][nt]);
    }
  }
  ushort* yb = y1r + (size_t)b * 256 * T_LEN;
  #pragma unroll
  for (int mi = 0; mi < 4; ++mi) {
    #pragma unroll
    for (int nt = 0; nt < 4; ++nt) {
      const int tt = t0 + nt * 16 + (lane & 15);
      #pragma unroll
      for (int r = 0; r < 4; ++r)
        yb[(size_t)(16 * (4 * w + mi) + q4 + r) * T_LEN + tt] =
            f2bf(fmaxf(acc[mi][nt][r], 0.f));
    }
  }
}

// ---- post2: out = p2_w @ y1r + b (fp32) ----
#define YSTR 264
__global__ __launch_bounds__(256) void post2_mfma(
    const ushort* __restrict__ y1r, const ushort* __restrict__ wp2,
    const float* __restrict__ p2b, float* __restrict__ out) {
  __shared__ ushort YT[64 * YSTR];
  const int tid = threadIdx.x;
  const int lane = tid & 63;
  const int w = tid >> 6;
  const int t0 = blockIdx.x * 64;
  const int b = blockIdx.y;
  const ushort* yb = y1r + (size_t)b * 256 * T_LEN;
  const int t = t0 + lane;
  for (int kc = 0; kc < 8; ++kc) {
    int k0 = w * 64 + kc * 8;
    us8v v;
    #pragma unroll
    for (int j = 0; j < 8; ++j) v[j] = yb[(size_t)(k0 + j) * T_LEN + t];
    *reinterpret_cast<us8v*>(&YT[lane * YSTR + k0]) = v;
  }
  __syncthreads();
  const int q4 = 4 * (lane >> 4);
  facc acc[4][4];
  #pragma unroll
  for (int mi = 0; mi < 4; ++mi) {
    #pragma unroll
    for (int nt = 0; nt < 4; ++nt) {
      #pragma unroll
      for (int r = 0; r < 4; ++r)
        acc[mi][nt][r] = p2b[16 * (4 * w + mi) + q4 + r];
    }
  }
  const int lo = lane * 8;
  const int bofs = (lane & 15) * YSTR + 8 * (lane >> 4);
  #pragma unroll
  for (int kt = 0; kt < 8; ++kt) {
    bfrag a[4];
    #pragma unroll
    for (int mi = 0; mi < 4; ++mi)
      a[mi] = ldfrag(wp2 + ((4 * w + mi) * 8 + kt) * 512 + lo);
    #pragma unroll
    for (int nt = 0; nt < 4; ++nt) {
      bfrag bb = ldfrag(&YT[nt * 16 * YSTR + bofs + kt * 32]);
      #pragma unroll
      for (int mi = 0; mi < 4; ++mi) acc[mi][nt] = MFMA16(a[mi], bb, acc[mi][nt]);
    }
  }
  float* ob = out + (size_t)b * 256 * T_LEN;
  #pragma unroll
  for (int mi = 0; mi < 4; ++mi) {
    #pragma unroll
    for (int nt = 0; nt < 4; ++nt) {
      const int tt = t0 + nt * 16 + (lane & 15);
      #pragma unroll
      for (int r = 0; r < 4; ++r)
        ob[(size_t)(16 * (4 * w + mi) + q4 + r) * T_LEN + tt] = acc[mi][nt][r];
    }
  }
}

extern "C" void kernel_launch(void* const* d_in, const int* in_sizes, int n_in,
                              void* d_out, int out_size, void* d_ws,
                              size_t ws_size, hipStream_t stream) {
  const float* x       = (const float*)d_in[0];
  const float* mels    = (const float*)d_in[1];
  const float* input_w = (const float*)d_in[2];
  const float* input_b = (const float*)d_in[3];
  const float* mel_w   = (const float*)d_in[4];
  const float* mel_b   = (const float*)d_in[5];
  const float* dil_w   = (const float*)d_in[6];
  const float* dil_b   = (const float*)d_in[7];
  const float* cond_w  = (const float*)d_in[8];
  const float* cond_b  = (const float*)d_in[9];
  const float* skip_w  = (const float*)d_in[10];
  const float* skip_b  = (const float*)d_in[11];
  const float* res_w   = (const float*)d_in[12];
  const float* res_b   = (const float*)d_in[13];
  const float* p1_w    = (const float*)d_in[14];
  const float* p1_b    = (const float*)d_in[15];
  const float* p2_w    = (const float*)d_in[16];
  const float* p2_b    = (const float*)d_in[17];

  char* ws = (char*)d_ws;
  float* rfA    = (float*)(ws + RESF_OFF);
  float* rfB    = rfA + (size_t)2 * TP * 64;
  ushort* rhA   = (ushort*)(ws + RESH_OFF);
  ushort* rhB   = rhA + (size_t)2 * TP * 64;
  ushort* condb = (ushort*)(ws + CONDB_OFF);
  ushort* wa    = (ushort*)(ws + WA_OFF);
  ushort* wsf   = (ushort*)(ws + WSF_OFF);
  ushort* wrf   = (ushort*)(ws + WRF_OFF);
  ushort* wp1   = (ushort*)(ws + WP1_OFF);
  ushort* wp2   = (ushort*)(ws + WP2_OFF);
  float* zbp    = (float*)(ws + ZB_OFF);
  float* sbsp   = (float*)(ws + SBS_OFF);
  float* skipg  = (float*)(ws + SKIPG_OFF);
  ushort* condA = (ushort*)(ws + CONDA_OFF);
  ushort* hbuf  = (ushort*)(ws + HB_OFF);
  ushort* y1rp  = (ushort*)(ws + Y1R_OFF);
  float* out    = (float*)d_out;

  int G = 0;
  if (ws_size >= (size_t)HB_OFF + 12ull * SLOT_BYTES) {
    G = 6;
  } else if (ws_size >= (size_t)HB_OFF + 2ull * SLOT_BYTES) {
    G = (int)((ws_size - HB_OFF) / (2ull * SLOT_BYTES));
    if (G > 6) G = 6;
  }
  const bool defer = (G >= 1);

  for (int k = 0; k < 2; ++k)
    for (int b = 0; b < 2; ++b) {
      hipMemsetAsync((char*)(k == 0 ? rfA : rfB) + (size_t)b * TP * 64 * 4, 0,
                     (size_t)PAD * 64 * 4, stream);
      hipMemsetAsync((char*)(k == 0 ? rhA : rhB) + (size_t)b * TP * 64 * 2, 0,
                     (size_t)PAD * 64 * 2, stream);
    }
  hipMemsetAsync(condb, 0, (size_t)2 * TP * 96 * 2, stream);

  prep_kernel<<<2048, 256, 0, stream>>>(dil_w, cond_w, skip_w, res_w, p1_w,
                                        p2_w, mel_w, dil_b, cond_b, skip_b, wa,
                                        wsf, wrf, wp1, wp2, condA, zbp, sbsp);
  cond_mfma<<<dim3(64, BATCH, 2), 256, 0, stream>>>(mels, condA, mel_b, condb);
  if (!defer) {
    hipMemsetAsync(skipg, 0, (size_t)2 * T_LEN * 128 * 4, stream);
  }
  init_res_kernel<<<(BATCH * T_LEN * 64 + 255) / 256, 256, 0, stream>>>(
      x, input_w, input_b, rfA, rhA);

  float* rfi = rfA;
  float* rfo = rfB;
  ushort* rhi = rhA;
  ushort* rho = rhB;
  int groupStart = 0;
  const dim3 ag(T_LEN / 32, BATCH);
  for (int p = 0; p < NPAIRS; ++p) {
    int i0 = 2 * p;
    int d0 = 1 << (i0 % 10);
    int wr = (p < NPAIRS - 1) ? 1 : 0;
    if (defer) {
      ushort* h0 = hbuf + (size_t)(2 * (p - groupStart)) * SLOT_ELEMS;
      wn_pair_kernel<1><<<dim3(NTILES, BATCH), 256, 0, stream>>>(
          rfi, rfo, rhi, rho, condb, wa, wsf, wrf, zbp, res_b, skip_b, skipg,
          h0, h0 + SLOT_ELEMS, i0, d0, wr);
      if (p - groupStart + 1 == G || p == NPAIRS - 1) {
        int nl = 2 * (p - groupStart + 1);
        int base = 2 * groupStart;
        bool isF = (groupStart == 0);
        bool isL = (p == NPAIRS - 1);
        if (isF && isL)
          skip_accum<1, 1><<<ag, 256, 0, stream>>>(hbuf, wsf, skipg, sbsp, wp1,
                                                   p1_b, y1rp, base, nl);
        else if (isF)
          skip_accum<1, 0><<<ag, 256, 0, stream>>>(hbuf, wsf, skipg, sbsp, wp1,
                                                   p1_b, y1rp, base, nl);
        else if (isL)
          skip_accum<0, 1><<<ag, 256, 0, stream>>>(hbuf, wsf, skipg, sbsp, wp1,
                                                   p1_b, y1rp, base, nl);
        else
          skip_accum<0, 0><<<ag, 256, 0, stream>>>(hbuf, wsf, skipg, sbsp, wp1,
                                                   p1_b, y1rp, base, nl);
        groupStart = p + 1;
      }
    } else {
      wn_pair_kernel<0><<<dim3(NTILES, BATCH), 256, 0, stream>>>(
          rfi, rfo, rhi, rho, condb, wa, wsf, wrf, zbp, res_b, skip_b, skipg,
          nullptr, nullptr, i0, d0, wr);
    }
    float* tf = rfi; rfi = rfo; rfo = tf;
    ushort* th = rhi; rhi = rho; rho = th;
  }

  if (!defer) {
    post1_mfma<<<dim3(NTILES, BATCH), 256, 0, stream>>>(skipg, nullptr, wp1,
                                                        p1_b, y1rp);
  }
  post2_mfma<<<dim3(NTILES, BATCH), 256, 0, stream>>>(y1rp, wp2, p2_b, out);
}

// Round 11
// 848.455 us; speedup vs baseline: 1.2884x; 1.2782x over previous
//
#include <hip/hip_runtime.h>
#include <math.h>

#define T_LEN 32512
#define NTILES 508
#define BATCH 2
#define NMEL 80
#define FRAMES 128
#define NBLK 30
#define NPAIRS 15
#define PAD 768
#define TP (T_LEN + PAD)  // 33280

typedef short bfrag __attribute__((ext_vector_type(8)));
typedef float facc __attribute__((ext_vector_type(4)));
typedef ushort us4v __attribute__((ext_vector_type(4)));
typedef ushort us8v __attribute__((ext_vector_type(8)));

#define MFMA16(a, b, c) __builtin_amdgcn_mfma_f32_16x16x32_bf16((a), (b), (c), 0, 0, 0)

// ---- workspace layout (byte offsets) ----
#define RESH_OFF   0u          // bf16 [2buf][2b][TP][64] = 17,039,360
#define CONDB_OFF  17039360u   // bf16 [2b][TP][96]       = 12,779,520
#define WA_OFF     29818880u   // bf16 30*56*512
#define WSF_OFF    31539200u   // bf16 30*16*512
#define WRF_OFF    32030720u   // bf16 30*8*512
#define WP1_OFF    32276480u   // bf16 64*512
#define WP2_OFF    32342016u   // bf16 128*512
#define ZB_OFF     32473088u   // f32 30*128
#define SBS_OFF    32488448u   // f32 128
#define SKIPG_OFF  32488960u   // f32 [2b][T][128] = 33,292,288
#define CONDA_OFF  SKIPG_OFF   // condA aliased (dead before first skip_accum)
#define HB_OFF     65781248u   // bf16 h slots: [slot][2b][T][64]
#define SLOT_BYTES 8323072ull
#define SLOT_ELEMS 4161536ull
#define Y1R_OFF    82427392u   // bf16 [2b][256][T] = 33,292,288  (after 2 slots)
// Y1R placed after HB_OFF + 2 slots min; with 12 slots HB ends at 165,658,112.
// To be safe Y1R gets its own region AFTER max HB usage:
#undef Y1R_OFF
#define Y1R_OFF    165658112u  // bf16 [2b][256][T] = 33,292,288; total ~199 MB

static __device__ __forceinline__ ushort f2bf(float f) {
  union { float f; unsigned int u; } v;
  v.f = f;
  unsigned int r = (v.u + 0x7FFFu + ((v.u >> 16) & 1u)) >> 16;
  return (ushort)r;
}
static __device__ __forceinline__ float bf2f(ushort h) {
  union { unsigned int u; float f; } v;
  v.u = ((unsigned int)h) << 16;
  return v.f;
}
static __device__ __forceinline__ float sigmoidf_(float x) {
  return 1.f / (1.f + __expf(-x));
}
static __device__ __forceinline__ float tanhf_(float x) {
  return 2.f / (1.f + __expf(-2.f * x)) - 1.f;
}
static __device__ __forceinline__ bfrag ldfrag(const ushort* p) {
  return *reinterpret_cast<const bfrag*>(p);
}
static __device__ __forceinline__ void gload_lds16(const void* g, void* l) {
  __builtin_amdgcn_global_load_lds(
      (const __attribute__((address_space(1))) unsigned int*)g,
      (__attribute__((address_space(3))) unsigned int*)l, 16, 0, 0);
}

// ---- prep: weights -> MFMA A-fragments; condA; zb; sbs ----
__global__ __launch_bounds__(256) void prep_kernel(
    const float* __restrict__ dil_w, const float* __restrict__ cond_w,
    const float* __restrict__ skip_w, const float* __restrict__ res_w,
    const float* __restrict__ p1_w, const float* __restrict__ p2_w,
    const float* __restrict__ mel_w, const float* __restrict__ dil_b,
    const float* __restrict__ cond_b, const float* __restrict__ skip_b,
    ushort* __restrict__ wa, ushort* __restrict__ wsf, ushort* __restrict__ wrf,
    ushort* __restrict__ wp1, ushort* __restrict__ wp2,
    ushort* __restrict__ condA, float* __restrict__ zb,
    float* __restrict__ sbs) {
  int tid = blockIdx.x * blockDim.x + threadIdx.x;
  int stride = gridDim.x * blockDim.x;
  // W_all[layer][128 m][224 k]: k<64 tap0; k<128 tap1; k<208 cond(96-pad); else 0
  for (int idx = tid; idx < NBLK * 56 * 512; idx += stride) {
    int j = idx & 7, lane = (idx >> 3) & 63;
    int f = (idx >> 9) % 56, layer = idx / (56 * 512);
    int mt = f / 7, kt = f % 7;
    int m = 16 * mt + (lane & 15);
    int k = 32 * kt + 8 * (lane >> 4) + j;
    float v;
    if (k < 64)       v = dil_w[(((size_t)layer * 128 + m) * 64 + k) * 2 + 0];
    else if (k < 128) v = dil_w[(((size_t)layer * 128 + m) * 64 + (k - 64)) * 2 + 1];
    else if (k < 208) v = cond_w[((size_t)layer * 128 + m) * 80 + (k - 128)];
    else              v = 0.f;
    wa[idx] = f2bf(v);
  }
  for (int idx = tid; idx < NBLK * 16 * 512; idx += stride) {
    int j = idx & 7, lane = (idx >> 3) & 63;
    int f = (idx >> 9) & 15, layer = idx / (16 * 512);
    int mt = f >> 1, kt = f & 1;
    int m = 16 * mt + (lane & 15);
    int k = 32 * kt + 8 * (lane >> 4) + j;
    wsf[idx] = f2bf(skip_w[((size_t)layer * 128 + m) * 64 + k]);
  }
  for (int idx = tid; idx < NBLK * 8 * 512; idx += stride) {
    int j = idx & 7, lane = (idx >> 3) & 63;
    int f = (idx >> 9) & 7, layer = idx / (8 * 512);
    int mt = f >> 1, kt = f & 1;
    int m = 16 * mt + (lane & 15);
    int k = 32 * kt + 8 * (lane >> 4) + j;
    wrf[idx] = f2bf(res_w[((size_t)layer * 64 + m) * 64 + k]);
  }
  for (int idx = tid; idx < 64 * 512; idx += stride) {
    int j = idx & 7, lane = (idx >> 3) & 63;
    int f = idx >> 9;
    int mt = f >> 2, kt = f & 3;
    int m = 16 * mt + (lane & 15);
    int k = 32 * kt + 8 * (lane >> 4) + j;
    wp1[idx] = f2bf(p1_w[(size_t)m * 128 + k]);
  }
  for (int idx = tid; idx < 128 * 512; idx += stride) {
    int j = idx & 7, lane = (idx >> 3) & 63;
    int f = idx >> 9;
    int mt = f >> 3, kt = f & 7;
    int m = 16 * mt + (lane & 15);
    int k = 32 * kt + 8 * (lane >> 4) + j;
    wp2[idx] = f2bf(p2_w[(size_t)m * 256 + k]);
  }
  // condA[u][f=mt*5+kt][512] -- linear index = write-contiguous
  for (int idx = tid; idx < 25 * 512 * 256; idx += stride) {
    int q = idx & 511;
    int f = (idx >> 9) % 25;
    int u = idx / (25 * 512);
    int j = q & 7, lane = q >> 3;
    int mt = f / 5, kt = f % 5;
    int m = 16 * mt + (lane & 15);
    int k = 32 * kt + 8 * (lane >> 4) + j;
    int ci = (k < 80) ? k : k - 80;
    int kk = (k < 80) ? (255 - u) : (511 - u);
    condA[idx] = f2bf(mel_w[((size_t)m * 80 + ci) * 512 + kk]);
  }
  for (int idx = tid; idx < NBLK * 128; idx += stride)
    zb[idx] = dil_b[idx] + cond_b[idx];
  for (int idx = tid; idx < 128; idx += stride) {
    float s = 0.f;
    for (int i2 = 0; i2 < NBLK; ++i2) s += skip_b[i2 * 128 + idx];
    sbs[idx] = s;
  }
}

// ---- mel upsample MFMA; writes cond t-major [b][TP][96] bf16 ----
#define BSTR 168
__global__ __launch_bounds__(256) void cond_mfma(
    const float* __restrict__ mels, const ushort* __restrict__ condA,
    const float* __restrict__ mel_b, ushort* __restrict__ condb) {
  __shared__ ushort BT[128 * BSTR];
  const int tid = threadIdx.x;
  const int lane = tid & 63;
  const int w = tid >> 6;
  const int b = blockIdx.y;
  const int half = blockIdx.z;
  const int u = blockIdx.x * 4 + w;
  const int q4 = 4 * (lane >> 4);
  const int l15 = lane & 15;
  const float* melb = mels + (size_t)b * NMEL * FRAMES;
  for (int idx = tid; idx < 160 * 128; idx += 256) {
    int M = idx & 127;
    int k = idx >> 7;
    int ci = (k < 80) ? k : k - 80;
    int Mp = M + ((k < 80) ? 0 : 1);
    float v = (Mp < 128) ? melb[(size_t)ci * FRAMES + Mp] : 0.f;
    BT[M * BSTR + k] = f2bf(v);
  }
  __syncthreads();
  facc acc[5][4];
  #pragma unroll
  for (int mt = 0; mt < 5; ++mt) {
    #pragma unroll
    for (int nt = 0; nt < 4; ++nt) {
      #pragma unroll
      for (int r = 0; r < 4; ++r) acc[mt][nt][r] = mel_b[16 * mt + q4 + r];
    }
  }
  const ushort* cA = condA + (size_t)u * 25 * 512 + lane * 8;
  const int bofs = l15 * BSTR + 8 * (lane >> 4);
  #pragma unroll
  for (int kt = 0; kt < 5; ++kt) {
    bfrag a[5];
    #pragma unroll
    for (int mt = 0; mt < 5; ++mt) a[mt] = ldfrag(cA + (mt * 5 + kt) * 512);
    #pragma unroll
    for (int nt = 0; nt < 4; ++nt) {
      bfrag bb = ldfrag(&BT[(half * 64 + nt * 16) * BSTR + bofs + kt * 32]);
      #pragma unroll
      for (int mt = 0; mt < 5; ++mt) acc[mt][nt] = MFMA16(a[mt], bb, acc[mt][nt]);
    }
  }
  ushort* cbp = condb + (size_t)b * TP * 96;
  #pragma unroll
  for (int mt = 0; mt < 5; ++mt) {
    #pragma unroll
    for (int nt = 0; nt < 4; ++nt) {
      const int M = half * 64 + nt * 16 + l15;
      if (M < 127) {
        us4v p;
        #pragma unroll
        for (int r = 0; r < 4; ++r) p[r] = f2bf(acc[mt][nt][r]);
        const int t = M * 256 + u;
        *reinterpret_cast<us4v*>(&cbp[(size_t)(t + PAD) * 96 + 16 * mt + q4]) = p;
      }
    }
  }
}

// ---- init: res_0 bf16 t-major rows [PAD, PAD+T) ----
__global__ __launch_bounds__(256) void init_res_kernel(
    const float* __restrict__ x, const float* __restrict__ iw,
    const float* __restrict__ ib, ushort* __restrict__ resh0) {
  int idx = blockIdx.x * blockDim.x + threadIdx.x;
  if (idx >= BATCH * T_LEN * 64) return;
  int c = idx & 63;
  int t = (idx >> 6) % T_LEN;
  int b = idx / (64 * T_LEN);
  float v = x[(size_t)b * T_LEN + t] * iw[c] + ib[c];
  resh0[(size_t)b * TP * 64 + (size_t)(t + PAD) * 64 + c] = f2bf(v);
}

// ============ pair kernel (R7 structure, bf16-only residual) ============
template <int DEFER>
__global__ __launch_bounds__(256, 4) void wn_pair_kernel(
    const ushort* __restrict__ resh_in, ushort* __restrict__ resh_out,
    const ushort* __restrict__ condb, const ushort* __restrict__ wa,
    const ushort* __restrict__ wsf, const ushort* __restrict__ wrf,
    const float* __restrict__ zb, const float* __restrict__ res_b,
    const float* __restrict__ skip_b, float* __restrict__ skipg,
    ushort* __restrict__ hb0, ushort* __restrict__ hb1, int i0, int d0,
    int writeRes) {
  __shared__ ushort HT[64 * 72];
  __shared__ ushort RTs[64 * 72];
  __shared__ ushort RTh[64 * 72];
  const int i1 = i0 + 1;
  const int d1 = 2 * d0;
  const int tid = threadIdx.x;
  const int lane = tid & 63;
  const int w = tid >> 6;
  const int l15 = lane & 15;
  const int q4 = 4 * (lane >> 4);
  const int colq = 8 * (lane >> 4);
  // bijective XCD swizzle (508 = 8*63+4)
  const int orig = blockIdx.x;
  const int xcd = orig & 7;
  const int loc = orig >> 3;
  const int tile = (xcd < 4 ? xcd * 64 : 256 + (xcd - 4) * 63) + loc;
  const int t0 = tile * 64;
  const int t0s = t0 - d1;
  const int b = blockIdx.y;

  const ushort* rhi = resh_in + (size_t)b * TP * 64;
  ushort* rho = resh_out + (size_t)b * TP * 64;
  const ushort* cbp = condb + (size_t)b * TP * 96;
  const int bofs_h = l15 * 72 + colq;

  facc rs_s[4], rs_h[4], sk[8];
  facc accF[4], accG[4];
  if constexpr (!DEFER) {
    #pragma unroll
    for (int j = 0; j < 8; ++j) {
      const int ch = 32 * w + 16 * (j >> 2) + q4;
      facc s0 = *(const facc*)(skip_b + i0 * 128 + ch);
      facc s1 = *(const facc*)(skip_b + i1 * 128 + ch);
      sk[j] = s0 + s1;
    }
  }

#define ZG_INITB(LAYER)                                                       \
  _Pragma("unroll")                                                           \
  for (int nt = 0; nt < 4; ++nt) {                                            \
    accF[nt] = *(const facc*)(zb + (LAYER) * 128 + 16 * w + q4);              \
    accG[nt] = *(const facc*)(zb + (LAYER) * 128 + 64 + 16 * w + q4);         \
  }

#define ZG_GLOBAL(LAYER, TB)                                                  \
  {                                                                           \
    ZG_INITB(LAYER)                                                           \
    const ushort* wal = wa + (size_t)(LAYER) * 56 * 512 + lane * 8;           \
    const ushort* bp0[4];                                                     \
    const ushort* bp1[4];                                                     \
    const ushort* bpc[4];                                                     \
    _Pragma("unroll")                                                         \
    for (int nt = 0; nt < 4; ++nt) {                                          \
      const int tg = (TB) + nt * 16 + l15;                                    \
      bp0[nt] = rhi + (size_t)(tg - d0 + PAD) * 64 + colq;                    \
      bp1[nt] = rhi + (size_t)(tg + PAD) * 64 + colq;                         \
      bpc[nt] = cbp + (size_t)(tg + PAD) * 96 + colq;                         \
    }                                                                         \
    _Pragma("unroll")                                                         \
    for (int kt = 0; kt < 7; ++kt) {                                          \
      bfrag aF = ldfrag(wal + (w * 7 + kt) * 512);                            \
      bfrag aG = ldfrag(wal + ((w + 4) * 7 + kt) * 512);                      \
      _Pragma("unroll")                                                       \
      for (int nt = 0; nt < 4; ++nt) {                                        \
        bfrag bb = (kt < 2)   ? ldfrag(bp0[nt] + kt * 32)                     \
                   : (kt < 4) ? ldfrag(bp1[nt] + (kt - 2) * 32)               \
                              : ldfrag(bpc[nt] + (kt - 4) * 32);              \
        accF[nt] = MFMA16(aF, bb, accF[nt]);                                  \
        accG[nt] = MFMA16(aG, bb, accG[nt]);                                  \
      }                                                                       \
    }                                                                         \
  }

#define ZG_LDS(LAYER)                                                        \
  {                                                                           \
    ZG_INITB(LAYER)                                                           \
    const ushort* wal = wa + (size_t)(LAYER) * 56 * 512 + lane * 8;           \
    const ushort* bpc[4];                                                     \
    _Pragma("unroll")                                                         \
    for (int nt = 0; nt < 4; ++nt)                                            \
      bpc[nt] = cbp + (size_t)(t0 + nt * 16 + l15 + PAD) * 96 + colq;         \
    _Pragma("unroll")                                                         \
    for (int kt = 0; kt < 7; ++kt) {                                          \
      bfrag aF = ldfrag(wal + (w * 7 + kt) * 512);                            \
      bfrag aG = ldfrag(wal + ((w + 4) * 7 + kt) * 512);                      \
      _Pragma("unroll")                                                       \
      for (int nt = 0; nt < 4; ++nt) {                                        \
        bfrag bb = (kt < 2)                                                   \
            ? ldfrag(&RTs[(nt * 16 + l15) * 72 + kt * 32 + colq])             \
            : (kt < 4)                                                        \
                ? ldfrag(&RTh[(nt * 16 + l15) * 72 + (kt - 2) * 32 + colq])   \
                : ldfrag(bpc[nt] + (kt - 4) * 32);                            \
        accF[nt] = MFMA16(aF, bb, accF[nt]);                                  \
        accG[nt] = MFMA16(aG, bb, accG[nt]);                                  \
      }                                                                       \
    }                                                                         \
  }

#define GATE(HBPTR, DOHB)                                                     \
  {                                                                           \
    _Pragma("unroll")                                                         \
    for (int nt = 0; nt < 4; ++nt) {                                          \
      us4v p;                                                                 \
      _Pragma("unroll")                                                       \
      for (int r = 0; r < 4; ++r)                                             \
        p[r] = f2bf(tanhf_(accF[nt][r]) * sigmoidf_(accG[nt][r]));            \
      *reinterpret_cast<us4v*>(&HT[(nt * 16 + l15) * 72 + 16 * w + q4]) = p;  \
      if (DOHB)                                                               \
        *reinterpret_cast<us4v*>((HBPTR) + (size_t)b * T_LEN * 64 +           \
                                 (size_t)(t0 + nt * 16 + l15) * 64 +          \
                                 16 * w + q4) = p;                            \
    }                                                                         \
  }

#define RES_GEMM(LAYER, RS)                                                   \
  {                                                                           \
    const ushort* wrl = wrf + (size_t)(LAYER) * 8 * 512 + lane * 8;           \
    _Pragma("unroll")                                                         \
    for (int kt = 0; kt < 2; ++kt) {                                          \
      bfrag ar = ldfrag(wrl + (w * 2 + kt) * 512);                            \
      _Pragma("unroll")                                                       \
      for (int nt = 0; nt < 4; ++nt) {                                        \
        bfrag bb = ldfrag(&HT[nt * 16 * 72 + bofs_h + kt * 32]);              \
        RS[nt] = MFMA16(ar, bb, RS[nt]);                                      \
      }                                                                       \
    }                                                                         \
  }

#define SKIP_GEMM(LAYER)                                                      \
  {                                                                           \
    const ushort* wsl = wsf + (size_t)(LAYER) * 16 * 512 + lane * 8;          \
    _Pragma("unroll")                                                         \
    for (int kt = 0; kt < 2; ++kt) {                                          \
      bfrag a0 = ldfrag(wsl + ((2 * w) * 2 + kt) * 512);                      \
      bfrag a1 = ldfrag(wsl + ((2 * w + 1) * 2 + kt) * 512);                  \
      _Pragma("unroll")                                                       \
      for (int nt = 0; nt < 4; ++nt) {                                        \
        bfrag bb = ldfrag(&HT[nt * 16 * 72 + bofs_h + kt * 32]);              \
        sk[nt] = MFMA16(a0, bb, sk[nt]);                                      \
        sk[4 + nt] = MFMA16(a1, bb, sk[4 + nt]);                              \
      }                                                                       \
    }                                                                         \
  }

  // ===== ctx S: layer i0 @ shifted tile =====
  ZG_GLOBAL(i0, t0s);
  GATE(hb0, 0);
  __syncthreads();
  #pragma unroll
  for (int nt = 0; nt < 4; ++nt) {
    const int tg = t0s + nt * 16 + l15;
    us4v hv = *(const us4v*)(rhi + (size_t)(tg + PAD) * 64 + 16 * w + q4);
    facc rbv = *(const facc*)(res_b + i0 * 64 + 16 * w + q4);
    #pragma unroll
    for (int r = 0; r < 4; ++r) rs_s[nt][r] = bf2f(hv[r]) + rbv[r];
  }
  RES_GEMM(i0, rs_s);
  #pragma unroll
  for (int nt = 0; nt < 4; ++nt) {
    const bool ok = (t0s + nt * 16 + l15) >= 0;
    us4v p;
    #pragma unroll
    for (int r = 0; r < 4; ++r) p[r] = ok ? f2bf(rs_s[nt][r]) : (ushort)0;
    *reinterpret_cast<us4v*>(&RTs[(nt * 16 + l15) * 72 + 16 * w + q4]) = p;
  }
  __syncthreads();
  // ===== ctx H: layer i0 @ home (res base from bf16 mirror) =====
  ZG_GLOBAL(i0, t0);
  GATE(hb0, DEFER);
  __syncthreads();
  #pragma unroll
  for (int nt = 0; nt < 4; ++nt) {
    const int tg = t0 + nt * 16 + l15;
    us4v hv = *(const us4v*)(rhi + (size_t)(tg + PAD) * 64 + 16 * w + q4);
    facc rbv = *(const facc*)(res_b + i0 * 64 + 16 * w + q4);
    #pragma unroll
    for (int r = 0; r < 4; ++r) rs_h[nt][r] = bf2f(hv[r]) + rbv[r];
  }
  if constexpr (!DEFER) { SKIP_GEMM(i0); }
  RES_GEMM(i0, rs_h);
  #pragma unroll
  for (int nt = 0; nt < 4; ++nt) {
    us4v p;
    #pragma unroll
    for (int r = 0; r < 4; ++r) p[r] = f2bf(rs_h[nt][r]);
    *reinterpret_cast<us4v*>(&RTh[(nt * 16 + l15) * 72 + 16 * w + q4]) = p;
  }
  __syncthreads();
  // ===== layer i1 @ home (taps from RTs/RTh) =====
  ZG_LDS(i1);
  GATE(hb1, DEFER);
  __syncthreads();
  #pragma unroll
  for (int nt = 0; nt < 4; ++nt) {
    facc rbv = *(const facc*)(res_b + i1 * 64 + 16 * w + q4);
    rs_s[nt] = rs_h[nt] + rbv;
  }
  if constexpr (!DEFER) { SKIP_GEMM(i1); }
  RES_GEMM(i1, rs_s);
  // ===== epilogue: write bf16 residual only =====
  if (writeRes) {
    #pragma unroll
    for (int nt = 0; nt < 4; ++nt) {
      const int tg = t0 + nt * 16 + l15;
      us4v p;
      #pragma unroll
      for (int r = 0; r < 4; ++r) p[r] = f2bf(rs_s[nt][r]);
      *reinterpret_cast<us4v*>(rho + (size_t)(tg + PAD) * 64 + 16 * w + q4) = p;
    }
  }
  if constexpr (!DEFER) {
    float* sg = skipg + (size_t)b * T_LEN * 128;
    #pragma unroll
    for (int nt = 0; nt < 4; ++nt) {
      const int tg = t0 + nt * 16 + l15;
      facc* p0 = (facc*)(sg + (size_t)tg * 128 + 32 * w + q4);
      facc* p1 = (facc*)(sg + (size_t)tg * 128 + 32 * w + 16 + q4);
      *p0 = *p0 + sk[nt];
      *p1 = *p1 + sk[4 + nt];
    }
  }
#undef ZG_INITB
#undef ZG_GLOBAL
#undef ZG_LDS
#undef GATE
#undef RES_GEMM
#undef SKIP_GEMM
}

// ---- skip_accum v3: LDS-staged h, 32-t blocks; optional fused post1 ----
template <int FIRST, int FUSE>
__global__ __launch_bounds__(256) void skip_accum(
    const ushort* __restrict__ hb, const ushort* __restrict__ wsf,
    float* __restrict__ skipg, const float* __restrict__ sbs,
    const ushort* __restrict__ wp1, const float* __restrict__ p1b,
    ushort* __restrict__ y1r, int base, int nl) {
  __shared__ ushort HL[12 * 2048];
  const int tid = threadIdx.x;
  const int lane = tid & 63;
  const int w = tid >> 6;
  const int l15 = lane & 15;
  const int q4 = 4 * (lane >> 4);
  const int colq = 8 * (lane >> 4);
  const int t0 = blockIdx.x * 32;
  const int b = blockIdx.y;

  {
    const int D = tid * 16;
    const int Dsw = D ^ (((D >> 7) & 7) << 4);
    const char* srcb =
        (const char*)(hb + (size_t)b * T_LEN * 64 + (size_t)t0 * 64);
    char* ldsb = (char*)HL + (tid >> 6) * 1024;
    for (int l = 0; l < nl; ++l)
      gload_lds16(srcb + (size_t)l * SLOT_BYTES + Dsw, ldsb + l * 4096);
  }

  float* sg = skipg + (size_t)b * T_LEN * 128;
  facc a0[2], a1[2];
  if constexpr (FIRST) {
    #pragma unroll
    for (int nt = 0; nt < 2; ++nt) {
      #pragma unroll
      for (int r = 0; r < 4; ++r) { a0[nt][r] = 0.f; a1[nt][r] = 0.f; }
    }
  } else {
    #pragma unroll
    for (int nt = 0; nt < 2; ++nt) {
      const int tg = t0 + nt * 16 + l15;
      a0[nt] = *(const facc*)(sg + (size_t)tg * 128 + 32 * w + q4);
      a1[nt] = *(const facc*)(sg + (size_t)tg * 128 + 32 * w + 16 + q4);
    }
  }
  __syncthreads();

  for (int l = 0; l < nl; ++l) {
    const ushort* wsl = wsf + (size_t)(base + l) * 16 * 512 + lane * 8;
    #pragma unroll
    for (int kt = 0; kt < 2; ++kt) {
      bfrag f0 = ldfrag(wsl + ((2 * w) * 2 + kt) * 512);
      bfrag f1 = ldfrag(wsl + ((2 * w + 1) * 2 + kt) * 512);
      #pragma unroll
      for (int nt = 0; nt < 2; ++nt) {
        const int t = nt * 16 + l15;
        int byteoff = t * 128 + kt * 64 + colq * 2;
        byteoff ^= ((t & 7) << 4);
        bfrag bb = ldfrag((const ushort*)((const char*)HL + l * 4096 + byteoff));
        a0[nt] = MFMA16(f0, bb, a0[nt]);
        a1[nt] = MFMA16(f1, bb, a1[nt]);
      }
    }
  }

  if constexpr (!FUSE) {
    #pragma unroll
    for (int nt = 0; nt < 2; ++nt) {
      const int tg = t0 + nt * 16 + l15;
      *(facc*)(sg + (size_t)tg * 128 + 32 * w + q4) = a0[nt];
      *(facc*)(sg + (size_t)tg * 128 + 32 * w + 16 + q4) = a1[nt];
    }
  } else {
    __syncthreads();
    ushort* ST = HL;
    #pragma unroll
    for (int nt = 0; nt < 2; ++nt) {
      us4v p0, p1;
      #pragma unroll
      for (int r = 0; r < 4; ++r) {
        p0[r] = f2bf(fmaxf(a0[nt][r] + sbs[32 * w + q4 + r], 0.f));
        p1[r] = f2bf(fmaxf(a1[nt][r] + sbs[32 * w + 16 + q4 + r], 0.f));
      }
      const int row = nt * 16 + l15;
      *reinterpret_cast<us4v*>(&ST[row * 136 + 32 * w + q4]) = p0;
      *reinterpret_cast<us4v*>(&ST[row * 136 + 32 * w + 16 + q4]) = p1;
    }
    __syncthreads();
    facc acc2[4][2];
    #pragma unroll
    for (int mi = 0; mi < 4; ++mi) {
      #pragma unroll
      for (int nt = 0; nt < 2; ++nt) {
        #pragma unroll
        for (int r = 0; r < 4; ++r)
          acc2[mi][nt][r] = p1b[16 * (4 * w + mi) + q4 + r];
      }
    }
    const int lo = lane * 8;
    #pragma unroll
    for (int kt = 0; kt < 4; ++kt) {
      bfrag am[4];
      #pragma unroll
      for (int mi = 0; mi < 4; ++mi)
        am[mi] = ldfrag(wp1 + ((4 * w + mi) * 4 + kt) * 512 + lo);
      #pragma unroll
      for (int nt = 0; nt < 2; ++nt) {
        bfrag bb = ldfrag(&ST[(nt * 16 + l15) * 136 + kt * 32 + colq]);
        #pragma unroll
        for (int mi = 0; mi < 4; ++mi)
          acc2[mi][nt] = MFMA16(am[mi], bb, acc2[mi][nt]);
      }
    }
    ushort* yb = y1r + (size_t)b * 256 * T_LEN;
    #pragma unroll
    for (int mi = 0; mi < 4; ++mi) {
      #pragma unroll
      for (int nt = 0; nt < 2; ++nt) {
        const int tt = t0 + nt * 16 + l15;
        #pragma unroll
        for (int r = 0; r < 4; ++r)
          yb[(size_t)(16 * (4 * w + mi) + q4 + r) * T_LEN + tt] =
              f2bf(fmaxf(acc2[mi][nt][r], 0.f));
      }
    }
  }
}

// ---- standalone post1 (non-defer fallback only; sbs may be null) ----
#define FSSTR 136
__global__ __launch_bounds__(256) void post1_mfma(
    const float* __restrict__ skipg, const float* __restrict__ sbs,
    const ushort* __restrict__ wp1, const float* __restrict__ p1b,
    ushort* __restrict__ y1r) {
  __shared__ ushort ST[64 * FSSTR];
  const int tid = threadIdx.x;
  const int lane = tid & 63;
  const int w = tid >> 6;
  const int t0 = blockIdx.x * 64;
  const int b = blockIdx.y;
  {
    const int t = tid & 63;
    const int kc = tid >> 6;
    const float* sp =
        skipg + (size_t)b * T_LEN * 128 + (size_t)(t0 + t) * 128 + kc * 32;
    #pragma unroll
    for (int j = 0; j < 8; ++j) {
      facc v = *(const facc*)(sp + j * 4);
      us4v o;
      #pragma unroll
      for (int r = 0; r < 4; ++r) {
        float s = sbs ? sbs[kc * 32 + j * 4 + r] : 0.f;
        o[r] = f2bf(fmaxf(v[r] + s, 0.f));
      }
      *reinterpret_cast<us4v*>(&ST[t * FSSTR + kc * 32 + j * 4]) = o;
    }
  }
  __syncthreads();
  const int q4 = 4 * (lane >> 4);
  facc acc[4][4];
  #pragma unroll
  for (int mi = 0; mi < 4; ++mi) {
    #pragma unroll
    for (int nt = 0; nt < 4; ++nt) {
      #pragma unroll
      for (int r = 0; r < 4; ++r)
        acc[mi][nt][r] = p1b[16 * (4 * w + mi) + q4 + r];
    }
  }
  const int lo = lane * 8;
  const int bofs = (lane & 15) * FSSTR + 8 * (lane >> 4);
  #pragma unroll
  for (int kt = 0; kt < 4; ++kt) {
    bfrag a[4];
    #pragma unroll
    for (int mi = 0; mi < 4; ++mi)
      a[mi] = ldfrag(wp1 + ((4 * w + mi) * 4 + kt) * 512 + lo);
    #pragma unroll
    for (int nt = 0; nt < 4; ++nt) {
      bfrag bb = ldfrag(&ST[nt * 16 * FSSTR + bofs + kt * 32]);
      #pragma unroll
      for (int mi = 0; mi < 4; ++mi) acc[mi][nt] = MFMA16(a[mi], bb, acc[mi][nt]);
    }
  }
  ushort* yb = y1r + (size_t)b * 256 * T_LEN;
  #pragma unroll
  for (int mi = 0; mi < 4; ++mi) {
    #pragma unroll
    for (int nt = 0; nt < 4; ++nt) {
      const int tt = t0 + nt * 16 + (lane & 15);
      #pragma unroll
      for (int r = 0; r < 4; ++r)
        yb[(size_t)(16 * (4 * w + mi) + q4 + r) * T_LEN + tt] =
            f2bf(fmaxf(acc[mi][nt][r], 0.f));
    }
  }
}

// ---- post2: out = p2_w @ y1r + b (fp32) ----
#define YSTR 264
__global__ __launch_bounds__(256) void post2_mfma(
    const ushort* __restrict__ y1r, const ushort* __restrict__ wp2,
    const float* __restrict__ p2b, float* __restrict__ out) {
  __shared__ ushort YT[64 * YSTR];
  const int tid = threadIdx.x;
  const int lane = tid & 63;
  const int w = tid >> 6;
  const int t0 = blockIdx.x * 64;
  const int b = blockIdx.y;
  const ushort* yb = y1r + (size_t)b * 256 * T_LEN;
  const int t = t0 + lane;
  for (int kc = 0; kc < 8; ++kc) {
    int k0 = w * 64 + kc * 8;
    us8v v;
    #pragma unroll
    for (int j = 0; j < 8; ++j) v[j] = yb[(size_t)(k0 + j) * T_LEN + t];
    *reinterpret_cast<us8v*>(&YT[lane * YSTR + k0]) = v;
  }
  __syncthreads();
  const int q4 = 4 * (lane >> 4);
  facc acc[4][4];
  #pragma unroll
  for (int mi = 0; mi < 4; ++mi) {
    #pragma unroll
    for (int nt = 0; nt < 4; ++nt) {
      #pragma unroll
      for (int r = 0; r < 4; ++r)
        acc[mi][nt][r] = p2b[16 * (4 * w + mi) + q4 + r];
    }
  }
  const int lo = lane * 8;
  const int bofs = (lane & 15) * YSTR + 8 * (lane >> 4);
  #pragma unroll
  for (int kt = 0; kt < 8; ++kt) {
    bfrag a[4];
    #pragma unroll
    for (int mi = 0; mi < 4; ++mi)
      a[mi] = ldfrag(wp2 + ((4 * w + mi) * 8 + kt) * 512 + lo);
    #pragma unroll
    for (int nt = 0; nt < 4; ++nt) {
      bfrag bb = ldfrag(&YT[nt * 16 * YSTR + bofs + kt * 32]);
      #pragma unroll
      for (int mi = 0; mi < 4; ++mi) acc[mi][nt] = MFMA16(a[mi], bb, acc[mi][nt]);
    }
  }
  float* ob = out + (size_t)b * 256 * T_LEN;
  #pragma unroll
  for (int mi = 0; mi < 4; ++mi) {
    #pragma unroll
    for (int nt = 0; nt < 4; ++nt) {
      const int tt = t0 + nt * 16 + (lane & 15);
      #pragma unroll
      for (int r = 0; r < 4; ++r)
        ob[(size_t)(16 * (4 * w + mi) + q4 + r) * T_LEN + tt] = acc[mi][nt][r];
    }
  }
}

extern "C" void kernel_launch(void* const* d_in, const int* in_sizes, int n_in,
                              void* d_out, int out_size, void* d_ws,
                              size_t ws_size, hipStream_t stream) {
  const float* x       = (const float*)d_in[0];
  const float* mels    = (const float*)d_in[1];
  const float* input_w = (const float*)d_in[2];
  const float* input_b = (const float*)d_in[3];
  const float* mel_w   = (const float*)d_in[4];
  const float* mel_b   = (const float*)d_in[5];
  const float* dil_w   = (const float*)d_in[6];
  const float* dil_b   = (const float*)d_in[7];
  const float* cond_w  = (const float*)d_in[8];
  const float* cond_b  = (const float*)d_in[9];
  const float* skip_w  = (const float*)d_in[10];
  const float* skip_b  = (const float*)d_in[11];
  const float* res_w   = (const float*)d_in[12];
  const float* res_b   = (const float*)d_in[13];
  const float* p1_w    = (const float*)d_in[14];
  const float* p1_b    = (const float*)d_in[15];
  const float* p2_w    = (const float*)d_in[16];
  const float* p2_b    = (const float*)d_in[17];

  char* ws = (char*)d_ws;
  ushort* rhA   = (ushort*)(ws + RESH_OFF);
  ushort* rhB   = rhA + (size_t)2 * TP * 64;
  ushort* condb = (ushort*)(ws + CONDB_OFF);
  ushort* wa    = (ushort*)(ws + WA_OFF);
  ushort* wsf   = (ushort*)(ws + WSF_OFF);
  ushort* wrf   = (ushort*)(ws + WRF_OFF);
  ushort* wp1   = (ushort*)(ws + WP1_OFF);
  ushort* wp2   = (ushort*)(ws + WP2_OFF);
  float* zbp    = (float*)(ws + ZB_OFF);
  float* sbsp   = (float*)(ws + SBS_OFF);
  float* skipg  = (float*)(ws + SKIPG_OFF);
  ushort* condA = (ushort*)(ws + CONDA_OFF);
  ushort* hbuf  = (ushort*)(ws + HB_OFF);
  ushort* y1rp  = (ushort*)(ws + Y1R_OFF);
  float* out    = (float*)d_out;

  int G = 0;
  if (ws_size >= (size_t)Y1R_OFF + 33292288ull) {
    G = 6;
  } else if (ws_size >= (size_t)HB_OFF + 2ull * SLOT_BYTES + 33292288ull) {
    G = (int)((ws_size - HB_OFF - 33292288ull) / (2ull * SLOT_BYTES));
    if (G > 6) G = 6;
    // y1r must not overlap used hb slots; with G<6 place it right after
    y1rp = (ushort*)(ws + HB_OFF + (size_t)(2 * G) * SLOT_BYTES);
  }
  const bool defer = (G >= 1);

  for (int k = 0; k < 2; ++k)
    for (int b = 0; b < 2; ++b)
      hipMemsetAsync((char*)(k == 0 ? rhA : rhB) + (size_t)b * TP * 64 * 2, 0,
                     (size_t)PAD * 64 * 2, stream);
  hipMemsetAsync(condb, 0, (size_t)2 * TP * 96 * 2, stream);

  prep_kernel<<<2048, 256, 0, stream>>>(dil_w, cond_w, skip_w, res_w, p1_w,
                                        p2_w, mel_w, dil_b, cond_b, skip_b, wa,
                                        wsf, wrf, wp1, wp2, condA, zbp, sbsp);
  cond_mfma<<<dim3(64, BATCH, 2), 256, 0, stream>>>(mels, condA, mel_b, condb);
  if (!defer) {
    hipMemsetAsync(skipg, 0, (size_t)2 * T_LEN * 128 * 4, stream);
  }
  init_res_kernel<<<(BATCH * T_LEN * 64 + 255) / 256, 256, 0, stream>>>(
      x, input_w, input_b, rhA);

  ushort* rhi = rhA;
  ushort* rho = rhB;
  int groupStart = 0;
  const dim3 ag(T_LEN / 32, BATCH);
  for (int p = 0; p < NPAIRS; ++p) {
    int i0 = 2 * p;
    int d0 = 1 << (i0 % 10);
    int wr = (p < NPAIRS - 1) ? 1 : 0;
    if (defer) {
      ushort* h0 = hbuf + (size_t)(2 * (p - groupStart)) * SLOT_ELEMS;
      wn_pair_kernel<1><<<dim3(NTILES, BATCH), 256, 0, stream>>>(
          rhi, rho, condb, wa, wsf, wrf, zbp, res_b, skip_b, skipg, h0,
          h0 + SLOT_ELEMS, i0, d0, wr);
      if (p - groupStart + 1 == G || p == NPAIRS - 1) {
        int nl = 2 * (p - groupStart + 1);
        int base = 2 * groupStart;
        bool isF = (groupStart == 0);
        bool isL = (p == NPAIRS - 1);
        if (isF && isL)
          skip_accum<1, 1><<<ag, 256, 0, stream>>>(hbuf, wsf, skipg, sbsp, wp1,
                                                   p1_b, y1rp, base, nl);
        else if (isF)
          skip_accum<1, 0><<<ag, 256, 0, stream>>>(hbuf, wsf, skipg, sbsp, wp1,
                                                   p1_b, y1rp, base, nl);
        else if (isL)
          skip_accum<0, 1><<<ag, 256, 0, stream>>>(hbuf, wsf, skipg, sbsp, wp1,
                                                   p1_b, y1rp, base, nl);
        else
          skip_accum<0, 0><<<ag, 256, 0, stream>>>(hbuf, wsf, skipg, sbsp, wp1,
                                                   p1_b, y1rp, base, nl);
        groupStart = p + 1;
      }
    } else {
      wn_pair_kernel<0><<<dim3(NTILES, BATCH), 256, 0, stream>>>(
          rhi, rho, condb, wa, wsf, wrf, zbp, res_b, skip_b, skipg, nullptr,
          nullptr, i0, d0, wr);
    }
    ushort* th = rhi; rhi = rho; rho = th;
  }

  if (!defer) {
    post1_mfma<<<dim3(NTILES, BATCH), 256, 0, stream>>>(skipg, nullptr, wp1,
                                                        p1_b, y1rp);
  }
  post2_mfma<<<dim3(NTILES, BATCH), 256, 0, stream>>>(y1rp, wp2, p2_b, out);
}

// Round 12
// 697.833 us; speedup vs baseline: 1.5665x; 1.2158x over previous
//
#include <hip/hip_runtime.h>
#include <math.h>

#define T_LEN 32512
#define NTILES 508
#define BATCH 2
#define NMEL 80
#define FRAMES 128
#define NBLK 30
#define NPAIRS 15
#define PAD 768
#define TP (T_LEN + PAD)  // 33280

typedef short bfrag __attribute__((ext_vector_type(8)));
typedef float facc __attribute__((ext_vector_type(4)));
typedef ushort us4v __attribute__((ext_vector_type(4)));
typedef ushort us8v __attribute__((ext_vector_type(8)));

#define MFMA16(a, b, c) __builtin_amdgcn_mfma_f32_16x16x32_bf16((a), (b), (c), 0, 0, 0)

// ---- workspace layout (byte offsets) ----
#define RESH_OFF   0u          // bf16 [2buf][2b][TP][64] = 17,039,360
#define CONDB_OFF  17039360u   // bf16 [2b][TP][96]       = 12,779,520
#define WA_OFF     29818880u   // bf16 30*56*512
#define WSF_OFF    31539200u   // bf16 30*16*512
#define WRF_OFF    32030720u   // bf16 30*8*512
#define WP1_OFF    32276480u   // bf16 64*512
#define WP2_OFF    32342016u   // bf16 128*512
#define ZB_OFF     32473088u   // f32 30*128
#define SBS_OFF    32488448u   // f32 128
#define SKIPG_OFF  32488960u   // f32 [2b][T][128] = 33,292,288
#define CONDA_OFF  SKIPG_OFF   // condA aliased (dead before first skip_accum)
#define HB_OFF     65781248u   // bf16 h slots: [slot][2b][T][64]
#define SLOT_BYTES 8323072ull
#define SLOT_ELEMS 4161536ull
#define Y1R_OFF    165658112u  // bf16 [2b][256][T] = 33,292,288; total ~199 MB

static __device__ __forceinline__ ushort f2bf(float f) {
  union { float f; unsigned int u; } v;
  v.f = f;
  unsigned int r = (v.u + 0x7FFFu + ((v.u >> 16) & 1u)) >> 16;
  return (ushort)r;
}
static __device__ __forceinline__ float bf2f(ushort h) {
  union { unsigned int u; float f; } v;
  v.u = ((unsigned int)h) << 16;
  return v.f;
}
static __device__ __forceinline__ float sigmoidf_(float x) {
  return 1.f / (1.f + __expf(-x));
}
static __device__ __forceinline__ float tanhf_(float x) {
  return 2.f / (1.f + __expf(-2.f * x)) - 1.f;
}
static __device__ __forceinline__ bfrag ldfrag(const ushort* p) {
  return *reinterpret_cast<const bfrag*>(p);
}
static __device__ __forceinline__ void gload_lds16(const void* g, void* l) {
  __builtin_amdgcn_global_load_lds(
      (const __attribute__((address_space(1))) unsigned int*)g,
      (__attribute__((address_space(3))) unsigned int*)l, 16, 0, 0);
}

// ---- prep: weights -> MFMA A-fragments; condA; zb; sbs ----
__global__ __launch_bounds__(256) void prep_kernel(
    const float* __restrict__ dil_w, const float* __restrict__ cond_w,
    const float* __restrict__ skip_w, const float* __restrict__ res_w,
    const float* __restrict__ p1_w, const float* __restrict__ p2_w,
    const float* __restrict__ mel_w, const float* __restrict__ dil_b,
    const float* __restrict__ cond_b, const float* __restrict__ skip_b,
    ushort* __restrict__ wa, ushort* __restrict__ wsf, ushort* __restrict__ wrf,
    ushort* __restrict__ wp1, ushort* __restrict__ wp2,
    ushort* __restrict__ condA, float* __restrict__ zb,
    float* __restrict__ sbs) {
  int tid = blockIdx.x * blockDim.x + threadIdx.x;
  int stride = gridDim.x * blockDim.x;
  for (int idx = tid; idx < NBLK * 56 * 512; idx += stride) {
    int j = idx & 7, lane = (idx >> 3) & 63;
    int f = (idx >> 9) % 56, layer = idx / (56 * 512);
    int mt = f / 7, kt = f % 7;
    int m = 16 * mt + (lane & 15);
    int k = 32 * kt + 8 * (lane >> 4) + j;
    float v;
    if (k < 64)       v = dil_w[(((size_t)layer * 128 + m) * 64 + k) * 2 + 0];
    else if (k < 128) v = dil_w[(((size_t)layer * 128 + m) * 64 + (k - 64)) * 2 + 1];
    else if (k < 208) v = cond_w[((size_t)layer * 128 + m) * 80 + (k - 128)];
    else              v = 0.f;
    wa[idx] = f2bf(v);
  }
  for (int idx = tid; idx < NBLK * 16 * 512; idx += stride) {
    int j = idx & 7, lane = (idx >> 3) & 63;
    int f = (idx >> 9) & 15, layer = idx / (16 * 512);
    int mt = f >> 1, kt = f & 1;
    int m = 16 * mt + (lane & 15);
    int k = 32 * kt + 8 * (lane >> 4) + j;
    wsf[idx] = f2bf(skip_w[((size_t)layer * 128 + m) * 64 + k]);
  }
  for (int idx = tid; idx < NBLK * 8 * 512; idx += stride) {
    int j = idx & 7, lane = (idx >> 3) & 63;
    int f = (idx >> 9) & 7, layer = idx / (8 * 512);
    int mt = f >> 1, kt = f & 1;
    int m = 16 * mt + (lane & 15);
    int k = 32 * kt + 8 * (lane >> 4) + j;
    wrf[idx] = f2bf(res_w[((size_t)layer * 64 + m) * 64 + k]);
  }
  for (int idx = tid; idx < 64 * 512; idx += stride) {
    int j = idx & 7, lane = (idx >> 3) & 63;
    int f = idx >> 9;
    int mt = f >> 2, kt = f & 3;
    int m = 16 * mt + (lane & 15);
    int k = 32 * kt + 8 * (lane >> 4) + j;
    wp1[idx] = f2bf(p1_w[(size_t)m * 128 + k]);
  }
  for (int idx = tid; idx < 128 * 512; idx += stride) {
    int j = idx & 7, lane = (idx >> 3) & 63;
    int f = idx >> 9;
    int mt = f >> 3, kt = f & 7;
    int m = 16 * mt + (lane & 15);
    int k = 32 * kt + 8 * (lane >> 4) + j;
    wp2[idx] = f2bf(p2_w[(size_t)m * 256 + k]);
  }
  for (int idx = tid; idx < 25 * 512 * 256; idx += stride) {
    int q = idx & 511;
    int f = (idx >> 9) % 25;
    int u = idx / (25 * 512);
    int j = q & 7, lane = q >> 3;
    int mt = f / 5, kt = f % 5;
    int m = 16 * mt + (lane & 15);
    int k = 32 * kt + 8 * (lane >> 4) + j;
    int ci = (k < 80) ? k : k - 80;
    int kk = (k < 80) ? (255 - u) : (511 - u);
    condA[idx] = f2bf(mel_w[((size_t)m * 80 + ci) * 512 + kk]);
  }
  for (int idx = tid; idx < NBLK * 128; idx += stride)
    zb[idx] = dil_b[idx] + cond_b[idx];
  for (int idx = tid; idx < 128; idx += stride) {
    float s = 0.f;
    for (int i2 = 0; i2 < NBLK; ++i2) s += skip_b[i2 * 128 + idx];
    sbs[idx] = s;
  }
}

// ---- mel upsample MFMA; writes cond t-major [b][TP][96] bf16 ----
#define BSTR 168
__global__ __launch_bounds__(256) void cond_mfma(
    const float* __restrict__ mels, const ushort* __restrict__ condA,
    const float* __restrict__ mel_b, ushort* __restrict__ condb) {
  __shared__ ushort BT[128 * BSTR];
  const int tid = threadIdx.x;
  const int lane = tid & 63;
  const int w = tid >> 6;
  const int b = blockIdx.y;
  const int half = blockIdx.z;
  const int u = blockIdx.x * 4 + w;
  const int q4 = 4 * (lane >> 4);
  const int l15 = lane & 15;
  const float* melb = mels + (size_t)b * NMEL * FRAMES;
  for (int idx = tid; idx < 160 * 128; idx += 256) {
    int M = idx & 127;
    int k = idx >> 7;
    int ci = (k < 80) ? k : k - 80;
    int Mp = M + ((k < 80) ? 0 : 1);
    float v = (Mp < 128) ? melb[(size_t)ci * FRAMES + Mp] : 0.f;
    BT[M * BSTR + k] = f2bf(v);
  }
  __syncthreads();
  facc acc[5][4];
  #pragma unroll
  for (int mt = 0; mt < 5; ++mt) {
    #pragma unroll
    for (int nt = 0; nt < 4; ++nt) {
      #pragma unroll
      for (int r = 0; r < 4; ++r) acc[mt][nt][r] = mel_b[16 * mt + q4 + r];
    }
  }
  const ushort* cA = condA + (size_t)u * 25 * 512 + lane * 8;
  const int bofs = l15 * BSTR + 8 * (lane >> 4);
  #pragma unroll
  for (int kt = 0; kt < 5; ++kt) {
    bfrag a[5];
    #pragma unroll
    for (int mt = 0; mt < 5; ++mt) a[mt] = ldfrag(cA + (mt * 5 + kt) * 512);
    #pragma unroll
    for (int nt = 0; nt < 4; ++nt) {
      bfrag bb = ldfrag(&BT[(half * 64 + nt * 16) * BSTR + bofs + kt * 32]);
      #pragma unroll
      for (int mt = 0; mt < 5; ++mt) acc[mt][nt] = MFMA16(a[mt], bb, acc[mt][nt]);
    }
  }
  ushort* cbp = condb + (size_t)b * TP * 96;
  #pragma unroll
  for (int mt = 0; mt < 5; ++mt) {
    #pragma unroll
    for (int nt = 0; nt < 4; ++nt) {
      const int M = half * 64 + nt * 16 + l15;
      if (M < 127) {
        us4v p;
        #pragma unroll
        for (int r = 0; r < 4; ++r) p[r] = f2bf(acc[mt][nt][r]);
        const int t = M * 256 + u;
        *reinterpret_cast<us4v*>(&cbp[(size_t)(t + PAD) * 96 + 16 * mt + q4]) = p;
      }
    }
  }
}

// ---- init: res_0 bf16 t-major rows [PAD, PAD+T) ----
__global__ __launch_bounds__(256) void init_res_kernel(
    const float* __restrict__ x, const float* __restrict__ iw,
    const float* __restrict__ ib, ushort* __restrict__ resh0) {
  int idx = blockIdx.x * blockDim.x + threadIdx.x;
  if (idx >= BATCH * T_LEN * 64) return;
  int c = idx & 63;
  int t = (idx >> 6) % T_LEN;
  int b = idx / (64 * T_LEN);
  float v = x[(size_t)b * T_LEN + t] * iw[c] + ib[c];
  resh0[(size_t)b * TP * 64 + (size_t)(t + PAD) * 64 + c] = f2bf(v);
}

// ============ pair kernel v7: block-level LDS B-tiles (kill 4x redundancy) ====
// XT1: ctx-S taps [64 rows][256B] -> after use: lo = h(i0,S), hi = res_i0(S)
// XT2: ctx-H taps                 -> after use: lo = h(i0,H), hi = res_i0(H)
// CT : home cond (96 cols real + 32 zero), used by ctx H AND layer i1
// All tiles XOR-swizzled: byte ^= ((row&7)<<4); staged via gload_lds with
// inverse-swizzled source (rule: linear dest + swz source + swz read).
template <int DEFER>
__global__ __launch_bounds__(256, 3) void wn_pair_kernel(
    const ushort* __restrict__ resh_in, ushort* __restrict__ resh_out,
    const ushort* __restrict__ condb, const ushort* __restrict__ wa,
    const ushort* __restrict__ wsf, const ushort* __restrict__ wrf,
    const float* __restrict__ zb, const float* __restrict__ res_b,
    const float* __restrict__ skip_b, float* __restrict__ skipg,
    ushort* __restrict__ hb0, ushort* __restrict__ hb1, int i0, int d0,
    int writeRes) {
  __shared__ char XT1[16384];
  __shared__ char XT2[16384];
  __shared__ char CT[16384];
  const int i1 = i0 + 1;
  const int d1 = 2 * d0;
  const int tid = threadIdx.x;
  const int lane = tid & 63;
  const int w = tid >> 6;
  const int l15 = lane & 15;
  const int g = lane >> 4;
  const int q4 = 4 * g;
  // bijective XCD swizzle (508 = 8*63+4)
  const int orig = blockIdx.x;
  const int xcd = orig & 7;
  const int loc = orig >> 3;
  const int tile = (xcd < 4 ? xcd * 64 : 256 + (xcd - 4) * 63) + loc;
  const int t0 = tile * 64;
  const int t0s = t0 - d1;
  const int b = blockIdx.y;

  const ushort* rhi = resh_in + (size_t)b * TP * 64;
  ushort* rho = resh_out + (size_t)b * TP * 64;
  const ushort* cbp = condb + (size_t)b * TP * 96;

  // ---- stage the three tiles (each wave fills its 4KB quarter) ----
  #pragma unroll
  for (int j = 0; j < 4; ++j) {
    const int D = w * 4096 + j * 1024 + lane * 16;
    const int Ls = D ^ (((D >> 8) & 7) << 4);
    const int row = Ls >> 8;
    const int half = (Ls >> 7) & 1;
    const int off = Ls & 127;
    const char* s1 = (const char*)(rhi +
        (size_t)(t0s + row - (half ? 0 : d0) + PAD) * 64) + off;
    gload_lds16(s1, XT1 + D);
    const char* s2 = (const char*)(rhi +
        (size_t)(t0 + row - (half ? 0 : d0) + PAD) * 64) + off;
    gload_lds16(s2, XT2 + D);
    const int offc = Ls & 255;
    const char* s3 = (offc < 192)
        ? (const char*)cbp + (size_t)(t0 + row + PAD) * 192 + offc
        : (const char*)cbp + offc;  // zero-pad region
    gload_lds16(s3, CT + D);
  }

  facc accF[4], accG[4], rs_s[4], rs_h[4], sk[8];
  if constexpr (!DEFER) {
    #pragma unroll
    for (int jj = 0; jj < 8; ++jj) {
      const int ch = 32 * w + 16 * (jj >> 2) + q4;
      facc s0 = *(const facc*)(skip_b + i0 * 128 + ch);
      facc s1 = *(const facc*)(skip_b + i1 * 128 + ch);
      sk[jj] = s0 + s1;
    }
  }

// LDS swizzled b128 read: row r, byte x within row
#define LDSF(BUF, r, x) \
  ldfrag((const ushort*)((BUF) + ((((r) * 256 + (x)) ^ (((r) & 7) << 4)))))

#define ZG_INITB(LAYER)                                                       \
  _Pragma("unroll")                                                           \
  for (int nt = 0; nt < 4; ++nt) {                                            \
    accF[nt] = *(const facc*)(zb + (LAYER) * 128 + 16 * w + q4);              \
    accG[nt] = *(const facc*)(zb + (LAYER) * 128 + 64 + 16 * w + q4);         \
  }

// z for ctx S: taps from XT1, cond DIRECT global (shifted rows)
#define ZG_S(LAYER)                                                           \
  {                                                                           \
    ZG_INITB(LAYER)                                                           \
    const ushort* wal = wa + (size_t)(LAYER) * 56 * 512 + lane * 8;           \
    const ushort* bpc[4];                                                     \
    _Pragma("unroll")                                                         \
    for (int nt = 0; nt < 4; ++nt)                                            \
      bpc[nt] = cbp + (size_t)(t0s + nt * 16 + l15 + PAD) * 96 + 8 * g;       \
    _Pragma("unroll")                                                         \
    for (int kt = 0; kt < 7; ++kt) {                                          \
      bfrag aF = ldfrag(wal + (w * 7 + kt) * 512);                            \
      bfrag aG = ldfrag(wal + ((w + 4) * 7 + kt) * 512);                      \
      _Pragma("unroll")                                                       \
      for (int nt = 0; nt < 4; ++nt) {                                        \
        const int r = nt * 16 + l15;                                          \
        bfrag bb = (kt < 4) ? LDSF(XT1, r, kt * 64 + 16 * g)                  \
                            : ldfrag(bpc[nt] + (kt - 4) * 32);                \
        accF[nt] = MFMA16(aF, bb, accF[nt]);                                  \
        accG[nt] = MFMA16(aG, bb, accG[nt]);                                  \
      }                                                                       \
    }                                                                         \
  }

// z for ctx H: taps from XT2, cond from CT
#define ZG_H(LAYER)                                                           \
  {                                                                           \
    ZG_INITB(LAYER)                                                           \
    const ushort* wal = wa + (size_t)(LAYER) * 56 * 512 + lane * 8;           \
    _Pragma("unroll")                                                         \
    for (int kt = 0; kt < 7; ++kt) {                                          \
      bfrag aF = ldfrag(wal + (w * 7 + kt) * 512);                            \
      bfrag aG = ldfrag(wal + ((w + 4) * 7 + kt) * 512);                      \
      _Pragma("unroll")                                                       \
      for (int nt = 0; nt < 4; ++nt) {                                        \
        const int r = nt * 16 + l15;                                          \
        bfrag bb = (kt < 4) ? LDSF(XT2, r, kt * 64 + 16 * g)                  \
                            : LDSF(CT, r, (kt - 4) * 64 + 16 * g);            \
        accF[nt] = MFMA16(aF, bb, accF[nt]);                                  \
        accG[nt] = MFMA16(aG, bb, accG[nt]);                                  \
      }                                                                       \
    }                                                                         \
  }

// z for layer i1: tap0 = RTs (XT1 hi), tap1 = RTh (XT2 hi), cond from CT
#define ZG_I1(LAYER)                                                          \
  {                                                                           \
    ZG_INITB(LAYER)                                                           \
    const ushort* wal = wa + (size_t)(LAYER) * 56 * 512 + lane * 8;           \
    _Pragma("unroll")                                                         \
    for (int kt = 0; kt < 7; ++kt) {                                          \
      bfrag aF = ldfrag(wal + (w * 7 + kt) * 512);                            \
      bfrag aG = ldfrag(wal + ((w + 4) * 7 + kt) * 512);                      \
      _Pragma("unroll")                                                       \
      for (int nt = 0; nt < 4; ++nt) {                                        \
        const int r = nt * 16 + l15;                                          \
        bfrag bb = (kt < 2)                                                   \
            ? LDSF(XT1, r, 128 + kt * 64 + 16 * g)                            \
            : (kt < 4) ? LDSF(XT2, r, 128 + (kt - 2) * 64 + 16 * g)           \
                       : LDSF(CT, r, (kt - 4) * 64 + 16 * g);                 \
        accF[nt] = MFMA16(aF, bb, accF[nt]);                                  \
        accG[nt] = MFMA16(aG, bb, accG[nt]);                                  \
      }                                                                       \
    }                                                                         \
  }

// gate: write h bf16 into BUF lo (swizzled); optionally also to hb global
#define GATE(BUF, HBPTR, DOHB)                                                \
  {                                                                           \
    _Pragma("unroll")                                                         \
    for (int nt = 0; nt < 4; ++nt) {                                          \
      us4v p;                                                                 \
      _Pragma("unroll")                                                       \
      for (int r = 0; r < 4; ++r)                                             \
        p[r] = f2bf(tanhf_(accF[nt][r]) * sigmoidf_(accG[nt][r]));            \
      const int row = nt * 16 + l15;                                          \
      const int byo = (row * 256 + 32 * w + 8 * g) ^ ((row & 7) << 4);        \
      *reinterpret_cast<us4v*>((BUF) + byo) = p;                              \
      if (DOHB)                                                               \
        *reinterpret_cast<us4v*>((HBPTR) + (size_t)b * T_LEN * 64 +           \
                                 (size_t)(t0 + row) * 64 + 16 * w + q4) = p;  \
    }                                                                         \
  }

#define RES_GEMM(LAYER, HTBUF, RS)                                            \
  {                                                                           \
    const ushort* wrl = wrf + (size_t)(LAYER) * 8 * 512 + lane * 8;           \
    _Pragma("unroll")                                                         \
    for (int kt = 0; kt < 2; ++kt) {                                          \
      bfrag ar = ldfrag(wrl + (w * 2 + kt) * 512);                            \
      _Pragma("unroll")                                                       \
      for (int nt = 0; nt < 4; ++nt) {                                        \
        const int r = nt * 16 + l15;                                          \
        bfrag bb = LDSF(HTBUF, r, kt * 64 + 16 * g);                          \
        RS[nt] = MFMA16(ar, bb, RS[nt]);                                      \
      }                                                                       \
    }                                                                         \
  }

#define SKIP_GEMM(LAYER, HTBUF)                                               \
  {                                                                           \
    const ushort* wsl = wsf + (size_t)(LAYER) * 16 * 512 + lane * 8;          \
    _Pragma("unroll")                                                         \
    for (int kt = 0; kt < 2; ++kt) {                                          \
      bfrag a0 = ldfrag(wsl + ((2 * w) * 2 + kt) * 512);                      \
      bfrag a1 = ldfrag(wsl + ((2 * w + 1) * 2 + kt) * 512);                  \
      _Pragma("unroll")                                                       \
      for (int nt = 0; nt < 4; ++nt) {                                        \
        const int r = nt * 16 + l15;                                          \
        bfrag bb = LDSF(HTBUF, r, kt * 64 + 16 * g);                          \
        sk[nt] = MFMA16(a0, bb, sk[nt]);                                      \
        sk[4 + nt] = MFMA16(a1, bb, sk[4 + nt]);                              \
      }                                                                       \
    }                                                                         \
  }

// write res bf16 into BUF hi half (swizzled)
#define RT_WRITE(BUF, RS, GUARD)                                              \
  {                                                                           \
    _Pragma("unroll")                                                         \
    for (int nt = 0; nt < 4; ++nt) {                                          \
      us4v p;                                                                 \
      const bool ok = !(GUARD) || (t0s + nt * 16 + l15) >= 0;                 \
      _Pragma("unroll")                                                       \
      for (int r = 0; r < 4; ++r) p[r] = ok ? f2bf(RS[nt][r]) : (ushort)0;    \
      const int row = nt * 16 + l15;                                          \
      const int byo = (row * 256 + 128 + 32 * w + 8 * g) ^ ((row & 7) << 4);  \
      *reinterpret_cast<us4v*>((BUF) + byo) = p;                              \
    }                                                                         \
  }

  __syncthreads();  // B1: tiles staged (barrier drains gload_lds)

  // ===== ctx S: layer i0 @ shifted tile =====
  ZG_S(i0);
  __syncthreads();  // B2: all waves done reading XT1 taps
  GATE(XT1, hb0, 0);
  #pragma unroll
  for (int nt = 0; nt < 4; ++nt) {
    const int tg = t0s + nt * 16 + l15;
    us4v hv = *(const us4v*)(rhi + (size_t)(tg + PAD) * 64 + 16 * w + q4);
    facc rbv = *(const facc*)(res_b + i0 * 64 + 16 * w + q4);
    #pragma unroll
    for (int r = 0; r < 4; ++r) rs_s[nt][r] = bf2f(hv[r]) + rbv[r];
  }
  __syncthreads();  // B3: h(S) visible
  RES_GEMM(i0, XT1, rs_s);
  RT_WRITE(XT1, rs_s, 1);
  // ===== ctx H z (reads XT2 + CT; no conflict with XT1 ops) =====
  ZG_H(i0);
  __syncthreads();  // B4: all waves done reading XT2 taps; RTs stable
  GATE(XT2, hb0, DEFER);
  #pragma unroll
  for (int nt = 0; nt < 4; ++nt) {
    const int tg = t0 + nt * 16 + l15;
    us4v hv = *(const us4v*)(rhi + (size_t)(tg + PAD) * 64 + 16 * w + q4);
    facc rbv = *(const facc*)(res_b + i0 * 64 + 16 * w + q4);
    #pragma unroll
    for (int r = 0; r < 4; ++r) rs_h[nt][r] = bf2f(hv[r]) + rbv[r];
  }
  __syncthreads();  // B5: h(H) visible
  if constexpr (!DEFER) { SKIP_GEMM(i0, XT2); }
  RES_GEMM(i0, XT2, rs_h);
  RT_WRITE(XT2, rs_h, 0);
  __syncthreads();  // B6: RTh stable
  // ===== layer i1 @ home =====
  ZG_I1(i1);
  GATE(XT1, hb1, DEFER);  // XT1 lo dead since RES_GEMM_S (pre-B4); safe
  #pragma unroll
  for (int nt = 0; nt < 4; ++nt) {
    facc rbv = *(const facc*)(res_b + i1 * 64 + 16 * w + q4);
    rs_s[nt] = rs_h[nt] + rbv;
  }
  __syncthreads();  // B7: h(i1) visible
  if constexpr (!DEFER) { SKIP_GEMM(i1, XT1); }
  RES_GEMM(i1, XT1, rs_s);
  // ===== epilogue =====
  if (writeRes) {
    #pragma unroll
    for (int nt = 0; nt < 4; ++nt) {
      const int tg = t0 + nt * 16 + l15;
      us4v p;
      #pragma unroll
      for (int r = 0; r < 4; ++r) p[r] = f2bf(rs_s[nt][r]);
      *reinterpret_cast<us4v*>(rho + (size_t)(tg + PAD) * 64 + 16 * w + q4) = p;
    }
  }
  if constexpr (!DEFER) {
    float* sg = skipg + (size_t)b * T_LEN * 128;
    #pragma unroll
    for (int nt = 0; nt < 4; ++nt) {
      const int tg = t0 + nt * 16 + l15;
      facc* p0 = (facc*)(sg + (size_t)tg * 128 + 32 * w + q4);
      facc* p1 = (facc*)(sg + (size_t)tg * 128 + 32 * w + 16 + q4);
      *p0 = *p0 + sk[nt];
      *p1 = *p1 + sk[4 + nt];
    }
  }
#undef LDSF
#undef ZG_INITB
#undef ZG_S
#undef ZG_H
#undef ZG_I1
#undef GATE
#undef RES_GEMM
#undef SKIP_GEMM
#undef RT_WRITE
}

// ---- skip_accum v3: LDS-staged h, 32-t blocks; optional fused post1 ----
template <int FIRST, int FUSE>
__global__ __launch_bounds__(256) void skip_accum(
    const ushort* __restrict__ hb, const ushort* __restrict__ wsf,
    float* __restrict__ skipg, const float* __restrict__ sbs,
    const ushort* __restrict__ wp1, const float* __restrict__ p1b,
    ushort* __restrict__ y1r, int base, int nl) {
  __shared__ ushort HL[12 * 2048];
  const int tid = threadIdx.x;
  const int lane = tid & 63;
  const int w = tid >> 6;
  const int l15 = lane & 15;
  const int q4 = 4 * (lane >> 4);
  const int colq = 8 * (lane >> 4);
  const int t0 = blockIdx.x * 32;
  const int b = blockIdx.y;

  {
    const int D = tid * 16;
    const int Dsw = D ^ (((D >> 7) & 7) << 4);
    const char* srcb =
        (const char*)(hb + (size_t)b * T_LEN * 64 + (size_t)t0 * 64);
    char* ldsb = (char*)HL + (tid >> 6) * 1024;
    for (int l = 0; l < nl; ++l)
      gload_lds16(srcb + (size_t)l * SLOT_BYTES + Dsw, ldsb + l * 4096);
  }

  float* sg = skipg + (size_t)b * T_LEN * 128;
  facc a0[2], a1[2];
  if constexpr (FIRST) {
    #pragma unroll
    for (int nt = 0; nt < 2; ++nt) {
      #pragma unroll
      for (int r = 0; r < 4; ++r) { a0[nt][r] = 0.f; a1[nt][r] = 0.f; }
    }
  } else {
    #pragma unroll
    for (int nt = 0; nt < 2; ++nt) {
      const int tg = t0 + nt * 16 + l15;
      a0[nt] = *(const facc*)(sg + (size_t)tg * 128 + 32 * w + q4);
      a1[nt] = *(const facc*)(sg + (size_t)tg * 128 + 32 * w + 16 + q4);
    }
  }
  __syncthreads();

  for (int l = 0; l < nl; ++l) {
    const ushort* wsl = wsf + (size_t)(base + l) * 16 * 512 + lane * 8;
    #pragma unroll
    for (int kt = 0; kt < 2; ++kt) {
      bfrag f0 = ldfrag(wsl + ((2 * w) * 2 + kt) * 512);
      bfrag f1 = ldfrag(wsl + ((2 * w + 1) * 2 + kt) * 512);
      #pragma unroll
      for (int nt = 0; nt < 2; ++nt) {
        const int t = nt * 16 + l15;
        int byteoff = t * 128 + kt * 64 + colq * 2;
        byteoff ^= ((t & 7) << 4);
        bfrag bb = ldfrag((const ushort*)((const char*)HL + l * 4096 + byteoff));
        a0[nt] = MFMA16(f0, bb, a0[nt]);
        a1[nt] = MFMA16(f1, bb, a1[nt]);
      }
    }
  }

  if constexpr (!FUSE) {
    #pragma unroll
    for (int nt = 0; nt < 2; ++nt) {
      const int tg = t0 + nt * 16 + l15;
      *(facc*)(sg + (size_t)tg * 128 + 32 * w + q4) = a0[nt];
      *(facc*)(sg + (size_t)tg * 128 + 32 * w + 16 + q4) = a1[nt];
    }
  } else {
    __syncthreads();
    ushort* ST = HL;
    #pragma unroll
    for (int nt = 0; nt < 2; ++nt) {
      us4v p0, p1;
      #pragma unroll
      for (int r = 0; r < 4; ++r) {
        p0[r] = f2bf(fmaxf(a0[nt][r] + sbs[32 * w + q4 + r], 0.f));
        p1[r] = f2bf(fmaxf(a1[nt][r] + sbs[32 * w + 16 + q4 + r], 0.f));
      }
      const int row = nt * 16 + l15;
      *reinterpret_cast<us4v*>(&ST[row * 136 + 32 * w + q4]) = p0;
      *reinterpret_cast<us4v*>(&ST[row * 136 + 32 * w + 16 + q4]) = p1;
    }
    __syncthreads();
    facc acc2[4][2];
    #pragma unroll
    for (int mi = 0; mi < 4; ++mi) {
      #pragma unroll
      for (int nt = 0; nt < 2; ++nt) {
        #pragma unroll
        for (int r = 0; r < 4; ++r)
          acc2[mi][nt][r] = p1b[16 * (4 * w + mi) + q4 + r];
      }
    }
    const int lo = lane * 8;
    #pragma unroll
    for (int kt = 0; kt < 4; ++kt) {
      bfrag am[4];
      #pragma unroll
      for (int mi = 0; mi < 4; ++mi)
        am[mi] = ldfrag(wp1 + ((4 * w + mi) * 4 + kt) * 512 + lo);
      #pragma unroll
      for (int nt = 0; nt < 2; ++nt) {
        bfrag bb = ldfrag(&ST[(nt * 16 + l15) * 136 + kt * 32 + colq]);
        #pragma unroll
        for (int mi = 0; mi < 4; ++mi)
          acc2[mi][nt] = MFMA16(am[mi], bb, acc2[mi][nt]);
      }
    }
    ushort* yb = y1r + (size_t)b * 256 * T_LEN;
    #pragma unroll
    for (int mi = 0; mi < 4; ++mi) {
      #pragma unroll
      for (int nt = 0; nt < 2; ++nt) {
        const int tt = t0 + nt * 16 + l15;
        #pragma unroll
        for (int r = 0; r < 4; ++r)
          yb[(size_t)(16 * (4 * w + mi) + q4 + r) * T_LEN + tt] =
              f2bf(fmaxf(acc2[mi][nt][r], 0.f));
      }
    }
  }
}

// ---- standalone post1 (non-defer fallback only; sbs may be null) ----
#define FSSTR 136
__global__ __launch_bounds__(256) void post1_mfma(
    const float* __restrict__ skipg, const float* __restrict__ sbs,
    const ushort* __restrict__ wp1, const float* __restrict__ p1b,
    ushort* __restrict__ y1r) {
  __shared__ ushort ST[64 * FSSTR];
  const int tid = threadIdx.x;
  const int lane = tid & 63;
  const int w = tid >> 6;
  const int t0 = blockIdx.x * 64;
  const int b = blockIdx.y;
  {
    const int t = tid & 63;
    const int kc = tid >> 6;
    const float* sp =
        skipg + (size_t)b * T_LEN * 128 + (size_t)(t0 + t) * 128 + kc * 32;
    #pragma unroll
    for (int j = 0; j < 8; ++j) {
      facc v = *(const facc*)(sp + j * 4);
      us4v o;
      #pragma unroll
      for (int r = 0; r < 4; ++r) {
        float s = sbs ? sbs[kc * 32 + j * 4 + r] : 0.f;
        o[r] = f2bf(fmaxf(v[r] + s, 0.f));
      }
      *reinterpret_cast<us4v*>(&ST[t * FSSTR + kc * 32 + j * 4]) = o;
    }
  }
  __syncthreads();
  const int q4 = 4 * (lane >> 4);
  facc acc[4][4];
  #pragma unroll
  for (int mi = 0; mi < 4; ++mi) {
    #pragma unroll
    for (int nt = 0; nt < 4; ++nt) {
      #pragma unroll
      for (int r = 0; r < 4; ++r)
        acc[mi][nt][r] = p1b[16 * (4 * w + mi) + q4 + r];
    }
  }
  const int lo = lane * 8;
  const int bofs = (lane & 15) * FSSTR + 8 * (lane >> 4);
  #pragma unroll
  for (int kt = 0; kt < 4; ++kt) {
    bfrag a[4];
    #pragma unroll
    for (int mi = 0; mi < 4; ++mi)
      a[mi] = ldfrag(wp1 + ((4 * w + mi) * 4 + kt) * 512 + lo);
    #pragma unroll
    for (int nt = 0; nt < 4; ++nt) {
      bfrag bb = ldfrag(&ST[nt * 16 * FSSTR + bofs + kt * 32]);
      #pragma unroll
      for (int mi = 0; mi < 4; ++mi) acc[mi][nt] = MFMA16(a[mi], bb, acc[mi][nt]);
    }
  }
  ushort* yb = y1r + (size_t)b * 256 * T_LEN;
  #pragma unroll
  for (int mi = 0; mi < 4; ++mi) {
    #pragma unroll
    for (int nt = 0; nt < 4; ++nt) {
      const int tt = t0 + nt * 16 + (lane & 15);
      #pragma unroll
      for (int r = 0; r < 4; ++r)
        yb[(size_t)(16 * (4 * w + mi) + q4 + r) * T_LEN + tt] =
            f2bf(fmaxf(acc[mi][nt][r], 0.f));
    }
  }
}

// ---- post2: out = p2_w @ y1r + b (fp32) ----
#define YSTR 264
__global__ __launch_bounds__(256) void post2_mfma(
    const ushort* __restrict__ y1r, const ushort* __restrict__ wp2,
    const float* __restrict__ p2b, float* __restrict__ out) {
  __shared__ ushort YT[64 * YSTR];
  const int tid = threadIdx.x;
  const int lane = tid & 63;
  const int w = tid >> 6;
  const int t0 = blockIdx.x * 64;
  const int b = blockIdx.y;
  const ushort* yb = y1r + (size_t)b * 256 * T_LEN;
  const int t = t0 + lane;
  for (int kc = 0; kc < 8; ++kc) {
    int k0 = w * 64 + kc * 8;
    us8v v;
    #pragma unroll
    for (int j = 0; j < 8; ++j) v[j] = yb[(size_t)(k0 + j) * T_LEN + t];
    *reinterpret_cast<us8v*>(&YT[lane * YSTR + k0]) = v;
  }
  __syncthreads();
  const int q4 = 4 * (lane >> 4);
  facc acc[4][4];
  #pragma unroll
  for (int mi = 0; mi < 4; ++mi) {
    #pragma unroll
    for (int nt = 0; nt < 4; ++nt) {
      #pragma unroll
      for (int r = 0; r < 4; ++r)
        acc[mi][nt][r] = p2b[16 * (4 * w + mi) + q4 + r];
    }
  }
  const int lo = lane * 8;
  const int bofs = (lane & 15) * YSTR + 8 * (lane >> 4);
  #pragma unroll
  for (int kt = 0; kt < 8; ++kt) {
    bfrag a[4];
    #pragma unroll
    for (int mi = 0; mi < 4; ++mi)
      a[mi] = ldfrag(wp2 + ((4 * w + mi) * 8 + kt) * 512 + lo);
    #pragma unroll
    for (int nt = 0; nt < 4; ++nt) {
      bfrag bb = ldfrag(&YT[nt * 16 * YSTR + bofs + kt * 32]);
      #pragma unroll
      for (int mi = 0; mi < 4; ++mi) acc[mi][nt] = MFMA16(a[mi], bb, acc[mi][nt]);
    }
  }
  float* ob = out + (size_t)b * 256 * T_LEN;
  #pragma unroll
  for (int mi = 0; mi < 4; ++mi) {
    #pragma unroll
    for (int nt = 0; nt < 4; ++nt) {
      const int tt = t0 + nt * 16 + (lane & 15);
      #pragma unroll
      for (int r = 0; r < 4; ++r)
        ob[(size_t)(16 * (4 * w + mi) + q4 + r) * T_LEN + tt] = acc[mi][nt][r];
    }
  }
}

extern "C" void kernel_launch(void* const* d_in, const int* in_sizes, int n_in,
                              void* d_out, int out_size, void* d_ws,
                              size_t ws_size, hipStream_t stream) {
  const float* x       = (const float*)d_in[0];
  const float* mels    = (const float*)d_in[1];
  const float* input_w = (const float*)d_in[2];
  const float* input_b = (const float*)d_in[3];
  const float* mel_w   = (const float*)d_in[4];
  const float* mel_b   = (const float*)d_in[5];
  const float* dil_w   = (const float*)d_in[6];
  const float* dil_b   = (const float*)d_in[7];
  const float* cond_w  = (const float*)d_in[8];
  const float* cond_b  = (const float*)d_in[9];
  const float* skip_w  = (const float*)d_in[10];
  const float* skip_b  = (const float*)d_in[11];
  const float* res_w   = (const float*)d_in[12];
  const float* res_b   = (const float*)d_in[13];
  const float* p1_w    = (const float*)d_in[14];
  const float* p1_b    = (const float*)d_in[15];
  const float* p2_w    = (const float*)d_in[16];
  const float* p2_b    = (const float*)d_in[17];

  char* ws = (char*)d_ws;
  ushort* rhA   = (ushort*)(ws + RESH_OFF);
  ushort* rhB   = rhA + (size_t)2 * TP * 64;
  ushort* condb = (ushort*)(ws + CONDB_OFF);
  ushort* wa    = (ushort*)(ws + WA_OFF);
  ushort* wsf   = (ushort*)(ws + WSF_OFF);
  ushort* wrf   = (ushort*)(ws + WRF_OFF);
  ushort* wp1   = (ushort*)(ws + WP1_OFF);
  ushort* wp2   = (ushort*)(ws + WP2_OFF);
  float* zbp    = (float*)(ws + ZB_OFF);
  float* sbsp   = (float*)(ws + SBS_OFF);
  float* skipg  = (float*)(ws + SKIPG_OFF);
  ushort* condA = (ushort*)(ws + CONDA_OFF);
  ushort* hbuf  = (ushort*)(ws + HB_OFF);
  ushort* y1rp  = (ushort*)(ws + Y1R_OFF);
  float* out    = (float*)d_out;

  int G = 0;
  if (ws_size >= (size_t)Y1R_OFF + 33292288ull) {
    G = 6;
  } else if (ws_size >= (size_t)HB_OFF + 2ull * SLOT_BYTES + 33292288ull) {
    G = (int)((ws_size - HB_OFF - 33292288ull) / (2ull * SLOT_BYTES));
    if (G > 6) G = 6;
    y1rp = (ushort*)(ws + HB_OFF + (size_t)(2 * G) * SLOT_BYTES);
  }
  const bool defer = (G >= 1);

  for (int k = 0; k < 2; ++k)
    for (int b = 0; b < 2; ++b)
      hipMemsetAsync((char*)(k == 0 ? rhA : rhB) + (size_t)b * TP * 64 * 2, 0,
                     (size_t)PAD * 64 * 2, stream);
  hipMemsetAsync(condb, 0, (size_t)2 * TP * 96 * 2, stream);

  prep_kernel<<<2048, 256, 0, stream>>>(dil_w, cond_w, skip_w, res_w, p1_w,
                                        p2_w, mel_w, dil_b, cond_b, skip_b, wa,
                                        wsf, wrf, wp1, wp2, condA, zbp, sbsp);
  cond_mfma<<<dim3(64, BATCH, 2), 256, 0, stream>>>(mels, condA, mel_b, condb);
  if (!defer) {
    hipMemsetAsync(skipg, 0, (size_t)2 * T_LEN * 128 * 4, stream);
  }
  init_res_kernel<<<(BATCH * T_LEN * 64 + 255) / 256, 256, 0, stream>>>(
      x, input_w, input_b, rhA);

  ushort* rhi = rhA;
  ushort* rho = rhB;
  int groupStart = 0;
  const dim3 ag(T_LEN / 32, BATCH);
  for (int p = 0; p < NPAIRS; ++p) {
    int i0 = 2 * p;
    int d0 = 1 << (i0 % 10);
    int wr = (p < NPAIRS - 1) ? 1 : 0;
    if (defer) {
      ushort* h0 = hbuf + (size_t)(2 * (p - groupStart)) * SLOT_ELEMS;
      wn_pair_kernel<1><<<dim3(NTILES, BATCH), 256, 0, stream>>>(
          rhi, rho, condb, wa, wsf, wrf, zbp, res_b, skip_b, skipg, h0,
          h0 + SLOT_ELEMS, i0, d0, wr);
      if (p - groupStart + 1 == G || p == NPAIRS - 1) {
        int nl = 2 * (p - groupStart + 1);
        int base = 2 * groupStart;
        bool isF = (groupStart == 0);
        bool isL = (p == NPAIRS - 1);
        if (isF && isL)
          skip_accum<1, 1><<<ag, 256, 0, stream>>>(hbuf, wsf, skipg, sbsp, wp1,
                                                   p1_b, y1rp, base, nl);
        else if (isF)
          skip_accum<1, 0><<<ag, 256, 0, stream>>>(hbuf, wsf, skipg, sbsp, wp1,
                                                   p1_b, y1rp, base, nl);
        else if (isL)
          skip_accum<0, 1><<<ag, 256, 0, stream>>>(hbuf, wsf, skipg, sbsp, wp1,
                                                   p1_b, y1rp, base, nl);
        else
          skip_accum<0, 0><<<ag, 256, 0, stream>>>(hbuf, wsf, skipg, sbsp, wp1,
                                                   p1_b, y1rp, base, nl);
        groupStart = p + 1;
      }
    } else {
      wn_pair_kernel<0><<<dim3(NTILES, BATCH), 256, 0, stream>>>(
          rhi, rho, condb, wa, wsf, wrf, zbp, res_b, skip_b, skipg, nullptr,
          nullptr, i0, d0, wr);
    }
    ushort* th = rhi; rhi = rho; rho = th;
  }

  if (!defer) {
    post1_mfma<<<dim3(NTILES, BATCH), 256, 0, stream>>>(skipg, nullptr, wp1,
                                                        p1_b, y1rp);
  }
  post2_mfma<<<dim3(NTILES, BATCH), 256, 0, stream>>>(y1rp, wp2, p2_b, out);
}

// Round 13
// 688.577 us; speedup vs baseline: 1.5876x; 1.0134x over previous
//
#include <hip/hip_runtime.h>
#include <hip/hip_bf16.h>
#include <math.h>

#define T_LEN 32512
#define NTILES 508
#define BATCH 2
#define NMEL 80
#define FRAMES 128
#define NBLK 30
#define NPAIRS 15
#define PAD 768
#define TP (T_LEN + PAD)  // 33280

typedef short bfrag __attribute__((ext_vector_type(8)));
typedef float facc __attribute__((ext_vector_type(4)));
typedef ushort us4v __attribute__((ext_vector_type(4)));
typedef ushort us8v __attribute__((ext_vector_type(8)));

#define MFMA16(a, b, c) __builtin_amdgcn_mfma_f32_16x16x32_bf16((a), (b), (c), 0, 0, 0)

// ---- workspace layout (byte offsets) ----
#define RESH_OFF   0u          // bf16 [2buf][2b][TP][64] = 17,039,360
#define CONDB_OFF  17039360u   // bf16 [2b][TP][96]       = 12,779,520
#define WA_OFF     29818880u   // bf16 30*56*512
#define WSF_OFF    31539200u   // bf16 30*16*512
#define WRF_OFF    32030720u   // bf16 30*8*512
#define WP1_OFF    32276480u   // bf16 64*512
#define WP2_OFF    32342016u   // bf16 128*512
#define ZB_OFF     32473088u   // f32 30*128
#define SBS_OFF    32488448u   // f32 128
#define SKIPG_OFF  32488960u   // f32 [2b][T][128] = 33,292,288
#define CONDA_OFF  SKIPG_OFF   // condA aliased (dead before first skip_accum)
#define HB_OFF     65781248u   // bf16 h slots: [slot][2b][T][64]
#define SLOT_BYTES 8323072ull
#define SLOT_ELEMS 4161536ull
#define Y1R_OFF    165658112u  // bf16 [2b][256][T] = 33,292,288; total ~199 MB

static __device__ __forceinline__ ushort f2bf(float f) {
  union { __hip_bfloat16 h; ushort u; } v;
  v.h = __float2bfloat16(f);  // RNE; compiler fuses pairs to v_cvt_pk_bf16_f32
  return v.u;
}
static __device__ __forceinline__ float bf2f(ushort h) {
  union { unsigned int u; float f; } v;
  v.u = ((unsigned int)h) << 16;
  return v.f;
}
static __device__ __forceinline__ float sigmoidf_(float x) {
  return 1.f / (1.f + __expf(-x));
}
static __device__ __forceinline__ float tanhf_(float x) {
  return 2.f / (1.f + __expf(-2.f * x)) - 1.f;
}
static __device__ __forceinline__ bfrag ldfrag(const ushort* p) {
  return *reinterpret_cast<const bfrag*>(p);
}
static __device__ __forceinline__ void gload_lds16(const void* g, void* l) {
  __builtin_amdgcn_global_load_lds(
      (const __attribute__((address_space(1))) unsigned int*)g,
      (__attribute__((address_space(3))) unsigned int*)l, 16, 0, 0);
}

// ---- prep: weights -> MFMA A-fragments; condA; zb; sbs ----
__global__ __launch_bounds__(256) void prep_kernel(
    const float* __restrict__ dil_w, const float* __restrict__ cond_w,
    const float* __restrict__ skip_w, const float* __restrict__ res_w,
    const float* __restrict__ p1_w, const float* __restrict__ p2_w,
    const float* __restrict__ mel_w, const float* __restrict__ dil_b,
    const float* __restrict__ cond_b, const float* __restrict__ skip_b,
    ushort* __restrict__ wa, ushort* __restrict__ wsf, ushort* __restrict__ wrf,
    ushort* __restrict__ wp1, ushort* __restrict__ wp2,
    ushort* __restrict__ condA, float* __restrict__ zb,
    float* __restrict__ sbs) {
  int tid = blockIdx.x * blockDim.x + threadIdx.x;
  int stride = gridDim.x * blockDim.x;
  for (int idx = tid; idx < NBLK * 56 * 512; idx += stride) {
    int j = idx & 7, lane = (idx >> 3) & 63;
    int f = (idx >> 9) % 56, layer = idx / (56 * 512);
    int mt = f / 7, kt = f % 7;
    int m = 16 * mt + (lane & 15);
    int k = 32 * kt + 8 * (lane >> 4) + j;
    float v;
    if (k < 64)       v = dil_w[(((size_t)layer * 128 + m) * 64 + k) * 2 + 0];
    else if (k < 128) v = dil_w[(((size_t)layer * 128 + m) * 64 + (k - 64)) * 2 + 1];
    else if (k < 208) v = cond_w[((size_t)layer * 128 + m) * 80 + (k - 128)];
    else              v = 0.f;
    wa[idx] = f2bf(v);
  }
  for (int idx = tid; idx < NBLK * 16 * 512; idx += stride) {
    int j = idx & 7, lane = (idx >> 3) & 63;
    int f = (idx >> 9) & 15, layer = idx / (16 * 512);
    int mt = f >> 1, kt = f & 1;
    int m = 16 * mt + (lane & 15);
    int k = 32 * kt + 8 * (lane >> 4) + j;
    wsf[idx] = f2bf(skip_w[((size_t)layer * 128 + m) * 64 + k]);
  }
  for (int idx = tid; idx < NBLK * 8 * 512; idx += stride) {
    int j = idx & 7, lane = (idx >> 3) & 63;
    int f = (idx >> 9) & 7, layer = idx / (8 * 512);
    int mt = f >> 1, kt = f & 1;
    int m = 16 * mt + (lane & 15);
    int k = 32 * kt + 8 * (lane >> 4) + j;
    wrf[idx] = f2bf(res_w[((size_t)layer * 64 + m) * 64 + k]);
  }
  for (int idx = tid; idx < 64 * 512; idx += stride) {
    int j = idx & 7, lane = (idx >> 3) & 63;
    int f = idx >> 9;
    int mt = f >> 2, kt = f & 3;
    int m = 16 * mt + (lane & 15);
    int k = 32 * kt + 8 * (lane >> 4) + j;
    wp1[idx] = f2bf(p1_w[(size_t)m * 128 + k]);
  }
  for (int idx = tid; idx < 128 * 512; idx += stride) {
    int j = idx & 7, lane = (idx >> 3) & 63;
    int f = idx >> 9;
    int mt = f >> 3, kt = f & 7;
    int m = 16 * mt + (lane & 15);
    int k = 32 * kt + 8 * (lane >> 4) + j;
    wp2[idx] = f2bf(p2_w[(size_t)m * 256 + k]);
  }
  for (int idx = tid; idx < 25 * 512 * 256; idx += stride) {
    int q = idx & 511;
    int f = (idx >> 9) % 25;
    int u = idx / (25 * 512);
    int j = q & 7, lane = q >> 3;
    int mt = f / 5, kt = f % 5;
    int m = 16 * mt + (lane & 15);
    int k = 32 * kt + 8 * (lane >> 4) + j;
    int ci = (k < 80) ? k : k - 80;
    int kk = (k < 80) ? (255 - u) : (511 - u);
    condA[idx] = f2bf(mel_w[((size_t)m * 80 + ci) * 512 + kk]);
  }
  for (int idx = tid; idx < NBLK * 128; idx += stride)
    zb[idx] = dil_b[idx] + cond_b[idx];
  for (int idx = tid; idx < 128; idx += stride) {
    float s = 0.f;
    for (int i2 = 0; i2 < NBLK; ++i2) s += skip_b[i2 * 128 + idx];
    sbs[idx] = s;
  }
}

// ---- mel upsample MFMA; writes cond t-major [b][TP][96] bf16 ----
#define BSTR 168
__global__ __launch_bounds__(256) void cond_mfma(
    const float* __restrict__ mels, const ushort* __restrict__ condA,
    const float* __restrict__ mel_b, ushort* __restrict__ condb) {
  __shared__ ushort BT[128 * BSTR];
  const int tid = threadIdx.x;
  const int lane = tid & 63;
  const int w = tid >> 6;
  const int b = blockIdx.y;
  const int half = blockIdx.z;
  const int u = blockIdx.x * 4 + w;
  const int q4 = 4 * (lane >> 4);
  const int l15 = lane & 15;
  const float* melb = mels + (size_t)b * NMEL * FRAMES;
  for (int idx = tid; idx < 160 * 128; idx += 256) {
    int M = idx & 127;
    int k = idx >> 7;
    int ci = (k < 80) ? k : k - 80;
    int Mp = M + ((k < 80) ? 0 : 1);
    float v = (Mp < 128) ? melb[(size_t)ci * FRAMES + Mp] : 0.f;
    BT[M * BSTR + k] = f2bf(v);
  }
  __syncthreads();
  facc acc[5][4];
  #pragma unroll
  for (int mt = 0; mt < 5; ++mt) {
    #pragma unroll
    for (int nt = 0; nt < 4; ++nt) {
      #pragma unroll
      for (int r = 0; r < 4; ++r) acc[mt][nt][r] = mel_b[16 * mt + q4 + r];
    }
  }
  const ushort* cA = condA + (size_t)u * 25 * 512 + lane * 8;
  const int bofs = l15 * BSTR + 8 * (lane >> 4);
  #pragma unroll
  for (int kt = 0; kt < 5; ++kt) {
    bfrag a[5];
    #pragma unroll
    for (int mt = 0; mt < 5; ++mt) a[mt] = ldfrag(cA + (mt * 5 + kt) * 512);
    #pragma unroll
    for (int nt = 0; nt < 4; ++nt) {
      bfrag bb = ldfrag(&BT[(half * 64 + nt * 16) * BSTR + bofs + kt * 32]);
      #pragma unroll
      for (int mt = 0; mt < 5; ++mt) acc[mt][nt] = MFMA16(a[mt], bb, acc[mt][nt]);
    }
  }
  ushort* cbp = condb + (size_t)b * TP * 96;
  #pragma unroll
  for (int mt = 0; mt < 5; ++mt) {
    #pragma unroll
    for (int nt = 0; nt < 4; ++nt) {
      const int M = half * 64 + nt * 16 + l15;
      if (M < 127) {
        us4v p;
        #pragma unroll
        for (int r = 0; r < 4; ++r) p[r] = f2bf(acc[mt][nt][r]);
        const int t = M * 256 + u;
        *reinterpret_cast<us4v*>(&cbp[(size_t)(t + PAD) * 96 + 16 * mt + q4]) = p;
      }
    }
  }
}

// ---- init: res_0 bf16 t-major rows [PAD, PAD+T) ----
__global__ __launch_bounds__(256) void init_res_kernel(
    const float* __restrict__ x, const float* __restrict__ iw,
    const float* __restrict__ ib, ushort* __restrict__ resh0) {
  int idx = blockIdx.x * blockDim.x + threadIdx.x;
  if (idx >= BATCH * T_LEN * 64) return;
  int c = idx & 63;
  int t = (idx >> 6) % T_LEN;
  int b = idx / (64 * T_LEN);
  float v = x[(size_t)b * T_LEN + t] * iw[c] + ib[c];
  resh0[(size_t)b * TP * 64 + (size_t)(t + PAD) * 64 + c] = f2bf(v);
}

// ============ pair kernel v7: block-level LDS B-tiles ============
template <int DEFER>
__global__ __launch_bounds__(256, 3) void wn_pair_kernel(
    const ushort* __restrict__ resh_in, ushort* __restrict__ resh_out,
    const ushort* __restrict__ condb, const ushort* __restrict__ wa,
    const ushort* __restrict__ wsf, const ushort* __restrict__ wrf,
    const float* __restrict__ zb, const float* __restrict__ res_b,
    const float* __restrict__ skip_b, float* __restrict__ skipg,
    ushort* __restrict__ hb0, ushort* __restrict__ hb1, int i0, int d0,
    int writeRes) {
  __shared__ char XT1[16384];
  __shared__ char XT2[16384];
  __shared__ char CT[16384];
  const int i1 = i0 + 1;
  const int d1 = 2 * d0;
  const int tid = threadIdx.x;
  const int lane = tid & 63;
  const int w = tid >> 6;
  const int l15 = lane & 15;
  const int g = lane >> 4;
  const int q4 = 4 * g;
  const int orig = blockIdx.x;
  const int xcd = orig & 7;
  const int loc = orig >> 3;
  const int tile = (xcd < 4 ? xcd * 64 : 256 + (xcd - 4) * 63) + loc;
  const int t0 = tile * 64;
  const int t0s = t0 - d1;
  const int b = blockIdx.y;

  const ushort* rhi = resh_in + (size_t)b * TP * 64;
  ushort* rho = resh_out + (size_t)b * TP * 64;
  const ushort* cbp = condb + (size_t)b * TP * 96;

  #pragma unroll
  for (int j = 0; j < 4; ++j) {
    const int D = w * 4096 + j * 1024 + lane * 16;
    const int Ls = D ^ (((D >> 8) & 7) << 4);
    const int row = Ls >> 8;
    const int half = (Ls >> 7) & 1;
    const int off = Ls & 127;
    const char* s1 = (const char*)(rhi +
        (size_t)(t0s + row - (half ? 0 : d0) + PAD) * 64) + off;
    gload_lds16(s1, XT1 + D);
    const char* s2 = (const char*)(rhi +
        (size_t)(t0 + row - (half ? 0 : d0) + PAD) * 64) + off;
    gload_lds16(s2, XT2 + D);
    const int offc = Ls & 255;
    const char* s3 = (offc < 192)
        ? (const char*)cbp + (size_t)(t0 + row + PAD) * 192 + offc
        : (const char*)cbp + offc;
    gload_lds16(s3, CT + D);
  }

  facc accF[4], accG[4], rs_s[4], rs_h[4], sk[8];
  if constexpr (!DEFER) {
    #pragma unroll
    for (int jj = 0; jj < 8; ++jj) {
      const int ch = 32 * w + 16 * (jj >> 2) + q4;
      facc s0 = *(const facc*)(skip_b + i0 * 128 + ch);
      facc s1 = *(const facc*)(skip_b + i1 * 128 + ch);
      sk[jj] = s0 + s1;
    }
  }

#define LDSF(BUF, r, x) \
  ldfrag((const ushort*)((BUF) + ((((r) * 256 + (x)) ^ (((r) & 7) << 4)))))

#define ZG_INITB(LAYER)                                                       \
  _Pragma("unroll")                                                           \
  for (int nt = 0; nt < 4; ++nt) {                                            \
    accF[nt] = *(const facc*)(zb + (LAYER) * 128 + 16 * w + q4);              \
    accG[nt] = *(const facc*)(zb + (LAYER) * 128 + 64 + 16 * w + q4);         \
  }

#define ZG_S(LAYER)                                                           \
  {                                                                           \
    ZG_INITB(LAYER)                                                           \
    const ushort* wal = wa + (size_t)(LAYER) * 56 * 512 + lane * 8;           \
    const ushort* bpc[4];                                                     \
    _Pragma("unroll")                                                         \
    for (int nt = 0; nt < 4; ++nt)                                            \
      bpc[nt] = cbp + (size_t)(t0s + nt * 16 + l15 + PAD) * 96 + 8 * g;       \
    _Pragma("unroll")                                                         \
    for (int kt = 0; kt < 7; ++kt) {                                          \
      bfrag aF = ldfrag(wal + (w * 7 + kt) * 512);                            \
      bfrag aG = ldfrag(wal + ((w + 4) * 7 + kt) * 512);                      \
      _Pragma("unroll")                                                       \
      for (int nt = 0; nt < 4; ++nt) {                                        \
        const int r = nt * 16 + l15;                                          \
        bfrag bb = (kt < 4) ? LDSF(XT1, r, kt * 64 + 16 * g)                  \
                            : ldfrag(bpc[nt] + (kt - 4) * 32);                \
        accF[nt] = MFMA16(aF, bb, accF[nt]);                                  \
        accG[nt] = MFMA16(aG, bb, accG[nt]);                                  \
      }                                                                       \
    }                                                                         \
  }

#define ZG_H(LAYER)                                                           \
  {                                                                           \
    ZG_INITB(LAYER)                                                           \
    const ushort* wal = wa + (size_t)(LAYER) * 56 * 512 + lane * 8;           \
    _Pragma("unroll")                                                         \
    for (int kt = 0; kt < 7; ++kt) {                                          \
      bfrag aF = ldfrag(wal + (w * 7 + kt) * 512);                            \
      bfrag aG = ldfrag(wal + ((w + 4) * 7 + kt) * 512);                      \
      _Pragma("unroll")                                                       \
      for (int nt = 0; nt < 4; ++nt) {                                        \
        const int r = nt * 16 + l15;                                          \
        bfrag bb = (kt < 4) ? LDSF(XT2, r, kt * 64 + 16 * g)                  \
                            : LDSF(CT, r, (kt - 4) * 64 + 16 * g);            \
        accF[nt] = MFMA16(aF, bb, accF[nt]);                                  \
        accG[nt] = MFMA16(aG, bb, accG[nt]);                                  \
      }                                                                       \
    }                                                                         \
  }

#define ZG_I1(LAYER)                                                          \
  {                                                                           \
    ZG_INITB(LAYER)                                                           \
    const ushort* wal = wa + (size_t)(LAYER) * 56 * 512 + lane * 8;           \
    _Pragma("unroll")                                                         \
    for (int kt = 0; kt < 7; ++kt) {                                          \
      bfrag aF = ldfrag(wal + (w * 7 + kt) * 512);                            \
      bfrag aG = ldfrag(wal + ((w + 4) * 7 + kt) * 512);                      \
      _Pragma("unroll")                                                       \
      for (int nt = 0; nt < 4; ++nt) {                                        \
        const int r = nt * 16 + l15;                                          \
        bfrag bb = (kt < 2)                                                   \
            ? LDSF(XT1, r, 128 + kt * 64 + 16 * g)                            \
            : (kt < 4) ? LDSF(XT2, r, 128 + (kt - 2) * 64 + 16 * g)           \
                       : LDSF(CT, r, (kt - 4) * 64 + 16 * g);                 \
        accF[nt] = MFMA16(aF, bb, accF[nt]);                                  \
        accG[nt] = MFMA16(aG, bb, accG[nt]);                                  \
      }                                                                       \
    }                                                                         \
  }

#define GATE(BUF, HBPTR, DOHB)                                                \
  {                                                                           \
    _Pragma("unroll")                                                         \
    for (int nt = 0; nt < 4; ++nt) {                                          \
      us4v p;                                                                 \
      _Pragma("unroll")                                                       \
      for (int r = 0; r < 4; ++r)                                             \
        p[r] = f2bf(tanhf_(accF[nt][r]) * sigmoidf_(accG[nt][r]));            \
      const int row = nt * 16 + l15;                                          \
      const int byo = (row * 256 + 32 * w + 8 * g) ^ ((row & 7) << 4);        \
      *reinterpret_cast<us4v*>((BUF) + byo) = p;                              \
      if (DOHB)                                                               \
        *reinterpret_cast<us4v*>((HBPTR) + (size_t)b * T_LEN * 64 +           \
                                 (size_t)(t0 + row) * 64 + 16 * w + q4) = p;  \
    }                                                                         \
  }

#define RES_GEMM(LAYER, HTBUF, RS)                                            \
  {                                                                           \
    const ushort* wrl = wrf + (size_t)(LAYER) * 8 * 512 + lane * 8;           \
    _Pragma("unroll")                                                         \
    for (int kt = 0; kt < 2; ++kt) {                                          \
      bfrag ar = ldfrag(wrl + (w * 2 + kt) * 512);                            \
      _Pragma("unroll")                                                       \
      for (int nt = 0; nt < 4; ++nt) {                                        \
        const int r = nt * 16 + l15;                                          \
        bfrag bb = LDSF(HTBUF, r, kt * 64 + 16 * g);                          \
        RS[nt] = MFMA16(ar, bb, RS[nt]);                                      \
      }                                                                       \
    }                                                                         \
  }

#define SKIP_GEMM(LAYER, HTBUF)                                               \
  {                                                                           \
    const ushort* wsl = wsf + (size_t)(LAYER) * 16 * 512 + lane * 8;          \
    _Pragma("unroll")                                                         \
    for (int kt = 0; kt < 2; ++kt) {                                          \
      bfrag a0 = ldfrag(wsl + ((2 * w) * 2 + kt) * 512);                      \
      bfrag a1 = ldfrag(wsl + ((2 * w + 1) * 2 + kt) * 512);                  \
      _Pragma("unroll")                                                       \
      for (int nt = 0; nt < 4; ++nt) {                                        \
        const int r = nt * 16 + l15;                                          \
        bfrag bb = LDSF(HTBUF, r, kt * 64 + 16 * g);                          \
        sk[nt] = MFMA16(a0, bb, sk[nt]);                                      \
        sk[4 + nt] = MFMA16(a1, bb, sk[4 + nt]);                              \
      }                                                                       \
    }                                                                         \
  }

#define RT_WRITE(BUF, RS, GUARD)                                              \
  {                                                                           \
    _Pragma("unroll")                                                         \
    for (int nt = 0; nt < 4; ++nt) {                                          \
      us4v p;                                                                 \
      const bool ok = !(GUARD) || (t0s + nt * 16 + l15) >= 0;                 \
      _Pragma("unroll")                                                       \
      for (int r = 0; r < 4; ++r) p[r] = ok ? f2bf(RS[nt][r]) : (ushort)0;    \
      const int row = nt * 16 + l15;                                          \
      const int byo = (row * 256 + 128 + 32 * w + 8 * g) ^ ((row & 7) << 4);  \
      *reinterpret_cast<us4v*>((BUF) + byo) = p;                              \
    }                                                                         \
  }

  __syncthreads();  // B1: tiles staged

  ZG_S(i0);
  __syncthreads();  // B2
  GATE(XT1, hb0, 0);
  #pragma unroll
  for (int nt = 0; nt < 4; ++nt) {
    const int tg = t0s + nt * 16 + l15;
    us4v hv = *(const us4v*)(rhi + (size_t)(tg + PAD) * 64 + 16 * w + q4);
    facc rbv = *(const facc*)(res_b + i0 * 64 + 16 * w + q4);
    #pragma unroll
    for (int r = 0; r < 4; ++r) rs_s[nt][r] = bf2f(hv[r]) + rbv[r];
  }
  __syncthreads();  // B3
  RES_GEMM(i0, XT1, rs_s);
  RT_WRITE(XT1, rs_s, 1);
  ZG_H(i0);
  __syncthreads();  // B4
  GATE(XT2, hb0, DEFER);
  #pragma unroll
  for (int nt = 0; nt < 4; ++nt) {
    const int tg = t0 + nt * 16 + l15;
    us4v hv = *(const us4v*)(rhi + (size_t)(tg + PAD) * 64 + 16 * w + q4);
    facc rbv = *(const facc*)(res_b + i0 * 64 + 16 * w + q4);
    #pragma unroll
    for (int r = 0; r < 4; ++r) rs_h[nt][r] = bf2f(hv[r]) + rbv[r];
  }
  __syncthreads();  // B5
  if constexpr (!DEFER) { SKIP_GEMM(i0, XT2); }
  RES_GEMM(i0, XT2, rs_h);
  RT_WRITE(XT2, rs_h, 0);
  __syncthreads();  // B6
  ZG_I1(i1);
  GATE(XT1, hb1, DEFER);
  #pragma unroll
  for (int nt = 0; nt < 4; ++nt) {
    facc rbv = *(const facc*)(res_b + i1 * 64 + 16 * w + q4);
    rs_s[nt] = rs_h[nt] + rbv;
  }
  __syncthreads();  // B7
  if constexpr (!DEFER) { SKIP_GEMM(i1, XT1); }
  RES_GEMM(i1, XT1, rs_s);
  if (writeRes) {
    #pragma unroll
    for (int nt = 0; nt < 4; ++nt) {
      const int tg = t0 + nt * 16 + l15;
      us4v p;
      #pragma unroll
      for (int r = 0; r < 4; ++r) p[r] = f2bf(rs_s[nt][r]);
      *reinterpret_cast<us4v*>(rho + (size_t)(tg + PAD) * 64 + 16 * w + q4) = p;
    }
  }
  if constexpr (!DEFER) {
    float* sg = skipg + (size_t)b * T_LEN * 128;
    #pragma unroll
    for (int nt = 0; nt < 4; ++nt) {
      const int tg = t0 + nt * 16 + l15;
      facc* p0 = (facc*)(sg + (size_t)tg * 128 + 32 * w + q4);
      facc* p1 = (facc*)(sg + (size_t)tg * 128 + 32 * w + 16 + q4);
      *p0 = *p0 + sk[nt];
      *p1 = *p1 + sk[4 + nt];
    }
  }
#undef LDSF
#undef ZG_INITB
#undef ZG_S
#undef ZG_H
#undef ZG_I1
#undef GATE
#undef RES_GEMM
#undef SKIP_GEMM
#undef RT_WRITE
}

// ---- skip_accum v4: chunked LDS staging (16KB -> 8 blocks/CU) ----
#define SACHUNK 4
template <int FIRST, int FUSE>
__global__ __launch_bounds__(256) void skip_accum(
    const ushort* __restrict__ hb, const ushort* __restrict__ wsf,
    float* __restrict__ skipg, const float* __restrict__ sbs,
    const ushort* __restrict__ wp1, const float* __restrict__ p1b,
    ushort* __restrict__ y1r, int base, int nl) {
  __shared__ ushort HL[SACHUNK * 2048];  // 16 KB
  const int tid = threadIdx.x;
  const int lane = tid & 63;
  const int w = tid >> 6;
  const int l15 = lane & 15;
  const int q4 = 4 * (lane >> 4);
  const int colq = 8 * (lane >> 4);
  const int t0 = blockIdx.x * 32;
  const int b = blockIdx.y;

  const int D = tid * 16;
  const int Dsw = D ^ (((D >> 7) & 7) << 4);
  const char* srcb =
      (const char*)(hb + (size_t)b * T_LEN * 64 + (size_t)t0 * 64);
  char* ldsb = (char*)HL + (tid >> 6) * 1024;

  float* sg = skipg + (size_t)b * T_LEN * 128;
  facc a0[2], a1[2];
  if constexpr (FIRST) {
    #pragma unroll
    for (int nt = 0; nt < 2; ++nt) {
      #pragma unroll
      for (int r = 0; r < 4; ++r) { a0[nt][r] = 0.f; a1[nt][r] = 0.f; }
    }
  } else {
    #pragma unroll
    for (int nt = 0; nt < 2; ++nt) {
      const int tg = t0 + nt * 16 + l15;
      a0[nt] = *(const facc*)(sg + (size_t)tg * 128 + 32 * w + q4);
      a1[nt] = *(const facc*)(sg + (size_t)tg * 128 + 32 * w + 16 + q4);
    }
  }

  for (int c0 = 0; c0 < nl; c0 += SACHUNK) {
    const int nc = (nl - c0 < SACHUNK) ? (nl - c0) : SACHUNK;
    for (int l = 0; l < nc; ++l)
      gload_lds16(srcb + (size_t)(c0 + l) * SLOT_BYTES + Dsw, ldsb + l * 4096);
    __syncthreads();  // drains gload_lds (vmcnt) + protects HL overwrite
    for (int l = 0; l < nc; ++l) {
      const ushort* wsl = wsf + (size_t)(base + c0 + l) * 16 * 512 + lane * 8;
      #pragma unroll
      for (int kt = 0; kt < 2; ++kt) {
        bfrag f0 = ldfrag(wsl + ((2 * w) * 2 + kt) * 512);
        bfrag f1 = ldfrag(wsl + ((2 * w + 1) * 2 + kt) * 512);
        #pragma unroll
        for (int nt = 0; nt < 2; ++nt) {
          const int t = nt * 16 + l15;
          int byteoff = t * 128 + kt * 64 + colq * 2;
          byteoff ^= ((t & 7) << 4);
          bfrag bb =
              ldfrag((const ushort*)((const char*)HL + l * 4096 + byteoff));
          a0[nt] = MFMA16(f0, bb, a0[nt]);
          a1[nt] = MFMA16(f1, bb, a1[nt]);
        }
      }
    }
    __syncthreads();  // all waves done with HL before next stage
  }

  if constexpr (!FUSE) {
    #pragma unroll
    for (int nt = 0; nt < 2; ++nt) {
      const int tg = t0 + nt * 16 + l15;
      *(facc*)(sg + (size_t)tg * 128 + 32 * w + q4) = a0[nt];
      *(facc*)(sg + (size_t)tg * 128 + 32 * w + 16 + q4) = a1[nt];
    }
  } else {
    ushort* ST = HL;  // [32][136] = 8704 B <= 16 KB
    #pragma unroll
    for (int nt = 0; nt < 2; ++nt) {
      us4v p0, p1;
      #pragma unroll
      for (int r = 0; r < 4; ++r) {
        p0[r] = f2bf(fmaxf(a0[nt][r] + sbs[32 * w + q4 + r], 0.f));
        p1[r] = f2bf(fmaxf(a1[nt][r] + sbs[32 * w + 16 + q4 + r], 0.f));
      }
      const int row = nt * 16 + l15;
      *reinterpret_cast<us4v*>(&ST[row * 136 + 32 * w + q4]) = p0;
      *reinterpret_cast<us4v*>(&ST[row * 136 + 32 * w + 16 + q4]) = p1;
    }
    __syncthreads();
    facc acc2[4][2];
    #pragma unroll
    for (int mi = 0; mi < 4; ++mi) {
      #pragma unroll
      for (int nt = 0; nt < 2; ++nt) {
        #pragma unroll
        for (int r = 0; r < 4; ++r)
          acc2[mi][nt][r] = p1b[16 * (4 * w + mi) + q4 + r];
      }
    }
    const int lo = lane * 8;
    #pragma unroll
    for (int kt = 0; kt < 4; ++kt) {
      bfrag am[4];
      #pragma unroll
      for (int mi = 0; mi < 4; ++mi)
        am[mi] = ldfrag(wp1 + ((4 * w + mi) * 4 + kt) * 512 + lo);
      #pragma unroll
      for (int nt = 0; nt < 2; ++nt) {
        bfrag bb = ldfrag(&ST[(nt * 16 + l15) * 136 + kt * 32 + colq]);
        #pragma unroll
        for (int mi = 0; mi < 4; ++mi)
          acc2[mi][nt] = MFMA16(am[mi], bb, acc2[mi][nt]);
      }
    }
    ushort* yb = y1r + (size_t)b * 256 * T_LEN;
    #pragma unroll
    for (int mi = 0; mi < 4; ++mi) {
      #pragma unroll
      for (int nt = 0; nt < 2; ++nt) {
        const int tt = t0 + nt * 16 + l15;
        #pragma unroll
        for (int r = 0; r < 4; ++r)
          yb[(size_t)(16 * (4 * w + mi) + q4 + r) * T_LEN + tt] =
              f2bf(fmaxf(acc2[mi][nt][r], 0.f));
      }
    }
  }
}

// ---- standalone post1 (non-defer fallback only; sbs may be null) ----
#define FSSTR 136
__global__ __launch_bounds__(256) void post1_mfma(
    const float* __restrict__ skipg, const float* __restrict__ sbs,
    const ushort* __restrict__ wp1, const float* __restrict__ p1b,
    ushort* __restrict__ y1r) {
  __shared__ ushort ST[64 * FSSTR];
  const int tid = threadIdx.x;
  const int lane = tid & 63;
  const int w = tid >> 6;
  const int t0 = blockIdx.x * 64;
  const int b = blockIdx.y;
  {
    const int t = tid & 63;
    const int kc = tid >> 6;
    const float* sp =
        skipg + (size_t)b * T_LEN * 128 + (size_t)(t0 + t) * 128 + kc * 32;
    #pragma unroll
    for (int j = 0; j < 8; ++j) {
      facc v = *(const facc*)(sp + j * 4);
      us4v o;
      #pragma unroll
      for (int r = 0; r < 4; ++r) {
        float s = sbs ? sbs[kc * 32 + j * 4 + r] : 0.f;
        o[r] = f2bf(fmaxf(v[r] + s, 0.f));
      }
      *reinterpret_cast<us4v*>(&ST[t * FSSTR + kc * 32 + j * 4]) = o;
    }
  }
  __syncthreads();
  const int q4 = 4 * (lane >> 4);
  facc acc[4][4];
  #pragma unroll
  for (int mi = 0; mi < 4; ++mi) {
    #pragma unroll
    for (int nt = 0; nt < 4; ++nt) {
      #pragma unroll
      for (int r = 0; r < 4; ++r)
        acc[mi][nt][r] = p1b[16 * (4 * w + mi) + q4 + r];
    }
  }
  const int lo = lane * 8;
  const int bofs = (lane & 15) * FSSTR + 8 * (lane >> 4);
  #pragma unroll
  for (int kt = 0; kt < 4; ++kt) {
    bfrag a[4];
    #pragma unroll
    for (int mi = 0; mi < 4; ++mi)
      a[mi] = ldfrag(wp1 + ((4 * w + mi) * 4 + kt) * 512 + lo);
    #pragma unroll
    for (int nt = 0; nt < 4; ++nt) {
      bfrag bb = ldfrag(&ST[nt * 16 * FSSTR + bofs + kt * 32]);
      #pragma unroll
      for (int mi = 0; mi < 4; ++mi) acc[mi][nt] = MFMA16(a[mi], bb, acc[mi][nt]);
    }
  }
  ushort* yb = y1r + (size_t)b * 256 * T_LEN;
  #pragma unroll
  for (int mi = 0; mi < 4; ++mi) {
    #pragma unroll
    for (int nt = 0; nt < 4; ++nt) {
      const int tt = t0 + nt * 16 + (lane & 15);
      #pragma unroll
      for (int r = 0; r < 4; ++r)
        yb[(size_t)(16 * (4 * w + mi) + q4 + r) * T_LEN + tt] =
            f2bf(fmaxf(acc[mi][nt][r], 0.f));
    }
  }
}

// ---- post2: out = p2_w @ y1r + b (fp32) ----
#define YSTR 264
__global__ __launch_bounds__(256) void post2_mfma(
    const ushort* __restrict__ y1r, const ushort* __restrict__ wp2,
    const float* __restrict__ p2b, float* __restrict__ out) {
  __shared__ ushort YT[64 * YSTR];
  const int tid = threadIdx.x;
  const int lane = tid & 63;
  const int w = tid >> 6;
  const int t0 = blockIdx.x * 64;
  const int b = blockIdx.y;
  const ushort* yb = y1r + (size_t)b * 256 * T_LEN;
  const int t = t0 + lane;
  for (int kc = 0; kc < 8; ++kc) {
    int k0 = w * 64 + kc * 8;
    us8v v;
    #pragma unroll
    for (int j = 0; j < 8; ++j) v[j] = yb[(size_t)(k0 + j) * T_LEN + t];
    *reinterpret_cast<us8v*>(&YT[lane * YSTR + k0]) = v;
  }
  __syncthreads();
  const int q4 = 4 * (lane >> 4);
  facc acc[4][4];
  #pragma unroll
  for (int mi = 0; mi < 4; ++mi) {
    #pragma unroll
    for (int nt = 0; nt < 4; ++nt) {
      #pragma unroll
      for (int r = 0; r < 4; ++r)
        acc[mi][nt][r] = p2b[16 * (4 * w + mi) + q4 + r];
    }
  }
  const int lo = lane * 8;
  const int bofs = (lane & 15) * YSTR + 8 * (lane >> 4);
  #pragma unroll
  for (int kt = 0; kt < 8; ++kt) {
    bfrag a[4];
    #pragma unroll
    for (int mi = 0; mi < 4; ++mi)
      a[mi] = ldfrag(wp2 + ((4 * w + mi) * 8 + kt) * 512 + lo);
    #pragma unroll
    for (int nt = 0; nt < 4; ++nt) {
      bfrag bb = ldfrag(&YT[nt * 16 * YSTR + bofs + kt * 32]);
      #pragma unroll
      for (int mi = 0; mi < 4; ++mi) acc[mi][nt] = MFMA16(a[mi], bb, acc[mi][nt]);
    }
  }
  float* ob = out + (size_t)b * 256 * T_LEN;
  #pragma unroll
  for (int mi = 0; mi < 4; ++mi) {
    #pragma unroll
    for (int nt = 0; nt < 4; ++nt) {
      const int tt = t0 + nt * 16 + (lane & 15);
      #pragma unroll
      for (int r = 0; r < 4; ++r)
        ob[(size_t)(16 * (4 * w + mi) + q4 + r) * T_LEN + tt] = acc[mi][nt][r];
    }
  }
}

extern "C" void kernel_launch(void* const* d_in, const int* in_sizes, int n_in,
                              void* d_out, int out_size, void* d_ws,
                              size_t ws_size, hipStream_t stream) {
  const float* x       = (const float*)d_in[0];
  const float* mels    = (const float*)d_in[1];
  const float* input_w = (const float*)d_in[2];
  const float* input_b = (const float*)d_in[3];
  const float* mel_w   = (const float*)d_in[4];
  const float* mel_b   = (const float*)d_in[5];
  const float* dil_w   = (const float*)d_in[6];
  const float* dil_b   = (const float*)d_in[7];
  const float* cond_w  = (const float*)d_in[8];
  const float* cond_b  = (const float*)d_in[9];
  const float* skip_w  = (const float*)d_in[10];
  const float* skip_b  = (const float*)d_in[11];
  const float* res_w   = (const float*)d_in[12];
  const float* res_b   = (const float*)d_in[13];
  const float* p1_w    = (const float*)d_in[14];
  const float* p1_b    = (const float*)d_in[15];
  const float* p2_w    = (const float*)d_in[16];
  const float* p2_b    = (const float*)d_in[17];

  char* ws = (char*)d_ws;
  ushort* rhA   = (ushort*)(ws + RESH_OFF);
  ushort* rhB   = rhA + (size_t)2 * TP * 64;
  ushort* condb = (ushort*)(ws + CONDB_OFF);
  ushort* wa    = (ushort*)(ws + WA_OFF);
  ushort* wsf   = (ushort*)(ws + WSF_OFF);
  ushort* wrf   = (ushort*)(ws + WRF_OFF);
  ushort* wp1   = (ushort*)(ws + WP1_OFF);
  ushort* wp2   = (ushort*)(ws + WP2_OFF);
  float* zbp    = (float*)(ws + ZB_OFF);
  float* sbsp   = (float*)(ws + SBS_OFF);
  float* skipg  = (float*)(ws + SKIPG_OFF);
  ushort* condA = (ushort*)(ws + CONDA_OFF);
  ushort* hbuf  = (ushort*)(ws + HB_OFF);
  ushort* y1rp  = (ushort*)(ws + Y1R_OFF);
  float* out    = (float*)d_out;

  int G = 0;
  if (ws_size >= (size_t)Y1R_OFF + 33292288ull) {
    G = 6;
  } else if (ws_size >= (size_t)HB_OFF + 2ull * SLOT_BYTES + 33292288ull) {
    G = (int)((ws_size - HB_OFF - 33292288ull) / (2ull * SLOT_BYTES));
    if (G > 6) G = 6;
    y1rp = (ushort*)(ws + HB_OFF + (size_t)(2 * G) * SLOT_BYTES);
  }
  const bool defer = (G >= 1);

  for (int k = 0; k < 2; ++k)
    for (int b = 0; b < 2; ++b)
      hipMemsetAsync((char*)(k == 0 ? rhA : rhB) + (size_t)b * TP * 64 * 2, 0,
                     (size_t)PAD * 64 * 2, stream);
  hipMemsetAsync(condb, 0, (size_t)2 * TP * 96 * 2, stream);

  prep_kernel<<<2048, 256, 0, stream>>>(dil_w, cond_w, skip_w, res_w, p1_w,
                                        p2_w, mel_w, dil_b, cond_b, skip_b, wa,
                                        wsf, wrf, wp1, wp2, condA, zbp, sbsp);
  cond_mfma<<<dim3(64, BATCH, 2), 256, 0, stream>>>(mels, condA, mel_b, condb);
  if (!defer) {
    hipMemsetAsync(skipg, 0, (size_t)2 * T_LEN * 128 * 4, stream);
  }
  init_res_kernel<<<(BATCH * T_LEN * 64 + 255) / 256, 256, 0, stream>>>(
      x, input_w, input_b, rhA);

  ushort* rhi = rhA;
  ushort* rho = rhB;
  int groupStart = 0;
  const dim3 ag(T_LEN / 32, BATCH);
  for (int p = 0; p < NPAIRS; ++p) {
    int i0 = 2 * p;
    int d0 = 1 << (i0 % 10);
    int wr = (p < NPAIRS - 1) ? 1 : 0;
    if (defer) {
      ushort* h0 = hbuf + (size_t)(2 * (p - groupStart)) * SLOT_ELEMS;
      wn_pair_kernel<1><<<dim3(NTILES, BATCH), 256, 0, stream>>>(
          rhi, rho, condb, wa, wsf, wrf, zbp, res_b, skip_b, skipg, h0,
          h0 + SLOT_ELEMS, i0, d0, wr);
      if (p - groupStart + 1 == G || p == NPAIRS - 1) {
        int nl = 2 * (p - groupStart + 1);
        int base = 2 * groupStart;
        bool isF = (groupStart == 0);
        bool isL = (p == NPAIRS - 1);
        if (isF && isL)
          skip_accum<1, 1><<<ag, 256, 0, stream>>>(hbuf, wsf, skipg, sbsp, wp1,
                                                   p1_b, y1rp, base, nl);
        else if (isF)
          skip_accum<1, 0><<<ag, 256, 0, stream>>>(hbuf, wsf, skipg, sbsp, wp1,
                                                   p1_b, y1rp, base, nl);
        else if (isL)
          skip_accum<0, 1><<<ag, 256, 0, stream>>>(hbuf, wsf, skipg, sbsp, wp1,
                                                   p1_b, y1rp, base, nl);
        else
          skip_accum<0, 0><<<ag, 256, 0, stream>>>(hbuf, wsf, skipg, sbsp, wp1,
                                                   p1_b, y1rp, base, nl);
        groupStart = p + 1;
      }
    } else {
      wn_pair_kernel<0><<<dim3(NTILES, BATCH), 256, 0, stream>>>(
          rhi, rho, condb, wa, wsf, wrf, zbp, res_b, skip_b, skipg, nullptr,
          nullptr, i0, d0, wr);
    }
    ushort* th = rhi; rhi = rho; rho = th;
  }

  if (!defer) {
    post1_mfma<<<dim3(NTILES, BATCH), 256, 0, stream>>>(skipg, nullptr, wp1,
                                                        p1_b, y1rp);
  }
  post2_mfma<<<dim3(NTILES, BATCH), 256, 0, stream>>>(y1rp, wp2, p2_b, out);
}